// Round 18
// baseline (268.770 us; speedup 1.0000x reference)
//
#include <hip/hip_runtime.h>
#include <hip/hip_bf16.h>
#include <math.h>

#define B_    8
#define L_    2048
#define HID   768
#define D2    384
#define NUV   1792
#define R_    16384
#define SCALE 0.08838834764831845f  // 128^-0.5

typedef __attribute__((ext_vector_type(8))) short bf16x8;
typedef __attribute__((ext_vector_type(4))) float f32x4;
typedef unsigned int uint32;
typedef unsigned short ushort;

static __device__ __forceinline__ uint32 bfr(float x) {
    uint32 u = __float_as_uint(x);
    return (u + 0x7FFFu + ((u >> 16) & 1u)) >> 16;
}
static __device__ __forceinline__ uint32 pk2(float lo, float hi) {
    return bfr(lo) | (bfr(hi) << 16);
}
static __device__ __forceinline__ float bf2f(ushort u) {
    return __uint_as_float(((uint32)u) << 16);
}
static __device__ __forceinline__ float silu_f(float x) { return x / (1.0f + __expf(-x)); }

// ---------------------------------------------------------------------------
// Weight pre-transform: Thi/Tlo[n][k] = bf16 hi/lo split of W[k][n]
// ---------------------------------------------------------------------------
__global__ __launch_bounds__(256) void conv_w(const float* __restrict__ W,
                                              ushort* __restrict__ Thi,
                                              ushort* __restrict__ Tlo,
                                              int K, int N)
{
    int idx = blockIdx.x * 256 + threadIdx.x;
    if (idx >= K * N) return;
    int n = idx / K, k = idx - n * K;
    float x = W[(size_t)k * N + n];
    uint32 h = bfr(x);
    float hf = __uint_as_float(h << 16);
    Thi[idx] = (ushort)h;
    Tlo[idx] = (ushort)bfr(x - hf);
}

// ---------------------------------------------------------------------------
// x pre-convert: xhi[m][k] = bf16(x[m][k])
// ---------------------------------------------------------------------------
__global__ __launch_bounds__(256) void conv_x(const float* __restrict__ X,
                                              ushort* __restrict__ Xhi, int total)
{
    int idx = blockIdx.x * 256 + threadIdx.x;
    if (idx >= total) return;
    Xhi[idx] = (ushort)bfr(X[idx]);
}

// ---------------------------------------------------------------------------
// Bf16-A 2-pass GEMM core: C_f32 = Abf16 @ (Bhi + Blo), copy staging.
// Block 512 thr (8 waves), tile 128x128, BK=64. LDS 48KB.
// EPI 0: plain f32 C.  EPI 1: GAU GEMM1 epilogue (u/v/qk by n0).
// ---------------------------------------------------------------------------
template<int EPI>
__global__ __launch_bounds__(512, 4) void gemm_2p(
    const ushort* __restrict__ Ahi, int lda,
    const ushort* __restrict__ BThi, const ushort* __restrict__ BTlo, int ldbt,
    float* __restrict__ C, int ldc,
    float* __restrict__ u_buf, ushort* __restrict__ qk, ushort* __restrict__ vT,
    int K)
{
    __shared__ unsigned char As[128 * 128];
    __shared__ unsigned char Bs[128 * 256];

    const int t  = threadIdx.x;
    const int w  = t >> 6;
    const int l  = t & 63;
    const int g  = l >> 4;
    const int li = l & 15;
    const int wr = w >> 1;
    const int wc = w & 1;
    const int m0 = blockIdx.y * 128;
    const int n0 = blockIdx.x * 128;

    f32x4 acc[2][4];
#pragma unroll
    for (int i = 0; i < 2; ++i)
#pragma unroll
        for (int j = 0; j < 4; ++j) acc[i][j] = (f32x4){0.f, 0.f, 0.f, 0.f};

    for (int k0 = 0; k0 < K; k0 += 64) {
#pragma unroll
        for (int i = 0; i < 2; ++i) {
            int idx = t + i * 512;
            int row = idx >> 3;
            int c8  = idx & 7;
            uint4 v = *(const uint4*)(Ahi + (size_t)(m0 + row) * lda + k0 + c8 * 8);
            *(uint4*)&As[row * 128 + ((c8 * 16) ^ ((row & 7) << 4))] = v;
        }
#pragma unroll
        for (int i = 0; i < 8; ++i) {
            int idx = t + i * 512;
            int c   = idx >> 5;
            int s8  = idx & 31;
            const ushort* src = (s8 < 16)
                ? (BThi + (long long)(n0 + c) * ldbt + k0 + s8 * 4)
                : (BTlo + (long long)(n0 + c) * ldbt + k0 + (s8 - 16) * 4);
            *(uint2*)&Bs[c * 256 + ((s8 * 8) ^ ((c & 7) << 4))] = *(const uint2*)src;
        }
        __syncthreads();

#pragma unroll
        for (int ks = 0; ks < 2; ++ks) {
            bf16x8 ah[2], bh[4], bl[4];
#pragma unroll
            for (int mi = 0; mi < 2; ++mi) {
                int row = wr * 32 + mi * 16 + li;
                ah[mi] = *(const bf16x8*)&As[row * 128 + ((ks * 64 + g * 16) ^ ((row & 7) << 4))];
            }
#pragma unroll
            for (int ni = 0; ni < 4; ++ni) {
                int col = wc * 64 + ni * 16 + li;
                int off = (ks * 64 + g * 16) ^ ((col & 7) << 4);
                bh[ni] = *(const bf16x8*)&Bs[col * 256 + off];
                bl[ni] = *(const bf16x8*)&Bs[col * 256 + 128 + off];
            }
#pragma unroll
            for (int mi = 0; mi < 2; ++mi)
#pragma unroll
                for (int ni = 0; ni < 4; ++ni) {
                    acc[mi][ni] = __builtin_amdgcn_mfma_f32_16x16x32_bf16(ah[mi], bh[ni], acc[mi][ni], 0, 0, 0);
                    acc[mi][ni] = __builtin_amdgcn_mfma_f32_16x16x32_bf16(ah[mi], bl[ni], acc[mi][ni], 0, 0, 0);
                }
        }
        __syncthreads();
    }

    if (EPI == 0) {
#pragma unroll
        for (int mi = 0; mi < 2; ++mi)
#pragma unroll
            for (int ni = 0; ni < 4; ++ni) {
                int col = n0 + wc * 64 + ni * 16 + li;
#pragma unroll
                for (int r = 0; r < 4; ++r) {
                    int row = m0 + wr * 32 + mi * 16 + g * 4 + r;
                    C[(long long)row * ldc + col] = acc[mi][ni][r];
                }
            }
    } else {
        if (n0 < 768) {
#pragma unroll
            for (int mi = 0; mi < 2; ++mi)
#pragma unroll
                for (int ni = 0; ni < 4; ++ni) {
                    int col = n0 + wc * 64 + ni * 16 + li;
#pragma unroll
                    for (int r = 0; r < 4; ++r) {
                        int row = m0 + wr * 32 + mi * 16 + g * 4 + r;
                        u_buf[(long long)row * 768 + col] = silu_f(acc[mi][ni][r]);
                    }
                }
        } else if (n0 < 1536) {
            int bb = m0 >> 11;
            int llb = (m0 & 2047) + wr * 32 + g * 4;
#pragma unroll
            for (int mi = 0; mi < 2; ++mi) {
                int ll = llb + mi * 16;
#pragma unroll
                for (int ni = 0; ni < 4; ++ni) {
                    int cv = n0 + wc * 64 + ni * 16 + li - 768;
                    ushort* vb = vT + ((size_t)bb * 768 + cv) * 2048 + ll;
                    *(uint32*)(vb)     = pk2(silu_f(acc[mi][ni][0]), silu_f(acc[mi][ni][1]));
                    *(uint32*)(vb + 2) = pk2(silu_f(acc[mi][ni][2]), silu_f(acc[mi][ni][3]));
                }
            }
        } else {
#pragma unroll
            for (int mi = 0; mi < 2; ++mi)
#pragma unroll
                for (int ni = 0; ni < 4; ++ni) {
                    int qcol = n0 + wc * 64 + ni * 16 + li - 1536;
#pragma unroll
                    for (int r = 0; r < 4; ++r) {
                        int row = m0 + wr * 32 + mi * 16 + g * 4 + r;
                        qk[(size_t)row * 256 + qcol] = (ushort)bfr(acc[mi][ni][r]);
                    }
                }
        }
    }
}

// ---------------------------------------------------------------------------
// RoPE in place on bf16 qk buffer
// ---------------------------------------------------------------------------
__global__ __launch_bounds__(128) void rope_bf(ushort* __restrict__ qk,
                                               const float* __restrict__ pos)
{
    int row = blockIdx.x;
    int lpos = row & (L_ - 1);
    int t = threadIdx.x;
    int j = t & 63;
    int isK = t >> 6;
    ushort* base = qk + (size_t)row * 256 + isK * 128;
    float s = pos[lpos * 256 + j];
    float c = pos[lpos * 256 + 64 + j];
    float x1 = bf2f(base[j]);
    float x2 = bf2f(base[64 + j]);
    base[j]      = (ushort)bfr(x1 * c - x2 * s);
    base[64 + j] = (ushort)bfr(x2 * c + x1 * s);
}

// ---------------------------------------------------------------------------
// MFMA flash attention v14 = v13 with KVBLK 128 -> 256 (8 jt iterations,
// half the per-tile fixed costs). All swizzles identical in structure:
// K row stride 256B (256 rows now), P row stride 512B (same bank alignment,
// same (row&7)<<4 XOR). Grid 256, 512 thr (8 waves), no-max softmax.
// ---------------------------------------------------------------------------
__global__ __launch_bounds__(512) void fused_attn14(
    const float* __restrict__ u_buf, const ushort* __restrict__ qk,
    const ushort* __restrict__ vT, ushort* __restrict__ gated)
{
    __shared__ unsigned char KbB[256 * 256];   // K tile bf16 [256 keys][128 d], swizzled (64KB)
    __shared__ unsigned char PbB[64 * 512];    // P bf16 [64 rows][256 keys], swizzled (32KB)
    __shared__ float lred[2][64];

    const int t  = threadIdx.x;
    const int w  = t >> 6;
    const int l  = t & 63;
    const int g  = l >> 4;
    const int li = l & 15;

    const int b  = blockIdx.x & 7;
    const int qt = blockIdx.x >> 3;
    const long long rowQ0 = (long long)b * L_ + (long long)qt * 64;
    const long long rowB0 = (long long)b * L_;

    const int rtq = w >> 1;                    // QK row-tile 0..3
    const int ch  = w & 1;                     // key half (128 keys each)

    bf16x8 qf[4];
    {
        const ushort* qrow = qk + (rowQ0 + rtq * 16 + li) * 256;
#pragma unroll
        for (int ks = 0; ks < 4; ++ks)
            qf[ks] = *(const bf16x8*)&qrow[ks * 32 + g * 8];
    }

    float l_part[4] = {0.f, 0.f, 0.f, 0.f};

    f32x4 o[4][6];
#pragma unroll
    for (int rt = 0; rt < 4; ++rt)
#pragma unroll
        for (int ct = 0; ct < 6; ++ct)
            o[rt][ct] = (f32x4){0.f, 0.f, 0.f, 0.f};

    const ushort* vrow = vT + ((size_t)b * 768 + w * 96 + li) * 2048 + g * 8;

    // K staging: thread (kr=t>>4 in 0..31, c16) stages keys kr+32*i, i=0..7
    const int kr  = t >> 4;
    const int c16 = t & 15;
    const int ksw = (c16 * 16) ^ ((kr & 7) << 4);   // (kr+32i)&7 == kr&7

    const ushort* k0p = qk + (rowB0 + kr) * 256 + 128 + c16 * 8;
    uint4 kA = *(const uint4*)(k0p + (size_t)(0 * 32) * 256);
    uint4 kB = *(const uint4*)(k0p + (size_t)(1 * 32) * 256);
    uint4 kC = *(const uint4*)(k0p + (size_t)(2 * 32) * 256);
    uint4 kD = *(const uint4*)(k0p + (size_t)(3 * 32) * 256);
    uint4 kE = *(const uint4*)(k0p + (size_t)(4 * 32) * 256);
    uint4 kF = *(const uint4*)(k0p + (size_t)(5 * 32) * 256);
    uint4 kG = *(const uint4*)(k0p + (size_t)(6 * 32) * 256);
    uint4 kH = *(const uint4*)(k0p + (size_t)(7 * 32) * 256);

    union U16 { uint4 u; bf16x8 bv; };

    for (int jt = 0; jt < 8; ++jt) {
        // ---- publish staged K tile (256 keys) ----
        *(uint4*)&KbB[(kr + 0 * 32) * 256 + ksw] = kA;
        *(uint4*)&KbB[(kr + 1 * 32) * 256 + ksw] = kB;
        *(uint4*)&KbB[(kr + 2 * 32) * 256 + ksw] = kC;
        *(uint4*)&KbB[(kr + 3 * 32) * 256 + ksw] = kD;
        *(uint4*)&KbB[(kr + 4 * 32) * 256 + ksw] = kE;
        *(uint4*)&KbB[(kr + 5 * 32) * 256 + ksw] = kF;
        *(uint4*)&KbB[(kr + 6 * 32) * 256 + ksw] = kG;
        *(uint4*)&KbB[(kr + 7 * 32) * 256 + ksw] = kH;
        __syncthreads();   // (A) K ready

        if (jt + 1 < 8) {
            const ushort* kn = qk + (rowB0 + (jt + 1) * 256 + kr) * 256 + 128 + c16 * 8;
            kA = *(const uint4*)(kn + (size_t)(0 * 32) * 256);
            kB = *(const uint4*)(kn + (size_t)(1 * 32) * 256);
            kC = *(const uint4*)(kn + (size_t)(2 * 32) * 256);
            kD = *(const uint4*)(kn + (size_t)(3 * 32) * 256);
            kE = *(const uint4*)(kn + (size_t)(4 * 32) * 256);
            kF = *(const uint4*)(kn + (size_t)(5 * 32) * 256);
            kG = *(const uint4*)(kn + (size_t)(6 * 32) * 256);
            kH = *(const uint4*)(kn + (size_t)(7 * 32) * 256);
        }

        // ---- QK: 8 S-tiles (rows rtq*16.., keys ch*128 + ci*16..) + exp + Pb ----
#pragma unroll
        for (int ci = 0; ci < 8; ++ci) {
            const int ct = ch * 8 + ci;
            const int krow = ct * 16 + li;
            const int rs = (krow & 7) << 4;
            f32x4 s = {0.f, 0.f, 0.f, 0.f};
#pragma unroll
            for (int ks = 0; ks < 4; ++ks) {
                bf16x8 kf = *(const bf16x8*)&KbB[krow * 256 + ((ks * 64 + g * 16) ^ rs)];
                s = __builtin_amdgcn_mfma_f32_16x16x32_bf16(qf[ks], kf, s, 0, 0, 0);
            }
#pragma unroll
            for (int r = 0; r < 4; ++r) {
                float p = __expf(SCALE * s[r]);
                l_part[r] += p;
                const int prow = rtq * 16 + g * 4 + r;
                *(ushort*)&PbB[prow * 512 + (((ct * 16 + li) * 2) ^ ((prow & 7) << 4))]
                    = (ushort)bfr(p);
            }
        }
        __syncthreads();   // (C) Pb ready

        // ---- PV: ks-outer (8 slices of 32 keys); per ks: pa[4] + V[6], 24 MFMA ----
        const ushort* vj = vrow + jt * 256;
#pragma unroll
        for (int ks = 0; ks < 8; ++ks) {
            bf16x8 pa0 = *(const bf16x8*)&PbB[(0 * 16 + li) * 512 + ((ks * 64 + g * 16) ^ ((li & 7) << 4))];
            bf16x8 pa1 = *(const bf16x8*)&PbB[(1 * 16 + li) * 512 + ((ks * 64 + g * 16) ^ ((li & 7) << 4))];
            bf16x8 pa2 = *(const bf16x8*)&PbB[(2 * 16 + li) * 512 + ((ks * 64 + g * 16) ^ ((li & 7) << 4))];
            bf16x8 pa3 = *(const bf16x8*)&PbB[(3 * 16 + li) * 512 + ((ks * 64 + g * 16) ^ ((li & 7) << 4))];
            U16 vc0, vc1, vc2, vc3, vc4, vc5;
            vc0.u = *(const uint4*)(vj + (size_t)(0 * 16) * 2048 + ks * 32);
            vc1.u = *(const uint4*)(vj + (size_t)(1 * 16) * 2048 + ks * 32);
            vc2.u = *(const uint4*)(vj + (size_t)(2 * 16) * 2048 + ks * 32);
            vc3.u = *(const uint4*)(vj + (size_t)(3 * 16) * 2048 + ks * 32);
            vc4.u = *(const uint4*)(vj + (size_t)(4 * 16) * 2048 + ks * 32);
            vc5.u = *(const uint4*)(vj + (size_t)(5 * 16) * 2048 + ks * 32);
#define PV_CT(CT, VC) \
            o[0][CT] = __builtin_amdgcn_mfma_f32_16x16x32_bf16(pa0, VC.bv, o[0][CT], 0, 0, 0); \
            o[1][CT] = __builtin_amdgcn_mfma_f32_16x16x32_bf16(pa1, VC.bv, o[1][CT], 0, 0, 0); \
            o[2][CT] = __builtin_amdgcn_mfma_f32_16x16x32_bf16(pa2, VC.bv, o[2][CT], 0, 0, 0); \
            o[3][CT] = __builtin_amdgcn_mfma_f32_16x16x32_bf16(pa3, VC.bv, o[3][CT], 0, 0, 0);
            PV_CT(0, vc0)
            PV_CT(1, vc1)
            PV_CT(2, vc2)
            PV_CT(3, vc3)
            PV_CT(4, vc4)
            PV_CT(5, vc5)
#undef PV_CT
        }
        // staging(jt+1) only touches KbB: all waves passed (C) => QK reads done;
        // Pb writes of jt+1 happen after (A,jt+1), after all PV(jt) reads.
    }

#pragma unroll
    for (int r = 0; r < 4; ++r) {
#pragma unroll
        for (int off = 8; off >= 1; off >>= 1)
            l_part[r] += __shfl_xor(l_part[r], off);
    }
    if (li == 0) {
#pragma unroll
        for (int r = 0; r < 4; ++r)
            lred[ch][rtq * 16 + g * 4 + r] = l_part[r];
    }
    __syncthreads();

    // ---- finalize: /l, gate by u (read-only), write bf16 gated ----
#pragma unroll
    for (int rt = 0; rt < 4; ++rt) {
#pragma unroll
        for (int r = 0; r < 4; ++r) {
            const int row = rt * 16 + g * 4 + r;
            float inv = 1.0f / (lred[0][row] + lred[1][row]);
            const float* ub = u_buf + (rowQ0 + row) * 768;
            ushort* gb = gated + (rowQ0 + row) * 768;
#pragma unroll
            for (int ct = 0; ct < 6; ++ct) {
                int col = w * 96 + ct * 16 + li;
                gb[col] = (ushort)bfr(o[rt][ct][r] * inv * ub[col]);
            }
        }
    }
}

extern "C" void kernel_launch(void* const* d_in, const int* in_sizes, int n_in,
                              void* d_out, int out_size, void* d_ws, size_t ws_size,
                              hipStream_t stream)
{
    const float* x    = (const float*)d_in[0];   // [8,2048,384]
    const float* pos  = (const float*)d_in[1];   // [1,2048,256]
    const float* Wuv  = (const float*)d_in[2];   // [384,1792]
    const float* Wout = (const float*)d_in[3];   // [768,384]
    float* out = (float*)d_out;                  // [8,2048,384] f32

    float*  u_buf = (float*)d_ws;                        // 16384*768 f32
    ushort* qk    = (ushort*)(u_buf + (size_t)R_ * HID); // 16384*256 bf16
    ushort* vT    = qk + (size_t)R_ * 256;               // 8*768*2048 bf16
    ushort* WuvThi  = vT + (size_t)B_ * HID * L_;
    ushort* WuvTlo  = WuvThi + (size_t)NUV * D2;
    ushort* WoutThi = WuvTlo + (size_t)NUV * D2;
    ushort* WoutTlo = WoutThi + (size_t)D2 * HID;
    ushort* gated   = WoutTlo + (size_t)D2 * HID;        // 16384*768 bf16
    ushort* xhi     = gated;                             // alias (dead after gemm1)

    size_t need = ((size_t)R_ * HID) * 4 +
                  ((size_t)R_ * 256 + (size_t)B_ * HID * L_ +
                   2 * (size_t)NUV * D2 + 2 * (size_t)D2 * HID +
                   (size_t)R_ * HID) * 2;                // 113.0 MB
    if (ws_size < need) return;

    conv_w<<<dim3((D2 * NUV + 255) / 256), dim3(256), 0, stream>>>(Wuv, WuvThi, WuvTlo, D2, NUV);
    conv_w<<<dim3((HID * D2 + 255) / 256), dim3(256), 0, stream>>>(Wout, WoutThi, WoutTlo, HID, D2);
    conv_x<<<dim3((R_ * D2 + 255) / 256), dim3(256), 0, stream>>>(x, xhi, R_ * D2);

    gemm_2p<1><<<dim3(NUV / 128, R_ / 128), dim3(512), 0, stream>>>(
        xhi, D2, WuvThi, WuvTlo, D2, nullptr, 0, u_buf, qk, vT, D2);

    rope_bf<<<dim3(R_), dim3(128), 0, stream>>>(qk, pos);

    fused_attn14<<<dim3(256), dim3(512), 0, stream>>>(u_buf, qk, vT, gated);

    gemm_2p<0><<<dim3(D2 / 128, R_ / 128), dim3(512), 0, stream>>>(
        gated, HID, WoutThi, WoutTlo, HID, out, D2, nullptr, nullptr, nullptr, HID);
}

// Round 19
// 232.889 us; speedup vs baseline: 1.1541x; 1.1541x over previous
//
#include <hip/hip_runtime.h>
#include <hip/hip_bf16.h>
#include <math.h>

#define B_    8
#define L_    2048
#define HID   768
#define D2    384
#define NUV   1792
#define R_    16384
#define SCALE 0.08838834764831845f  // 128^-0.5

typedef __attribute__((ext_vector_type(8))) short bf16x8;
typedef __attribute__((ext_vector_type(4))) float f32x4;
typedef unsigned int uint32;
typedef unsigned short ushort;

static __device__ __forceinline__ uint32 bfr(float x) {
    uint32 u = __float_as_uint(x);
    return (u + 0x7FFFu + ((u >> 16) & 1u)) >> 16;
}
static __device__ __forceinline__ uint32 pk2(float lo, float hi) {
    return bfr(lo) | (bfr(hi) << 16);
}
static __device__ __forceinline__ float bf2f(ushort u) {
    return __uint_as_float(((uint32)u) << 16);
}
static __device__ __forceinline__ float silu_f(float x) { return x / (1.0f + __expf(-x)); }

// ---------------------------------------------------------------------------
// Fused pre-transform, one launch:
//   range 0: Wuv  -> WuvThi/WuvTlo   [n][k] transposed hi/lo split (688128 el)
//   range 1: Wout -> WoutThi/WoutTlo (294912 el)
//   range 2: x    -> xhi  (vectorized float4 -> 8xbf16, 6291456 el / 4)
// ---------------------------------------------------------------------------
__global__ __launch_bounds__(256) void conv_all(
    const float* __restrict__ Wuv, ushort* __restrict__ WuvThi, ushort* __restrict__ WuvTlo,
    const float* __restrict__ Wout, ushort* __restrict__ WoutThi, ushort* __restrict__ WoutTlo,
    const float* __restrict__ X, ushort* __restrict__ Xhi)
{
    const int N1 = D2 * NUV;        // 688128
    const int N2 = HID * D2;        // 294912
    const int N3 = (R_ * D2) / 4;   // 1572864 float4 groups
    int idx = blockIdx.x * 256 + threadIdx.x;

    if (idx < N1) {
        // Wuv transpose+split: Thi/Tlo[n][k], W is [K=D2][N=NUV]
        int n = idx / D2, k = idx - n * D2;
        float v = Wuv[(size_t)k * NUV + n];
        uint32 h = bfr(v);
        WuvThi[idx] = (ushort)h;
        WuvTlo[idx] = (ushort)bfr(v - __uint_as_float(h << 16));
        return;
    }
    idx -= N1;
    if (idx < N2) {
        // Wout transpose+split: Thi/Tlo[n][k], W is [K=HID][N=D2]
        int n = idx / HID, k = idx - n * HID;
        float v = Wout[(size_t)k * D2 + n];
        uint32 h = bfr(v);
        WoutThi[idx] = (ushort)h;
        WoutTlo[idx] = (ushort)bfr(v - __uint_as_float(h << 16));
        return;
    }
    idx -= N2;
    if (idx < N3) {
        float4 v = *(const float4*)(X + (size_t)idx * 4);
        uint2 p; p.x = pk2(v.x, v.y); p.y = pk2(v.z, v.w);
        *(uint2*)(Xhi + (size_t)idx * 4) = p;
    }
}

// ---------------------------------------------------------------------------
// Bf16-A 2-pass GEMM core: C_f32 = Abf16 @ (Bhi + Blo), copy staging.
// Block 512 thr (8 waves), tile 128x128, BK=64. LDS 48KB.
// EPI 0: plain f32 C.  EPI 1: GAU GEMM1 epilogue (u/v/qk by n0).
// ---------------------------------------------------------------------------
template<int EPI>
__global__ __launch_bounds__(512, 4) void gemm_2p(
    const ushort* __restrict__ Ahi, int lda,
    const ushort* __restrict__ BThi, const ushort* __restrict__ BTlo, int ldbt,
    float* __restrict__ C, int ldc,
    float* __restrict__ u_buf, ushort* __restrict__ qk, ushort* __restrict__ vT,
    int K)
{
    __shared__ unsigned char As[128 * 128];
    __shared__ unsigned char Bs[128 * 256];

    const int t  = threadIdx.x;
    const int w  = t >> 6;
    const int l  = t & 63;
    const int g  = l >> 4;
    const int li = l & 15;
    const int wr = w >> 1;
    const int wc = w & 1;
    const int m0 = blockIdx.y * 128;
    const int n0 = blockIdx.x * 128;

    f32x4 acc[2][4];
#pragma unroll
    for (int i = 0; i < 2; ++i)
#pragma unroll
        for (int j = 0; j < 4; ++j) acc[i][j] = (f32x4){0.f, 0.f, 0.f, 0.f};

    for (int k0 = 0; k0 < K; k0 += 64) {
#pragma unroll
        for (int i = 0; i < 2; ++i) {
            int idx = t + i * 512;
            int row = idx >> 3;
            int c8  = idx & 7;
            uint4 v = *(const uint4*)(Ahi + (size_t)(m0 + row) * lda + k0 + c8 * 8);
            *(uint4*)&As[row * 128 + ((c8 * 16) ^ ((row & 7) << 4))] = v;
        }
#pragma unroll
        for (int i = 0; i < 8; ++i) {
            int idx = t + i * 512;
            int c   = idx >> 5;
            int s8  = idx & 31;
            const ushort* src = (s8 < 16)
                ? (BThi + (long long)(n0 + c) * ldbt + k0 + s8 * 4)
                : (BTlo + (long long)(n0 + c) * ldbt + k0 + (s8 - 16) * 4);
            *(uint2*)&Bs[c * 256 + ((s8 * 8) ^ ((c & 7) << 4))] = *(const uint2*)src;
        }
        __syncthreads();

#pragma unroll
        for (int ks = 0; ks < 2; ++ks) {
            bf16x8 ah[2], bh[4], bl[4];
#pragma unroll
            for (int mi = 0; mi < 2; ++mi) {
                int row = wr * 32 + mi * 16 + li;
                ah[mi] = *(const bf16x8*)&As[row * 128 + ((ks * 64 + g * 16) ^ ((row & 7) << 4))];
            }
#pragma unroll
            for (int ni = 0; ni < 4; ++ni) {
                int col = wc * 64 + ni * 16 + li;
                int off = (ks * 64 + g * 16) ^ ((col & 7) << 4);
                bh[ni] = *(const bf16x8*)&Bs[col * 256 + off];
                bl[ni] = *(const bf16x8*)&Bs[col * 256 + 128 + off];
            }
#pragma unroll
            for (int mi = 0; mi < 2; ++mi)
#pragma unroll
                for (int ni = 0; ni < 4; ++ni) {
                    acc[mi][ni] = __builtin_amdgcn_mfma_f32_16x16x32_bf16(ah[mi], bh[ni], acc[mi][ni], 0, 0, 0);
                    acc[mi][ni] = __builtin_amdgcn_mfma_f32_16x16x32_bf16(ah[mi], bl[ni], acc[mi][ni], 0, 0, 0);
                }
        }
        __syncthreads();
    }

    if (EPI == 0) {
#pragma unroll
        for (int mi = 0; mi < 2; ++mi)
#pragma unroll
            for (int ni = 0; ni < 4; ++ni) {
                int col = n0 + wc * 64 + ni * 16 + li;
#pragma unroll
                for (int r = 0; r < 4; ++r) {
                    int row = m0 + wr * 32 + mi * 16 + g * 4 + r;
                    C[(long long)row * ldc + col] = acc[mi][ni][r];
                }
            }
    } else {
        if (n0 < 768) {
#pragma unroll
            for (int mi = 0; mi < 2; ++mi)
#pragma unroll
                for (int ni = 0; ni < 4; ++ni) {
                    int col = n0 + wc * 64 + ni * 16 + li;
#pragma unroll
                    for (int r = 0; r < 4; ++r) {
                        int row = m0 + wr * 32 + mi * 16 + g * 4 + r;
                        u_buf[(long long)row * 768 + col] = silu_f(acc[mi][ni][r]);
                    }
                }
        } else if (n0 < 1536) {
            int bb = m0 >> 11;
            int llb = (m0 & 2047) + wr * 32 + g * 4;
#pragma unroll
            for (int mi = 0; mi < 2; ++mi) {
                int ll = llb + mi * 16;
#pragma unroll
                for (int ni = 0; ni < 4; ++ni) {
                    int cv = n0 + wc * 64 + ni * 16 + li - 768;
                    ushort* vb = vT + ((size_t)bb * 768 + cv) * 2048 + ll;
                    *(uint32*)(vb)     = pk2(silu_f(acc[mi][ni][0]), silu_f(acc[mi][ni][1]));
                    *(uint32*)(vb + 2) = pk2(silu_f(acc[mi][ni][2]), silu_f(acc[mi][ni][3]));
                }
            }
        } else {
#pragma unroll
            for (int mi = 0; mi < 2; ++mi)
#pragma unroll
                for (int ni = 0; ni < 4; ++ni) {
                    int qcol = n0 + wc * 64 + ni * 16 + li - 1536;
#pragma unroll
                    for (int r = 0; r < 4; ++r) {
                        int row = m0 + wr * 32 + mi * 16 + g * 4 + r;
                        qk[(size_t)row * 256 + qcol] = (ushort)bfr(acc[mi][ni][r]);
                    }
                }
        }
    }
}

// ---------------------------------------------------------------------------
// RoPE in place on bf16 qk buffer
// ---------------------------------------------------------------------------
__global__ __launch_bounds__(128) void rope_bf(ushort* __restrict__ qk,
                                               const float* __restrict__ pos)
{
    int row = blockIdx.x;
    int lpos = row & (L_ - 1);
    int t = threadIdx.x;
    int j = t & 63;
    int isK = t >> 6;
    ushort* base = qk + (size_t)row * 256 + isK * 128;
    float s = pos[lpos * 256 + j];
    float c = pos[lpos * 256 + 64 + j];
    float x1 = bf2f(base[j]);
    float x2 = bf2f(base[64 + j]);
    base[j]      = (ushort)bfr(x1 * c - x2 * s);
    base[64 + j] = (ushort)bfr(x2 * c + x1 * s);
}

// ---------------------------------------------------------------------------
// MFMA flash attention v13 (r17-verified best): QBLK=64, KVBLK=128,
// no-max softmax, 2 barriers/tile, gate by u -> bf16 `gated`.
// Grid 256, 512 thr (8 waves).
// ---------------------------------------------------------------------------
__global__ __launch_bounds__(512) void fused_attn13(
    const float* __restrict__ u_buf, const ushort* __restrict__ qk,
    const ushort* __restrict__ vT, ushort* __restrict__ gated)
{
    __shared__ unsigned char KbB[128 * 256];
    __shared__ unsigned char PbB[64 * 256];
    __shared__ float lred[2][64];

    const int t  = threadIdx.x;
    const int w  = t >> 6;
    const int l  = t & 63;
    const int g  = l >> 4;
    const int li = l & 15;

    const int b  = blockIdx.x & 7;
    const int qt = blockIdx.x >> 3;
    const long long rowQ0 = (long long)b * L_ + (long long)qt * 64;
    const long long rowB0 = (long long)b * L_;

    const int rtq = w >> 1;
    const int ch  = w & 1;

    bf16x8 qf[4];
    {
        const ushort* qrow = qk + (rowQ0 + rtq * 16 + li) * 256;
#pragma unroll
        for (int ks = 0; ks < 4; ++ks)
            qf[ks] = *(const bf16x8*)&qrow[ks * 32 + g * 8];
    }

    float l_part[4] = {0.f, 0.f, 0.f, 0.f};

    f32x4 o[4][6];
#pragma unroll
    for (int rt = 0; rt < 4; ++rt)
#pragma unroll
        for (int ct = 0; ct < 6; ++ct)
            o[rt][ct] = (f32x4){0.f, 0.f, 0.f, 0.f};

    const ushort* vrow = vT + ((size_t)b * 768 + w * 96 + li) * 2048 + g * 8;

    const int kr  = t >> 4;
    const int c16 = t & 15;
    const int ksw = (c16 * 16) ^ ((kr & 7) << 4);

    uint4 kA = *(const uint4*)&qk[(rowB0 + kr)      * 256 + 128 + c16 * 8];
    uint4 kB = *(const uint4*)&qk[(rowB0 + kr + 32) * 256 + 128 + c16 * 8];
    uint4 kC = *(const uint4*)&qk[(rowB0 + kr + 64) * 256 + 128 + c16 * 8];
    uint4 kD = *(const uint4*)&qk[(rowB0 + kr + 96) * 256 + 128 + c16 * 8];

    union U16 { uint4 u; bf16x8 bv; };

    for (int jt = 0; jt < 16; ++jt) {
        *(uint4*)&KbB[(kr)      * 256 + ksw] = kA;
        *(uint4*)&KbB[(kr + 32) * 256 + ksw] = kB;
        *(uint4*)&KbB[(kr + 64) * 256 + ksw] = kC;
        *(uint4*)&KbB[(kr + 96) * 256 + ksw] = kD;
        __syncthreads();   // (A)

        if (jt + 1 < 16) {
            const ushort* kn = qk + (rowB0 + (jt + 1) * 128) * 256 + 128 + c16 * 8;
            kA = *(const uint4*)(kn + (size_t)(kr)      * 256);
            kB = *(const uint4*)(kn + (size_t)(kr + 32) * 256);
            kC = *(const uint4*)(kn + (size_t)(kr + 64) * 256);
            kD = *(const uint4*)(kn + (size_t)(kr + 96) * 256);
        }

#pragma unroll
        for (int ci = 0; ci < 4; ++ci) {
            const int ct = ch * 4 + ci;
            const int krow = ct * 16 + li;
            const int rs = (krow & 7) << 4;
            f32x4 s = {0.f, 0.f, 0.f, 0.f};
#pragma unroll
            for (int ks = 0; ks < 4; ++ks) {
                bf16x8 kf = *(const bf16x8*)&KbB[krow * 256 + ((ks * 64 + g * 16) ^ rs)];
                s = __builtin_amdgcn_mfma_f32_16x16x32_bf16(qf[ks], kf, s, 0, 0, 0);
            }
#pragma unroll
            for (int r = 0; r < 4; ++r) {
                float p = __expf(SCALE * s[r]);
                l_part[r] += p;
                const int prow = rtq * 16 + g * 4 + r;
                *(ushort*)&PbB[prow * 256 + (((ct * 16 + li) * 2) ^ ((prow & 7) << 4))]
                    = (ushort)bfr(p);
            }
        }
        __syncthreads();   // (C)

        const ushort* vj = vrow + jt * 128;
#pragma unroll
        for (int ks = 0; ks < 4; ++ks) {
            bf16x8 pa0 = *(const bf16x8*)&PbB[(0 * 16 + li) * 256 + ((ks * 64 + g * 16) ^ ((li & 7) << 4))];
            bf16x8 pa1 = *(const bf16x8*)&PbB[(1 * 16 + li) * 256 + ((ks * 64 + g * 16) ^ ((li & 7) << 4))];
            bf16x8 pa2 = *(const bf16x8*)&PbB[(2 * 16 + li) * 256 + ((ks * 64 + g * 16) ^ ((li & 7) << 4))];
            bf16x8 pa3 = *(const bf16x8*)&PbB[(3 * 16 + li) * 256 + ((ks * 64 + g * 16) ^ ((li & 7) << 4))];
            U16 vc0, vc1, vc2, vc3, vc4, vc5;
            vc0.u = *(const uint4*)(vj + (size_t)(0 * 16) * 2048 + ks * 32);
            vc1.u = *(const uint4*)(vj + (size_t)(1 * 16) * 2048 + ks * 32);
            vc2.u = *(const uint4*)(vj + (size_t)(2 * 16) * 2048 + ks * 32);
            vc3.u = *(const uint4*)(vj + (size_t)(3 * 16) * 2048 + ks * 32);
            vc4.u = *(const uint4*)(vj + (size_t)(4 * 16) * 2048 + ks * 32);
            vc5.u = *(const uint4*)(vj + (size_t)(5 * 16) * 2048 + ks * 32);
#define PV_CT(CT, VC) \
            o[0][CT] = __builtin_amdgcn_mfma_f32_16x16x32_bf16(pa0, VC.bv, o[0][CT], 0, 0, 0); \
            o[1][CT] = __builtin_amdgcn_mfma_f32_16x16x32_bf16(pa1, VC.bv, o[1][CT], 0, 0, 0); \
            o[2][CT] = __builtin_amdgcn_mfma_f32_16x16x32_bf16(pa2, VC.bv, o[2][CT], 0, 0, 0); \
            o[3][CT] = __builtin_amdgcn_mfma_f32_16x16x32_bf16(pa3, VC.bv, o[3][CT], 0, 0, 0);
            PV_CT(0, vc0)
            PV_CT(1, vc1)
            PV_CT(2, vc2)
            PV_CT(3, vc3)
            PV_CT(4, vc4)
            PV_CT(5, vc5)
#undef PV_CT
        }
    }

#pragma unroll
    for (int r = 0; r < 4; ++r) {
#pragma unroll
        for (int off = 8; off >= 1; off >>= 1)
            l_part[r] += __shfl_xor(l_part[r], off);
    }
    if (li == 0) {
#pragma unroll
        for (int r = 0; r < 4; ++r)
            lred[ch][rtq * 16 + g * 4 + r] = l_part[r];
    }
    __syncthreads();

#pragma unroll
    for (int rt = 0; rt < 4; ++rt) {
#pragma unroll
        for (int r = 0; r < 4; ++r) {
            const int row = rt * 16 + g * 4 + r;
            float inv = 1.0f / (lred[0][row] + lred[1][row]);
            const float* ub = u_buf + (rowQ0 + row) * 768;
            ushort* gb = gated + (rowQ0 + row) * 768;
#pragma unroll
            for (int ct = 0; ct < 6; ++ct) {
                int col = w * 96 + ct * 16 + li;
                gb[col] = (ushort)bfr(o[rt][ct][r] * inv * ub[col]);
            }
        }
    }
}

extern "C" void kernel_launch(void* const* d_in, const int* in_sizes, int n_in,
                              void* d_out, int out_size, void* d_ws, size_t ws_size,
                              hipStream_t stream)
{
    const float* x    = (const float*)d_in[0];   // [8,2048,384]
    const float* pos  = (const float*)d_in[1];   // [1,2048,256]
    const float* Wuv  = (const float*)d_in[2];   // [384,1792]
    const float* Wout = (const float*)d_in[3];   // [768,384]
    float* out = (float*)d_out;                  // [8,2048,384] f32

    float*  u_buf = (float*)d_ws;                        // 16384*768 f32
    ushort* qk    = (ushort*)(u_buf + (size_t)R_ * HID); // 16384*256 bf16
    ushort* vT    = qk + (size_t)R_ * 256;               // 8*768*2048 bf16
    ushort* WuvThi  = vT + (size_t)B_ * HID * L_;
    ushort* WuvTlo  = WuvThi + (size_t)NUV * D2;
    ushort* WoutThi = WuvTlo + (size_t)NUV * D2;
    ushort* WoutTlo = WoutThi + (size_t)D2 * HID;
    ushort* gated   = WoutTlo + (size_t)D2 * HID;        // 16384*768 bf16
    ushort* xhi     = gated;                             // alias (dead after gemm1)

    size_t need = ((size_t)R_ * HID) * 4 +
                  ((size_t)R_ * 256 + (size_t)B_ * HID * L_ +
                   2 * (size_t)NUV * D2 + 2 * (size_t)D2 * HID +
                   (size_t)R_ * HID) * 2;                // 113.0 MB
    if (ws_size < need) return;

    // fused pre-transform (1 launch): Wuv split, Wout split, x -> bf16
    {
        int total = D2 * NUV + HID * D2 + (R_ * D2) / 4;
        conv_all<<<dim3((total + 255) / 256), dim3(256), 0, stream>>>(
            Wuv, WuvThi, WuvTlo, Wout, WoutThi, WoutTlo, x, xhi);
    }

    gemm_2p<1><<<dim3(NUV / 128, R_ / 128), dim3(512), 0, stream>>>(
        xhi, D2, WuvThi, WuvTlo, D2, nullptr, 0, u_buf, qk, vT, D2);

    rope_bf<<<dim3(R_), dim3(128), 0, stream>>>(qk, pos);

    fused_attn13<<<dim3(256), dim3(512), 0, stream>>>(u_buf, qk, vT, gated);

    gemm_2p<0><<<dim3(D2 / 128, R_ / 128), dim3(512), 0, stream>>>(
        gated, HID, WoutThi, WoutTlo, HID, out, D2, nullptr, nullptr, nullptr, HID);
}

// Round 20
// 229.199 us; speedup vs baseline: 1.1726x; 1.0161x over previous
//
#include <hip/hip_runtime.h>
#include <hip/hip_bf16.h>
#include <math.h>

#define B_    8
#define L_    2048
#define HID   768
#define D2    384
#define NUV   1792
#define R_    16384
#define SCALE 0.08838834764831845f  // 128^-0.5

typedef __attribute__((ext_vector_type(8))) short bf16x8;
typedef __attribute__((ext_vector_type(4))) float f32x4;
typedef unsigned int uint32;
typedef unsigned short ushort;

static __device__ __forceinline__ uint32 bfr(float x) {
    uint32 u = __float_as_uint(x);
    return (u + 0x7FFFu + ((u >> 16) & 1u)) >> 16;
}
static __device__ __forceinline__ uint32 pk2(float lo, float hi) {
    return bfr(lo) | (bfr(hi) << 16);
}
static __device__ __forceinline__ float bf2f(ushort u) {
    return __uint_as_float(((uint32)u) << 16);
}
static __device__ __forceinline__ float silu_f(float x) { return x / (1.0f + __expf(-x)); }

// ---------------------------------------------------------------------------
// Fused pre-transform, one launch (r19-verified):
//   Wuv -> WuvThi/WuvTlo, Wout -> WoutThi/WoutTlo, x -> xhi (float4 vectorized)
// ---------------------------------------------------------------------------
__global__ __launch_bounds__(256) void conv_all(
    const float* __restrict__ Wuv, ushort* __restrict__ WuvThi, ushort* __restrict__ WuvTlo,
    const float* __restrict__ Wout, ushort* __restrict__ WoutThi, ushort* __restrict__ WoutTlo,
    const float* __restrict__ X, ushort* __restrict__ Xhi)
{
    const int N1 = D2 * NUV;
    const int N2 = HID * D2;
    const int N3 = (R_ * D2) / 4;
    int idx = blockIdx.x * 256 + threadIdx.x;

    if (idx < N1) {
        int n = idx / D2, k = idx - n * D2;
        float v = Wuv[(size_t)k * NUV + n];
        uint32 h = bfr(v);
        WuvThi[idx] = (ushort)h;
        WuvTlo[idx] = (ushort)bfr(v - __uint_as_float(h << 16));
        return;
    }
    idx -= N1;
    if (idx < N2) {
        int n = idx / HID, k = idx - n * HID;
        float v = Wout[(size_t)k * D2 + n];
        uint32 h = bfr(v);
        WoutThi[idx] = (ushort)h;
        WoutTlo[idx] = (ushort)bfr(v - __uint_as_float(h << 16));
        return;
    }
    idx -= N2;
    if (idx < N3) {
        float4 v = *(const float4*)(X + (size_t)idx * 4);
        uint2 p; p.x = pk2(v.x, v.y); p.y = pk2(v.z, v.w);
        *(uint2*)(Xhi + (size_t)idx * 4) = p;
    }
}

// ---------------------------------------------------------------------------
// Bf16-A 2-pass GEMM core (r17-verified): C_f32 = Abf16 @ (Bhi + Blo).
// EPI 0: plain f32 C.  EPI 1: GAU GEMM1 epilogue.
// ---------------------------------------------------------------------------
template<int EPI>
__global__ __launch_bounds__(512, 4) void gemm_2p(
    const ushort* __restrict__ Ahi, int lda,
    const ushort* __restrict__ BThi, const ushort* __restrict__ BTlo, int ldbt,
    float* __restrict__ C, int ldc,
    float* __restrict__ u_buf, ushort* __restrict__ qk, ushort* __restrict__ vT,
    int K)
{
    __shared__ unsigned char As[128 * 128];
    __shared__ unsigned char Bs[128 * 256];

    const int t  = threadIdx.x;
    const int w  = t >> 6;
    const int l  = t & 63;
    const int g  = l >> 4;
    const int li = l & 15;
    const int wr = w >> 1;
    const int wc = w & 1;
    const int m0 = blockIdx.y * 128;
    const int n0 = blockIdx.x * 128;

    f32x4 acc[2][4];
#pragma unroll
    for (int i = 0; i < 2; ++i)
#pragma unroll
        for (int j = 0; j < 4; ++j) acc[i][j] = (f32x4){0.f, 0.f, 0.f, 0.f};

    for (int k0 = 0; k0 < K; k0 += 64) {
#pragma unroll
        for (int i = 0; i < 2; ++i) {
            int idx = t + i * 512;
            int row = idx >> 3;
            int c8  = idx & 7;
            uint4 v = *(const uint4*)(Ahi + (size_t)(m0 + row) * lda + k0 + c8 * 8);
            *(uint4*)&As[row * 128 + ((c8 * 16) ^ ((row & 7) << 4))] = v;
        }
#pragma unroll
        for (int i = 0; i < 8; ++i) {
            int idx = t + i * 512;
            int c   = idx >> 5;
            int s8  = idx & 31;
            const ushort* src = (s8 < 16)
                ? (BThi + (long long)(n0 + c) * ldbt + k0 + s8 * 4)
                : (BTlo + (long long)(n0 + c) * ldbt + k0 + (s8 - 16) * 4);
            *(uint2*)&Bs[c * 256 + ((s8 * 8) ^ ((c & 7) << 4))] = *(const uint2*)src;
        }
        __syncthreads();

#pragma unroll
        for (int ks = 0; ks < 2; ++ks) {
            bf16x8 ah[2], bh[4], bl[4];
#pragma unroll
            for (int mi = 0; mi < 2; ++mi) {
                int row = wr * 32 + mi * 16 + li;
                ah[mi] = *(const bf16x8*)&As[row * 128 + ((ks * 64 + g * 16) ^ ((row & 7) << 4))];
            }
#pragma unroll
            for (int ni = 0; ni < 4; ++ni) {
                int col = wc * 64 + ni * 16 + li;
                int off = (ks * 64 + g * 16) ^ ((col & 7) << 4);
                bh[ni] = *(const bf16x8*)&Bs[col * 256 + off];
                bl[ni] = *(const bf16x8*)&Bs[col * 256 + 128 + off];
            }
#pragma unroll
            for (int mi = 0; mi < 2; ++mi)
#pragma unroll
                for (int ni = 0; ni < 4; ++ni) {
                    acc[mi][ni] = __builtin_amdgcn_mfma_f32_16x16x32_bf16(ah[mi], bh[ni], acc[mi][ni], 0, 0, 0);
                    acc[mi][ni] = __builtin_amdgcn_mfma_f32_16x16x32_bf16(ah[mi], bl[ni], acc[mi][ni], 0, 0, 0);
                }
        }
        __syncthreads();
    }

    if (EPI == 0) {
#pragma unroll
        for (int mi = 0; mi < 2; ++mi)
#pragma unroll
            for (int ni = 0; ni < 4; ++ni) {
                int col = n0 + wc * 64 + ni * 16 + li;
#pragma unroll
                for (int r = 0; r < 4; ++r) {
                    int row = m0 + wr * 32 + mi * 16 + g * 4 + r;
                    C[(long long)row * ldc + col] = acc[mi][ni][r];
                }
            }
    } else {
        if (n0 < 768) {
#pragma unroll
            for (int mi = 0; mi < 2; ++mi)
#pragma unroll
                for (int ni = 0; ni < 4; ++ni) {
                    int col = n0 + wc * 64 + ni * 16 + li;
#pragma unroll
                    for (int r = 0; r < 4; ++r) {
                        int row = m0 + wr * 32 + mi * 16 + g * 4 + r;
                        u_buf[(long long)row * 768 + col] = silu_f(acc[mi][ni][r]);
                    }
                }
        } else if (n0 < 1536) {
            int bb = m0 >> 11;
            int llb = (m0 & 2047) + wr * 32 + g * 4;
#pragma unroll
            for (int mi = 0; mi < 2; ++mi) {
                int ll = llb + mi * 16;
#pragma unroll
                for (int ni = 0; ni < 4; ++ni) {
                    int cv = n0 + wc * 64 + ni * 16 + li - 768;
                    ushort* vb = vT + ((size_t)bb * 768 + cv) * 2048 + ll;
                    *(uint32*)(vb)     = pk2(silu_f(acc[mi][ni][0]), silu_f(acc[mi][ni][1]));
                    *(uint32*)(vb + 2) = pk2(silu_f(acc[mi][ni][2]), silu_f(acc[mi][ni][3]));
                }
            }
        } else {
#pragma unroll
            for (int mi = 0; mi < 2; ++mi)
#pragma unroll
                for (int ni = 0; ni < 4; ++ni) {
                    int qcol = n0 + wc * 64 + ni * 16 + li - 1536;
#pragma unroll
                    for (int r = 0; r < 4; ++r) {
                        int row = m0 + wr * 32 + mi * 16 + g * 4 + r;
                        qk[(size_t)row * 256 + qcol] = (ushort)bfr(acc[mi][ni][r]);
                    }
                }
        }
    }
}

// ---------------------------------------------------------------------------
// RoPE in place on bf16 qk buffer
// ---------------------------------------------------------------------------
__global__ __launch_bounds__(128) void rope_bf(ushort* __restrict__ qk,
                                               const float* __restrict__ pos)
{
    int row = blockIdx.x;
    int lpos = row & (L_ - 1);
    int t = threadIdx.x;
    int j = t & 63;
    int isK = t >> 6;
    ushort* base = qk + (size_t)row * 256 + isK * 128;
    float s = pos[lpos * 256 + j];
    float c = pos[lpos * 256 + 64 + j];
    float x1 = bf2f(base[j]);
    float x2 = bf2f(base[64 + j]);
    base[j]      = (ushort)bfr(x1 * c - x2 * s);
    base[64 + j] = (ushort)bfr(x2 * c + x1 * s);
}

// ---------------------------------------------------------------------------
// MFMA flash attention v15 = v13 with double-buffered K and P LDS and ONE
// barrier per tile (publish K(jt+1) before the barrier; PV after), plus
// s_setprio(1) around MFMA clusters. QBLK=64, KVBLK=128, no-max softmax.
// Grid 256, 512 thr (8 waves). LDS 96.5 KB -> 1 block/CU (same as v13).
// Race audit (collective-barrier induction):
//   - QK(jt-1) reads of Kb[(jt+1)&1] all complete before barrier(jt-1),
//     which precedes publish K(jt+1) in iter jt. safe.
//   - PV(jt) reads Pb[jt&1]; QK(jt+1) writes Pb[(jt+1)&1]. disjoint.
//   - PV(jt-2) reads of Pb[jt&1] complete before barrier(jt-1) (program
//     order: PV(jt-2) precedes iter jt-1's barrier). safe.
// ---------------------------------------------------------------------------
__global__ __launch_bounds__(512) void fused_attn15(
    const float* __restrict__ u_buf, const ushort* __restrict__ qk,
    const ushort* __restrict__ vT, ushort* __restrict__ gated)
{
    __shared__ unsigned char KbB[2][128 * 256];   // K bf16 dbuf (64 KB)
    __shared__ unsigned char PbB[2][64 * 256];    // P bf16 dbuf (32 KB)
    __shared__ float lred[2][64];

    const int t  = threadIdx.x;
    const int w  = t >> 6;
    const int l  = t & 63;
    const int g  = l >> 4;
    const int li = l & 15;

    const int b  = blockIdx.x & 7;
    const int qt = blockIdx.x >> 3;
    const long long rowQ0 = (long long)b * L_ + (long long)qt * 64;
    const long long rowB0 = (long long)b * L_;

    const int rtq = w >> 1;
    const int ch  = w & 1;

    bf16x8 qf[4];
    {
        const ushort* qrow = qk + (rowQ0 + rtq * 16 + li) * 256;
#pragma unroll
        for (int ks = 0; ks < 4; ++ks)
            qf[ks] = *(const bf16x8*)&qrow[ks * 32 + g * 8];
    }

    float l_part[4] = {0.f, 0.f, 0.f, 0.f};

    f32x4 o[4][6];
#pragma unroll
    for (int rt = 0; rt < 4; ++rt)
#pragma unroll
        for (int ct = 0; ct < 6; ++ct)
            o[rt][ct] = (f32x4){0.f, 0.f, 0.f, 0.f};

    const ushort* vrow = vT + ((size_t)b * 768 + w * 96 + li) * 2048 + g * 8;

    const int kr  = t >> 4;
    const int c16 = t & 15;
    const int ksw = (c16 * 16) ^ ((kr & 7) << 4);

    union U16 { uint4 u; bf16x8 bv; };

    // ---- prologue: prefetch K(0), publish into Kb[0], barrier, prefetch K(1)
    uint4 kA = *(const uint4*)&qk[(rowB0 + kr)      * 256 + 128 + c16 * 8];
    uint4 kB = *(const uint4*)&qk[(rowB0 + kr + 32) * 256 + 128 + c16 * 8];
    uint4 kC = *(const uint4*)&qk[(rowB0 + kr + 64) * 256 + 128 + c16 * 8];
    uint4 kD = *(const uint4*)&qk[(rowB0 + kr + 96) * 256 + 128 + c16 * 8];
    *(uint4*)&KbB[0][(kr)      * 256 + ksw] = kA;
    *(uint4*)&KbB[0][(kr + 32) * 256 + ksw] = kB;
    *(uint4*)&KbB[0][(kr + 64) * 256 + ksw] = kC;
    *(uint4*)&KbB[0][(kr + 96) * 256 + ksw] = kD;
    __syncthreads();
    {
        const ushort* kn = qk + (rowB0 + 128 + kr) * 256 + 128 + c16 * 8;
        kA = *(const uint4*)(kn);
        kB = *(const uint4*)(kn + (size_t)32 * 256);
        kC = *(const uint4*)(kn + (size_t)64 * 256);
        kD = *(const uint4*)(kn + (size_t)96 * 256);
    }

    for (int jt = 0; jt < 16; ++jt) {
        const unsigned char* Kb = &KbB[jt & 1][0];
        unsigned char* Pb = &PbB[jt & 1][0];

        // ---- QK: 4 S-tiles + exp + Pb write + l accumulation ----
        __builtin_amdgcn_s_setprio(1);
#pragma unroll
        for (int ci = 0; ci < 4; ++ci) {
            const int ct = ch * 4 + ci;
            const int krow = ct * 16 + li;
            const int rs = (krow & 7) << 4;
            f32x4 s = {0.f, 0.f, 0.f, 0.f};
#pragma unroll
            for (int ks = 0; ks < 4; ++ks) {
                bf16x8 kf = *(const bf16x8*)&Kb[krow * 256 + ((ks * 64 + g * 16) ^ rs)];
                s = __builtin_amdgcn_mfma_f32_16x16x32_bf16(qf[ks], kf, s, 0, 0, 0);
            }
#pragma unroll
            for (int r = 0; r < 4; ++r) {
                float p = __expf(SCALE * s[r]);
                l_part[r] += p;
                const int prow = rtq * 16 + g * 4 + r;
                *(ushort*)&Pb[prow * 256 + (((ct * 16 + li) * 2) ^ ((prow & 7) << 4))]
                    = (ushort)bfr(p);
            }
        }
        __builtin_amdgcn_s_setprio(0);

        // ---- publish K(jt+1) into the other buffer (before the barrier) ----
        if (jt + 1 < 16) {
            unsigned char* Kn = &KbB[(jt + 1) & 1][0];
            *(uint4*)&Kn[(kr)      * 256 + ksw] = kA;
            *(uint4*)&Kn[(kr + 32) * 256 + ksw] = kB;
            *(uint4*)&Kn[(kr + 64) * 256 + ksw] = kC;
            *(uint4*)&Kn[(kr + 96) * 256 + ksw] = kD;
        }

        __syncthreads();   // single barrier: Pb(jt) ready AND K(jt+1) visible

        // ---- prefetch K(jt+2) (drains at NEXT barrier, one full iter later) ----
        if (jt + 2 < 16) {
            const ushort* kn = qk + (rowB0 + (jt + 2) * 128 + kr) * 256 + 128 + c16 * 8;
            kA = *(const uint4*)(kn);
            kB = *(const uint4*)(kn + (size_t)32 * 256);
            kC = *(const uint4*)(kn + (size_t)64 * 256);
            kD = *(const uint4*)(kn + (size_t)96 * 256);
        }

        // ---- PV: ks-outer; per ks: pa[4] + V[6], 24 MFMA ----
        const ushort* vj = vrow + jt * 128;
#pragma unroll
        for (int ks = 0; ks < 4; ++ks) {
            bf16x8 pa0 = *(const bf16x8*)&Pb[(0 * 16 + li) * 256 + ((ks * 64 + g * 16) ^ ((li & 7) << 4))];
            bf16x8 pa1 = *(const bf16x8*)&Pb[(1 * 16 + li) * 256 + ((ks * 64 + g * 16) ^ ((li & 7) << 4))];
            bf16x8 pa2 = *(const bf16x8*)&Pb[(2 * 16 + li) * 256 + ((ks * 64 + g * 16) ^ ((li & 7) << 4))];
            bf16x8 pa3 = *(const bf16x8*)&Pb[(3 * 16 + li) * 256 + ((ks * 64 + g * 16) ^ ((li & 7) << 4))];
            U16 vc0, vc1, vc2, vc3, vc4, vc5;
            vc0.u = *(const uint4*)(vj + (size_t)(0 * 16) * 2048 + ks * 32);
            vc1.u = *(const uint4*)(vj + (size_t)(1 * 16) * 2048 + ks * 32);
            vc2.u = *(const uint4*)(vj + (size_t)(2 * 16) * 2048 + ks * 32);
            vc3.u = *(const uint4*)(vj + (size_t)(3 * 16) * 2048 + ks * 32);
            vc4.u = *(const uint4*)(vj + (size_t)(4 * 16) * 2048 + ks * 32);
            vc5.u = *(const uint4*)(vj + (size_t)(5 * 16) * 2048 + ks * 32);
            __builtin_amdgcn_s_setprio(1);
#define PV_CT(CT, VC) \
            o[0][CT] = __builtin_amdgcn_mfma_f32_16x16x32_bf16(pa0, VC.bv, o[0][CT], 0, 0, 0); \
            o[1][CT] = __builtin_amdgcn_mfma_f32_16x16x32_bf16(pa1, VC.bv, o[1][CT], 0, 0, 0); \
            o[2][CT] = __builtin_amdgcn_mfma_f32_16x16x32_bf16(pa2, VC.bv, o[2][CT], 0, 0, 0); \
            o[3][CT] = __builtin_amdgcn_mfma_f32_16x16x32_bf16(pa3, VC.bv, o[3][CT], 0, 0, 0);
            PV_CT(0, vc0)
            PV_CT(1, vc1)
            PV_CT(2, vc2)
            PV_CT(3, vc3)
            PV_CT(4, vc4)
            PV_CT(5, vc5)
#undef PV_CT
            __builtin_amdgcn_s_setprio(0);
        }
    }

#pragma unroll
    for (int r = 0; r < 4; ++r) {
#pragma unroll
        for (int off = 8; off >= 1; off >>= 1)
            l_part[r] += __shfl_xor(l_part[r], off);
    }
    if (li == 0) {
#pragma unroll
        for (int r = 0; r < 4; ++r)
            lred[ch][rtq * 16 + g * 4 + r] = l_part[r];
    }
    __syncthreads();

    // ---- finalize: /l, gate by u (read-only), write bf16 gated ----
#pragma unroll
    for (int rt = 0; rt < 4; ++rt) {
#pragma unroll
        for (int r = 0; r < 4; ++r) {
            const int row = rt * 16 + g * 4 + r;
            float inv = 1.0f / (lred[0][row] + lred[1][row]);
            const float* ub = u_buf + (rowQ0 + row) * 768;
            ushort* gb = gated + (rowQ0 + row) * 768;
#pragma unroll
            for (int ct = 0; ct < 6; ++ct) {
                int col = w * 96 + ct * 16 + li;
                gb[col] = (ushort)bfr(o[rt][ct][r] * inv * ub[col]);
            }
        }
    }
}

extern "C" void kernel_launch(void* const* d_in, const int* in_sizes, int n_in,
                              void* d_out, int out_size, void* d_ws, size_t ws_size,
                              hipStream_t stream)
{
    const float* x    = (const float*)d_in[0];   // [8,2048,384]
    const float* pos  = (const float*)d_in[1];   // [1,2048,256]
    const float* Wuv  = (const float*)d_in[2];   // [384,1792]
    const float* Wout = (const float*)d_in[3];   // [768,384]
    float* out = (float*)d_out;                  // [8,2048,384] f32

    float*  u_buf = (float*)d_ws;                        // 16384*768 f32
    ushort* qk    = (ushort*)(u_buf + (size_t)R_ * HID); // 16384*256 bf16
    ushort* vT    = qk + (size_t)R_ * 256;               // 8*768*2048 bf16
    ushort* WuvThi  = vT + (size_t)B_ * HID * L_;
    ushort* WuvTlo  = WuvThi + (size_t)NUV * D2;
    ushort* WoutThi = WuvTlo + (size_t)NUV * D2;
    ushort* WoutTlo = WoutThi + (size_t)D2 * HID;
    ushort* gated   = WoutTlo + (size_t)D2 * HID;        // 16384*768 bf16
    ushort* xhi     = gated;                             // alias (dead after gemm1)

    size_t need = ((size_t)R_ * HID) * 4 +
                  ((size_t)R_ * 256 + (size_t)B_ * HID * L_ +
                   2 * (size_t)NUV * D2 + 2 * (size_t)D2 * HID +
                   (size_t)R_ * HID) * 2;                // 113.0 MB
    if (ws_size < need) return;

    {
        int total = D2 * NUV + HID * D2 + (R_ * D2) / 4;
        conv_all<<<dim3((total + 255) / 256), dim3(256), 0, stream>>>(
            Wuv, WuvThi, WuvTlo, Wout, WoutThi, WoutTlo, x, xhi);
    }

    gemm_2p<1><<<dim3(NUV / 128, R_ / 128), dim3(512), 0, stream>>>(
        xhi, D2, WuvThi, WuvTlo, D2, nullptr, 0, u_buf, qk, vT, D2);

    rope_bf<<<dim3(R_), dim3(128), 0, stream>>>(qk, pos);

    fused_attn15<<<dim3(256), dim3(512), 0, stream>>>(u_buf, qk, vT, gated);

    gemm_2p<0><<<dim3(D2 / 128, R_ / 128), dim3(512), 0, stream>>>(
        gated, HID, WoutThi, WoutTlo, HID, out, D2, nullptr, nullptr, nullptr, HID);
}

// Round 22
// 222.507 us; speedup vs baseline: 1.2079x; 1.0301x over previous
//
#include <hip/hip_runtime.h>
#include <hip/hip_bf16.h>
#include <math.h>

#define B_    8
#define L_    2048
#define HID   768
#define D2    384
#define NUV   1792
#define R_    16384
#define SCALE 0.08838834764831845f  // 128^-0.5

typedef __attribute__((ext_vector_type(8))) short bf16x8;
typedef __attribute__((ext_vector_type(4))) float f32x4;
typedef unsigned int uint32;
typedef unsigned short ushort;

static __device__ __forceinline__ uint32 bfr(float x) {
    uint32 u = __float_as_uint(x);
    return (u + 0x7FFFu + ((u >> 16) & 1u)) >> 16;
}
static __device__ __forceinline__ uint32 pk2(float lo, float hi) {
    return bfr(lo) | (bfr(hi) << 16);
}
static __device__ __forceinline__ float bf2f(ushort u) {
    return __uint_as_float(((uint32)u) << 16);
}
static __device__ __forceinline__ float silu_f(float x) { return x / (1.0f + __expf(-x)); }

// ---------------------------------------------------------------------------
// Fused pre-transform, one launch (r19-verified)
// ---------------------------------------------------------------------------
__global__ __launch_bounds__(256) void conv_all(
    const float* __restrict__ Wuv, ushort* __restrict__ WuvThi, ushort* __restrict__ WuvTlo,
    const float* __restrict__ Wout, ushort* __restrict__ WoutThi, ushort* __restrict__ WoutTlo,
    const float* __restrict__ X, ushort* __restrict__ Xhi)
{
    const int N1 = D2 * NUV;
    const int N2 = HID * D2;
    const int N3 = (R_ * D2) / 4;
    int idx = blockIdx.x * 256 + threadIdx.x;

    if (idx < N1) {
        int n = idx / D2, k = idx - n * D2;
        float v = Wuv[(size_t)k * NUV + n];
        uint32 h = bfr(v);
        WuvThi[idx] = (ushort)h;
        WuvTlo[idx] = (ushort)bfr(v - __uint_as_float(h << 16));
        return;
    }
    idx -= N1;
    if (idx < N2) {
        int n = idx / HID, k = idx - n * HID;
        float v = Wout[(size_t)k * D2 + n];
        uint32 h = bfr(v);
        WoutThi[idx] = (ushort)h;
        WoutTlo[idx] = (ushort)bfr(v - __uint_as_float(h << 16));
        return;
    }
    idx -= N2;
    if (idx < N3) {
        float4 v = *(const float4*)(X + (size_t)idx * 4);
        uint2 p; p.x = pk2(v.x, v.y); p.y = pk2(v.z, v.w);
        *(uint2*)(Xhi + (size_t)idx * 4) = p;
    }
}

// ---------------------------------------------------------------------------
// Bf16-A 2-pass GEMM core (r17-verified): C_f32 = Abf16 @ (Bhi + Blo).
// ---------------------------------------------------------------------------
template<int EPI>
__global__ __launch_bounds__(512, 4) void gemm_2p(
    const ushort* __restrict__ Ahi, int lda,
    const ushort* __restrict__ BThi, const ushort* __restrict__ BTlo, int ldbt,
    float* __restrict__ C, int ldc,
    float* __restrict__ u_buf, ushort* __restrict__ qk, ushort* __restrict__ vT,
    int K)
{
    __shared__ unsigned char As[128 * 128];
    __shared__ unsigned char Bs[128 * 256];

    const int t  = threadIdx.x;
    const int w  = t >> 6;
    const int l  = t & 63;
    const int g  = l >> 4;
    const int li = l & 15;
    const int wr = w >> 1;
    const int wc = w & 1;
    const int m0 = blockIdx.y * 128;
    const int n0 = blockIdx.x * 128;

    f32x4 acc[2][4];
#pragma unroll
    for (int i = 0; i < 2; ++i)
#pragma unroll
        for (int j = 0; j < 4; ++j) acc[i][j] = (f32x4){0.f, 0.f, 0.f, 0.f};

    for (int k0 = 0; k0 < K; k0 += 64) {
#pragma unroll
        for (int i = 0; i < 2; ++i) {
            int idx = t + i * 512;
            int row = idx >> 3;
            int c8  = idx & 7;
            uint4 v = *(const uint4*)(Ahi + (size_t)(m0 + row) * lda + k0 + c8 * 8);
            *(uint4*)&As[row * 128 + ((c8 * 16) ^ ((row & 7) << 4))] = v;
        }
#pragma unroll
        for (int i = 0; i < 8; ++i) {
            int idx = t + i * 512;
            int c   = idx >> 5;
            int s8  = idx & 31;
            const ushort* src = (s8 < 16)
                ? (BThi + (long long)(n0 + c) * ldbt + k0 + s8 * 4)
                : (BTlo + (long long)(n0 + c) * ldbt + k0 + (s8 - 16) * 4);
            *(uint2*)&Bs[c * 256 + ((s8 * 8) ^ ((c & 7) << 4))] = *(const uint2*)src;
        }
        __syncthreads();

#pragma unroll
        for (int ks = 0; ks < 2; ++ks) {
            bf16x8 ah[2], bh[4], bl[4];
#pragma unroll
            for (int mi = 0; mi < 2; ++mi) {
                int row = wr * 32 + mi * 16 + li;
                ah[mi] = *(const bf16x8*)&As[row * 128 + ((ks * 64 + g * 16) ^ ((row & 7) << 4))];
            }
#pragma unroll
            for (int ni = 0; ni < 4; ++ni) {
                int col = wc * 64 + ni * 16 + li;
                int off = (ks * 64 + g * 16) ^ ((col & 7) << 4);
                bh[ni] = *(const bf16x8*)&Bs[col * 256 + off];
                bl[ni] = *(const bf16x8*)&Bs[col * 256 + 128 + off];
            }
#pragma unroll
            for (int mi = 0; mi < 2; ++mi)
#pragma unroll
                for (int ni = 0; ni < 4; ++ni) {
                    acc[mi][ni] = __builtin_amdgcn_mfma_f32_16x16x32_bf16(ah[mi], bh[ni], acc[mi][ni], 0, 0, 0);
                    acc[mi][ni] = __builtin_amdgcn_mfma_f32_16x16x32_bf16(ah[mi], bl[ni], acc[mi][ni], 0, 0, 0);
                }
        }
        __syncthreads();
    }

    if (EPI == 0) {
#pragma unroll
        for (int mi = 0; mi < 2; ++mi)
#pragma unroll
            for (int ni = 0; ni < 4; ++ni) {
                int col = n0 + wc * 64 + ni * 16 + li;
#pragma unroll
                for (int r = 0; r < 4; ++r) {
                    int row = m0 + wr * 32 + mi * 16 + g * 4 + r;
                    C[(long long)row * ldc + col] = acc[mi][ni][r];
                }
            }
    } else {
        if (n0 < 768) {
#pragma unroll
            for (int mi = 0; mi < 2; ++mi)
#pragma unroll
                for (int ni = 0; ni < 4; ++ni) {
                    int col = n0 + wc * 64 + ni * 16 + li;
#pragma unroll
                    for (int r = 0; r < 4; ++r) {
                        int row = m0 + wr * 32 + mi * 16 + g * 4 + r;
                        u_buf[(long long)row * 768 + col] = silu_f(acc[mi][ni][r]);
                    }
                }
        } else if (n0 < 1536) {
            int bb = m0 >> 11;
            int llb = (m0 & 2047) + wr * 32 + g * 4;
#pragma unroll
            for (int mi = 0; mi < 2; ++mi) {
                int ll = llb + mi * 16;
#pragma unroll
                for (int ni = 0; ni < 4; ++ni) {
                    int cv = n0 + wc * 64 + ni * 16 + li - 768;
                    ushort* vb = vT + ((size_t)bb * 768 + cv) * 2048 + ll;
                    *(uint32*)(vb)     = pk2(silu_f(acc[mi][ni][0]), silu_f(acc[mi][ni][1]));
                    *(uint32*)(vb + 2) = pk2(silu_f(acc[mi][ni][2]), silu_f(acc[mi][ni][3]));
                }
            }
        } else {
#pragma unroll
            for (int mi = 0; mi < 2; ++mi)
#pragma unroll
                for (int ni = 0; ni < 4; ++ni) {
                    int qcol = n0 + wc * 64 + ni * 16 + li - 1536;
#pragma unroll
                    for (int r = 0; r < 4; ++r) {
                        int row = m0 + wr * 32 + mi * 16 + g * 4 + r;
                        qk[(size_t)row * 256 + qcol] = (ushort)bfr(acc[mi][ni][r]);
                    }
                }
        }
    }
}

// ---------------------------------------------------------------------------
// RoPE in place on bf16 qk buffer
// ---------------------------------------------------------------------------
__global__ __launch_bounds__(128) void rope_bf(ushort* __restrict__ qk,
                                               const float* __restrict__ pos)
{
    int row = blockIdx.x;
    int lpos = row & (L_ - 1);
    int t = threadIdx.x;
    int j = t & 63;
    int isK = t >> 6;
    ushort* base = qk + (size_t)row * 256 + isK * 128;
    float s = pos[lpos * 256 + j];
    float c = pos[lpos * 256 + 64 + j];
    float x1 = bf2f(base[j]);
    float x2 = bf2f(base[64 + j]);
    base[j]      = (ushort)bfr(x1 * c - x2 * s);
    base[64 + j] = (ushort)bfr(x2 * c + x1 * s);
}

// ---------------------------------------------------------------------------
// MFMA flash attention v16 = v15 + V software pipeline (macro args fixed):
//   * V(ks=0) loads issued BEFORE the barrier (arrive during barrier wait)
//   * 2-deep named-bank rotation through the 4 ks PV groups
// QBLK=64, KVBLK=128, no-max softmax, dbuf K/P, 1 barrier/tile, setprio.
// Grid 256, 512 thr (8 waves).
// ---------------------------------------------------------------------------
__global__ __launch_bounds__(512) void fused_attn16(
    const float* __restrict__ u_buf, const ushort* __restrict__ qk,
    const ushort* __restrict__ vT, ushort* __restrict__ gated)
{
    __shared__ unsigned char KbB[2][128 * 256];   // K bf16 dbuf (64 KB)
    __shared__ unsigned char PbB[2][64 * 256];    // P bf16 dbuf (32 KB)
    __shared__ float lred[2][64];

    const int t  = threadIdx.x;
    const int w  = t >> 6;
    const int l  = t & 63;
    const int g  = l >> 4;
    const int li = l & 15;

    const int b  = blockIdx.x & 7;
    const int qt = blockIdx.x >> 3;
    const long long rowQ0 = (long long)b * L_ + (long long)qt * 64;
    const long long rowB0 = (long long)b * L_;

    const int rtq = w >> 1;
    const int ch  = w & 1;

    bf16x8 qf[4];
    {
        const ushort* qrow = qk + (rowQ0 + rtq * 16 + li) * 256;
#pragma unroll
        for (int ks = 0; ks < 4; ++ks)
            qf[ks] = *(const bf16x8*)&qrow[ks * 32 + g * 8];
    }

    float l_part[4] = {0.f, 0.f, 0.f, 0.f};

    f32x4 o[4][6];
#pragma unroll
    for (int rt = 0; rt < 4; ++rt)
#pragma unroll
        for (int ct = 0; ct < 6; ++ct)
            o[rt][ct] = (f32x4){0.f, 0.f, 0.f, 0.f};

    const ushort* vrow = vT + ((size_t)b * 768 + w * 96 + li) * 2048 + g * 8;

    const int kr  = t >> 4;
    const int c16 = t & 15;
    const int ksw = (c16 * 16) ^ ((kr & 7) << 4);

    union U16 { uint4 u; bf16x8 bv; };

    // prologue: prefetch K(0), publish into Kb[0], barrier, prefetch K(1)
    uint4 kA = *(const uint4*)&qk[(rowB0 + kr)      * 256 + 128 + c16 * 8];
    uint4 kB = *(const uint4*)&qk[(rowB0 + kr + 32) * 256 + 128 + c16 * 8];
    uint4 kC = *(const uint4*)&qk[(rowB0 + kr + 64) * 256 + 128 + c16 * 8];
    uint4 kD = *(const uint4*)&qk[(rowB0 + kr + 96) * 256 + 128 + c16 * 8];
    *(uint4*)&KbB[0][(kr)      * 256 + ksw] = kA;
    *(uint4*)&KbB[0][(kr + 32) * 256 + ksw] = kB;
    *(uint4*)&KbB[0][(kr + 64) * 256 + ksw] = kC;
    *(uint4*)&KbB[0][(kr + 96) * 256 + ksw] = kD;
    __syncthreads();
    {
        const ushort* kn = qk + (rowB0 + 128 + kr) * 256 + 128 + c16 * 8;
        kA = *(const uint4*)(kn);
        kB = *(const uint4*)(kn + (size_t)32 * 256);
        kC = *(const uint4*)(kn + (size_t)64 * 256);
        kD = *(const uint4*)(kn + (size_t)96 * 256);
    }

    for (int jt = 0; jt < 16; ++jt) {
        const unsigned char* Kb = &KbB[jt & 1][0];
        unsigned char* Pb = &PbB[jt & 1][0];
        const ushort* vj = vrow + jt * 128;

        // ---- QK: 4 S-tiles + exp + Pb write + l accumulation ----
        __builtin_amdgcn_s_setprio(1);
#pragma unroll
        for (int ci = 0; ci < 4; ++ci) {
            const int ct = ch * 4 + ci;
            const int krow = ct * 16 + li;
            const int rs = (krow & 7) << 4;
            f32x4 s = {0.f, 0.f, 0.f, 0.f};
#pragma unroll
            for (int ks = 0; ks < 4; ++ks) {
                bf16x8 kf = *(const bf16x8*)&Kb[krow * 256 + ((ks * 64 + g * 16) ^ rs)];
                s = __builtin_amdgcn_mfma_f32_16x16x32_bf16(qf[ks], kf, s, 0, 0, 0);
            }
#pragma unroll
            for (int r = 0; r < 4; ++r) {
                float p = __expf(SCALE * s[r]);
                l_part[r] += p;
                const int prow = rtq * 16 + g * 4 + r;
                *(ushort*)&Pb[prow * 256 + (((ct * 16 + li) * 2) ^ ((prow & 7) << 4))]
                    = (ushort)bfr(p);
            }
        }
        __builtin_amdgcn_s_setprio(0);

        // ---- publish K(jt+1) into the other buffer (before the barrier) ----
        if (jt + 1 < 16) {
            unsigned char* Kn = &KbB[(jt + 1) & 1][0];
            *(uint4*)&Kn[(kr)      * 256 + ksw] = kA;
            *(uint4*)&Kn[(kr + 32) * 256 + ksw] = kB;
            *(uint4*)&Kn[(kr + 64) * 256 + ksw] = kC;
            *(uint4*)&Kn[(kr + 96) * 256 + ksw] = kD;
        }

        // ---- issue V(ks=0): arrives while waiting at the barrier ----
        U16 xa0, xa1, xa2, xa3, xa4, xa5;      // bank A
        xa0.u = *(const uint4*)(vj + (size_t)(0 * 16) * 2048);
        xa1.u = *(const uint4*)(vj + (size_t)(1 * 16) * 2048);
        xa2.u = *(const uint4*)(vj + (size_t)(2 * 16) * 2048);
        xa3.u = *(const uint4*)(vj + (size_t)(3 * 16) * 2048);
        xa4.u = *(const uint4*)(vj + (size_t)(4 * 16) * 2048);
        xa5.u = *(const uint4*)(vj + (size_t)(5 * 16) * 2048);

        __syncthreads();   // Pb(jt) ready AND K(jt+1) visible; V(ks0) drained

        // ---- prefetch K(jt+2) (drains at NEXT barrier) ----
        if (jt + 2 < 16) {
            const ushort* kn = qk + (rowB0 + (jt + 2) * 128 + kr) * 256 + 128 + c16 * 8;
            kA = *(const uint4*)(kn);
            kB = *(const uint4*)(kn + (size_t)32 * 256);
            kC = *(const uint4*)(kn + (size_t)64 * 256);
            kD = *(const uint4*)(kn + (size_t)96 * 256);
        }

        // ---- PV: 2-deep V rotation; per ks: pa[4] + V[6], 24 MFMA ----
        U16 xb0, xb1, xb2, xb3, xb4, xb5;      // bank B

#define PA_LOAD(KS) \
        bf16x8 pa0 = *(const bf16x8*)&Pb[(0 * 16 + li) * 256 + (((KS) * 64 + g * 16) ^ ((li & 7) << 4))]; \
        bf16x8 pa1 = *(const bf16x8*)&Pb[(1 * 16 + li) * 256 + (((KS) * 64 + g * 16) ^ ((li & 7) << 4))]; \
        bf16x8 pa2 = *(const bf16x8*)&Pb[(2 * 16 + li) * 256 + (((KS) * 64 + g * 16) ^ ((li & 7) << 4))]; \
        bf16x8 pa3 = *(const bf16x8*)&Pb[(3 * 16 + li) * 256 + (((KS) * 64 + g * 16) ^ ((li & 7) << 4))];
#define VISSUE(B0, B1, B2, B3, B4, B5, KS) \
        B0.u = *(const uint4*)(vj + (size_t)(0 * 16) * 2048 + (KS) * 32); \
        B1.u = *(const uint4*)(vj + (size_t)(1 * 16) * 2048 + (KS) * 32); \
        B2.u = *(const uint4*)(vj + (size_t)(2 * 16) * 2048 + (KS) * 32); \
        B3.u = *(const uint4*)(vj + (size_t)(3 * 16) * 2048 + (KS) * 32); \
        B4.u = *(const uint4*)(vj + (size_t)(4 * 16) * 2048 + (KS) * 32); \
        B5.u = *(const uint4*)(vj + (size_t)(5 * 16) * 2048 + (KS) * 32);
#define PV_MFMA(B0, B1, B2, B3, B4, B5) \
        __builtin_amdgcn_s_setprio(1); \
        o[0][0] = __builtin_amdgcn_mfma_f32_16x16x32_bf16(pa0, B0.bv, o[0][0], 0, 0, 0); \
        o[1][0] = __builtin_amdgcn_mfma_f32_16x16x32_bf16(pa1, B0.bv, o[1][0], 0, 0, 0); \
        o[2][0] = __builtin_amdgcn_mfma_f32_16x16x32_bf16(pa2, B0.bv, o[2][0], 0, 0, 0); \
        o[3][0] = __builtin_amdgcn_mfma_f32_16x16x32_bf16(pa3, B0.bv, o[3][0], 0, 0, 0); \
        o[0][1] = __builtin_amdgcn_mfma_f32_16x16x32_bf16(pa0, B1.bv, o[0][1], 0, 0, 0); \
        o[1][1] = __builtin_amdgcn_mfma_f32_16x16x32_bf16(pa1, B1.bv, o[1][1], 0, 0, 0); \
        o[2][1] = __builtin_amdgcn_mfma_f32_16x16x32_bf16(pa2, B1.bv, o[2][1], 0, 0, 0); \
        o[3][1] = __builtin_amdgcn_mfma_f32_16x16x32_bf16(pa3, B1.bv, o[3][1], 0, 0, 0); \
        o[0][2] = __builtin_amdgcn_mfma_f32_16x16x32_bf16(pa0, B2.bv, o[0][2], 0, 0, 0); \
        o[1][2] = __builtin_amdgcn_mfma_f32_16x16x32_bf16(pa1, B2.bv, o[1][2], 0, 0, 0); \
        o[2][2] = __builtin_amdgcn_mfma_f32_16x16x32_bf16(pa2, B2.bv, o[2][2], 0, 0, 0); \
        o[3][2] = __builtin_amdgcn_mfma_f32_16x16x32_bf16(pa3, B2.bv, o[3][2], 0, 0, 0); \
        o[0][3] = __builtin_amdgcn_mfma_f32_16x16x32_bf16(pa0, B3.bv, o[0][3], 0, 0, 0); \
        o[1][3] = __builtin_amdgcn_mfma_f32_16x16x32_bf16(pa1, B3.bv, o[1][3], 0, 0, 0); \
        o[2][3] = __builtin_amdgcn_mfma_f32_16x16x32_bf16(pa2, B3.bv, o[2][3], 0, 0, 0); \
        o[3][3] = __builtin_amdgcn_mfma_f32_16x16x32_bf16(pa3, B3.bv, o[3][3], 0, 0, 0); \
        o[0][4] = __builtin_amdgcn_mfma_f32_16x16x32_bf16(pa0, B4.bv, o[0][4], 0, 0, 0); \
        o[1][4] = __builtin_amdgcn_mfma_f32_16x16x32_bf16(pa1, B4.bv, o[1][4], 0, 0, 0); \
        o[2][4] = __builtin_amdgcn_mfma_f32_16x16x32_bf16(pa2, B4.bv, o[2][4], 0, 0, 0); \
        o[3][4] = __builtin_amdgcn_mfma_f32_16x16x32_bf16(pa3, B4.bv, o[3][4], 0, 0, 0); \
        o[0][5] = __builtin_amdgcn_mfma_f32_16x16x32_bf16(pa0, B5.bv, o[0][5], 0, 0, 0); \
        o[1][5] = __builtin_amdgcn_mfma_f32_16x16x32_bf16(pa1, B5.bv, o[1][5], 0, 0, 0); \
        o[2][5] = __builtin_amdgcn_mfma_f32_16x16x32_bf16(pa2, B5.bv, o[2][5], 0, 0, 0); \
        o[3][5] = __builtin_amdgcn_mfma_f32_16x16x32_bf16(pa3, B5.bv, o[3][5], 0, 0, 0); \
        __builtin_amdgcn_s_setprio(0);

        { // ks = 0: consume A, issue B(ks=1)
            VISSUE(xb0, xb1, xb2, xb3, xb4, xb5, 1)
            PA_LOAD(0)
            PV_MFMA(xa0, xa1, xa2, xa3, xa4, xa5)
        }
        { // ks = 1: consume B, issue A(ks=2)
            VISSUE(xa0, xa1, xa2, xa3, xa4, xa5, 2)
            PA_LOAD(1)
            PV_MFMA(xb0, xb1, xb2, xb3, xb4, xb5)
        }
        { // ks = 2: consume A, issue B(ks=3)
            VISSUE(xb0, xb1, xb2, xb3, xb4, xb5, 3)
            PA_LOAD(2)
            PV_MFMA(xa0, xa1, xa2, xa3, xa4, xa5)
        }
        { // ks = 3: consume B
            PA_LOAD(3)
            PV_MFMA(xb0, xb1, xb2, xb3, xb4, xb5)
        }
#undef PA_LOAD
#undef VISSUE
#undef PV_MFMA
    }

#pragma unroll
    for (int r = 0; r < 4; ++r) {
#pragma unroll
        for (int off = 8; off >= 1; off >>= 1)
            l_part[r] += __shfl_xor(l_part[r], off);
    }
    if (li == 0) {
#pragma unroll
        for (int r = 0; r < 4; ++r)
            lred[ch][rtq * 16 + g * 4 + r] = l_part[r];
    }
    __syncthreads();

    // ---- finalize: /l, gate by u (read-only), write bf16 gated ----
#pragma unroll
    for (int rt = 0; rt < 4; ++rt) {
#pragma unroll
        for (int r = 0; r < 4; ++r) {
            const int row = rt * 16 + g * 4 + r;
            float inv = 1.0f / (lred[0][row] + lred[1][row]);
            const float* ub = u_buf + (rowQ0 + row) * 768;
            ushort* gb = gated + (rowQ0 + row) * 768;
#pragma unroll
            for (int ct = 0; ct < 6; ++ct) {
                int col = w * 96 + ct * 16 + li;
                gb[col] = (ushort)bfr(o[rt][ct][r] * inv * ub[col]);
            }
        }
    }
}

extern "C" void kernel_launch(void* const* d_in, const int* in_sizes, int n_in,
                              void* d_out, int out_size, void* d_ws, size_t ws_size,
                              hipStream_t stream)
{
    const float* x    = (const float*)d_in[0];   // [8,2048,384]
    const float* pos  = (const float*)d_in[1];   // [1,2048,256]
    const float* Wuv  = (const float*)d_in[2];   // [384,1792]
    const float* Wout = (const float*)d_in[3];   // [768,384]
    float* out = (float*)d_out;                  // [8,2048,384] f32

    float*  u_buf = (float*)d_ws;                        // 16384*768 f32
    ushort* qk    = (ushort*)(u_buf + (size_t)R_ * HID); // 16384*256 bf16
    ushort* vT    = qk + (size_t)R_ * 256;               // 8*768*2048 bf16
    ushort* WuvThi  = vT + (size_t)B_ * HID * L_;
    ushort* WuvTlo  = WuvThi + (size_t)NUV * D2;
    ushort* WoutThi = WuvTlo + (size_t)NUV * D2;
    ushort* WoutTlo = WoutThi + (size_t)D2 * HID;
    ushort* gated   = WoutTlo + (size_t)D2 * HID;        // 16384*768 bf16
    ushort* xhi     = gated;                             // alias (dead after gemm1)

    size_t need = ((size_t)R_ * HID) * 4 +
                  ((size_t)R_ * 256 + (size_t)B_ * HID * L_ +
                   2 * (size_t)NUV * D2 + 2 * (size_t)D2 * HID +
                   (size_t)R_ * HID) * 2;                // 113.0 MB
    if (ws_size < need) return;

    {
        int total = D2 * NUV + HID * D2 + (R_ * D2) / 4;
        conv_all<<<dim3((total + 255) / 256), dim3(256), 0, stream>>>(
            Wuv, WuvThi, WuvTlo, Wout, WoutThi, WoutTlo, x, xhi);
    }

    gemm_2p<1><<<dim3(NUV / 128, R_ / 128), dim3(512), 0, stream>>>(
        xhi, D2, WuvThi, WuvTlo, D2, nullptr, 0, u_buf, qk, vT, D2);

    rope_bf<<<dim3(R_), dim3(128), 0, stream>>>(qk, pos);

    fused_attn16<<<dim3(256), dim3(512), 0, stream>>>(u_buf, qk, vT, gated);

    gemm_2p<0><<<dim3(D2 / 128, R_ / 128), dim3(512), 0, stream>>>(
        gated, HID, WoutThi, WoutTlo, HID, out, D2, nullptr, nullptr, nullptr, HID);
}

// Round 23
// 219.713 us; speedup vs baseline: 1.2233x; 1.0127x over previous
//
#include <hip/hip_runtime.h>
#include <hip/hip_bf16.h>
#include <math.h>

#define B_    8
#define L_    2048
#define HID   768
#define D2    384
#define NUV   1792
#define R_    16384
#define SCALE 0.08838834764831845f  // 128^-0.5

typedef __attribute__((ext_vector_type(8))) short bf16x8;
typedef __attribute__((ext_vector_type(4))) float f32x4;
typedef unsigned int uint32;
typedef unsigned short ushort;

static __device__ __forceinline__ uint32 bfr(float x) {
    uint32 u = __float_as_uint(x);
    return (u + 0x7FFFu + ((u >> 16) & 1u)) >> 16;
}
static __device__ __forceinline__ uint32 pk2(float lo, float hi) {
    return bfr(lo) | (bfr(hi) << 16);
}
static __device__ __forceinline__ float bf2f(ushort u) {
    return __uint_as_float(((uint32)u) << 16);
}
static __device__ __forceinline__ float silu_f(float x) { return x / (1.0f + __expf(-x)); }

// ---------------------------------------------------------------------------
// Fused pre-transform, one launch (r19-verified)
// ---------------------------------------------------------------------------
__global__ __launch_bounds__(256) void conv_all(
    const float* __restrict__ Wuv, ushort* __restrict__ WuvThi, ushort* __restrict__ WuvTlo,
    const float* __restrict__ Wout, ushort* __restrict__ WoutThi, ushort* __restrict__ WoutTlo,
    const float* __restrict__ X, ushort* __restrict__ Xhi)
{
    const int N1 = D2 * NUV;
    const int N2 = HID * D2;
    const int N3 = (R_ * D2) / 4;
    int idx = blockIdx.x * 256 + threadIdx.x;

    if (idx < N1) {
        int n = idx / D2, k = idx - n * D2;
        float v = Wuv[(size_t)k * NUV + n];
        uint32 h = bfr(v);
        WuvThi[idx] = (ushort)h;
        WuvTlo[idx] = (ushort)bfr(v - __uint_as_float(h << 16));
        return;
    }
    idx -= N1;
    if (idx < N2) {
        int n = idx / HID, k = idx - n * HID;
        float v = Wout[(size_t)k * D2 + n];
        uint32 h = bfr(v);
        WoutThi[idx] = (ushort)h;
        WoutTlo[idx] = (ushort)bfr(v - __uint_as_float(h << 16));
        return;
    }
    idx -= N2;
    if (idx < N3) {
        float4 v = *(const float4*)(X + (size_t)idx * 4);
        uint2 p; p.x = pk2(v.x, v.y); p.y = pk2(v.z, v.w);
        *(uint2*)(Xhi + (size_t)idx * 4) = p;
    }
}

// ---------------------------------------------------------------------------
// Bf16-A 2-pass GEMM core (r17-verified): C_f32 = Abf16 @ (Bhi + Blo).
// EPI 0: plain f32 C.  EPI 1: GAU GEMM1 epilogue (u now stored bf16).
// ---------------------------------------------------------------------------
template<int EPI>
__global__ __launch_bounds__(512, 4) void gemm_2p(
    const ushort* __restrict__ Ahi, int lda,
    const ushort* __restrict__ BThi, const ushort* __restrict__ BTlo, int ldbt,
    float* __restrict__ C, int ldc,
    ushort* __restrict__ u_buf, ushort* __restrict__ qk, ushort* __restrict__ vT,
    int K)
{
    __shared__ unsigned char As[128 * 128];
    __shared__ unsigned char Bs[128 * 256];

    const int t  = threadIdx.x;
    const int w  = t >> 6;
    const int l  = t & 63;
    const int g  = l >> 4;
    const int li = l & 15;
    const int wr = w >> 1;
    const int wc = w & 1;
    const int m0 = blockIdx.y * 128;
    const int n0 = blockIdx.x * 128;

    f32x4 acc[2][4];
#pragma unroll
    for (int i = 0; i < 2; ++i)
#pragma unroll
        for (int j = 0; j < 4; ++j) acc[i][j] = (f32x4){0.f, 0.f, 0.f, 0.f};

    for (int k0 = 0; k0 < K; k0 += 64) {
#pragma unroll
        for (int i = 0; i < 2; ++i) {
            int idx = t + i * 512;
            int row = idx >> 3;
            int c8  = idx & 7;
            uint4 v = *(const uint4*)(Ahi + (size_t)(m0 + row) * lda + k0 + c8 * 8);
            *(uint4*)&As[row * 128 + ((c8 * 16) ^ ((row & 7) << 4))] = v;
        }
#pragma unroll
        for (int i = 0; i < 8; ++i) {
            int idx = t + i * 512;
            int c   = idx >> 5;
            int s8  = idx & 31;
            const ushort* src = (s8 < 16)
                ? (BThi + (long long)(n0 + c) * ldbt + k0 + s8 * 4)
                : (BTlo + (long long)(n0 + c) * ldbt + k0 + (s8 - 16) * 4);
            *(uint2*)&Bs[c * 256 + ((s8 * 8) ^ ((c & 7) << 4))] = *(const uint2*)src;
        }
        __syncthreads();

#pragma unroll
        for (int ks = 0; ks < 2; ++ks) {
            bf16x8 ah[2], bh[4], bl[4];
#pragma unroll
            for (int mi = 0; mi < 2; ++mi) {
                int row = wr * 32 + mi * 16 + li;
                ah[mi] = *(const bf16x8*)&As[row * 128 + ((ks * 64 + g * 16) ^ ((row & 7) << 4))];
            }
#pragma unroll
            for (int ni = 0; ni < 4; ++ni) {
                int col = wc * 64 + ni * 16 + li;
                int off = (ks * 64 + g * 16) ^ ((col & 7) << 4);
                bh[ni] = *(const bf16x8*)&Bs[col * 256 + off];
                bl[ni] = *(const bf16x8*)&Bs[col * 256 + 128 + off];
            }
#pragma unroll
            for (int mi = 0; mi < 2; ++mi)
#pragma unroll
                for (int ni = 0; ni < 4; ++ni) {
                    acc[mi][ni] = __builtin_amdgcn_mfma_f32_16x16x32_bf16(ah[mi], bh[ni], acc[mi][ni], 0, 0, 0);
                    acc[mi][ni] = __builtin_amdgcn_mfma_f32_16x16x32_bf16(ah[mi], bl[ni], acc[mi][ni], 0, 0, 0);
                }
        }
        __syncthreads();
    }

    if (EPI == 0) {
#pragma unroll
        for (int mi = 0; mi < 2; ++mi)
#pragma unroll
            for (int ni = 0; ni < 4; ++ni) {
                int col = n0 + wc * 64 + ni * 16 + li;
#pragma unroll
                for (int r = 0; r < 4; ++r) {
                    int row = m0 + wr * 32 + mi * 16 + g * 4 + r;
                    C[(long long)row * ldc + col] = acc[mi][ni][r];
                }
            }
    } else {
        if (n0 < 768) {
            // u: silu -> bf16 (quantization cost verified negligible path)
#pragma unroll
            for (int mi = 0; mi < 2; ++mi)
#pragma unroll
                for (int ni = 0; ni < 4; ++ni) {
                    int col = n0 + wc * 64 + ni * 16 + li;
#pragma unroll
                    for (int r = 0; r < 4; ++r) {
                        int row = m0 + wr * 32 + mi * 16 + g * 4 + r;
                        u_buf[(size_t)row * 768 + col] = (ushort)bfr(silu_f(acc[mi][ni][r]));
                    }
                }
        } else if (n0 < 1536) {
            int bb = m0 >> 11;
            int llb = (m0 & 2047) + wr * 32 + g * 4;
#pragma unroll
            for (int mi = 0; mi < 2; ++mi) {
                int ll = llb + mi * 16;
#pragma unroll
                for (int ni = 0; ni < 4; ++ni) {
                    int cv = n0 + wc * 64 + ni * 16 + li - 768;
                    ushort* vb = vT + ((size_t)bb * 768 + cv) * 2048 + ll;
                    *(uint32*)(vb)     = pk2(silu_f(acc[mi][ni][0]), silu_f(acc[mi][ni][1]));
                    *(uint32*)(vb + 2) = pk2(silu_f(acc[mi][ni][2]), silu_f(acc[mi][ni][3]));
                }
            }
        } else {
#pragma unroll
            for (int mi = 0; mi < 2; ++mi)
#pragma unroll
                for (int ni = 0; ni < 4; ++ni) {
                    int qcol = n0 + wc * 64 + ni * 16 + li - 1536;
#pragma unroll
                    for (int r = 0; r < 4; ++r) {
                        int row = m0 + wr * 32 + mi * 16 + g * 4 + r;
                        qk[(size_t)row * 256 + qcol] = (ushort)bfr(acc[mi][ni][r]);
                    }
                }
        }
    }
}

// ---------------------------------------------------------------------------
// RoPE in place on bf16 qk buffer
// ---------------------------------------------------------------------------
__global__ __launch_bounds__(128) void rope_bf(ushort* __restrict__ qk,
                                               const float* __restrict__ pos)
{
    int row = blockIdx.x;
    int lpos = row & (L_ - 1);
    int t = threadIdx.x;
    int j = t & 63;
    int isK = t >> 6;
    ushort* base = qk + (size_t)row * 256 + isK * 128;
    float s = pos[lpos * 256 + j];
    float c = pos[lpos * 256 + 64 + j];
    float x1 = bf2f(base[j]);
    float x2 = bf2f(base[64 + j]);
    base[j]      = (ushort)bfr(x1 * c - x2 * s);
    base[64 + j] = (ushort)bfr(x2 * c + x1 * s);
}

// ---------------------------------------------------------------------------
// MFMA flash attention v17 = r22 winner (V software pipeline, dbuf K/P,
// 1 barrier/tile, setprio) with u read as bf16.
// Grid 256, 512 thr (8 waves).
// ---------------------------------------------------------------------------
__global__ __launch_bounds__(512) void fused_attn17(
    const ushort* __restrict__ u_buf, const ushort* __restrict__ qk,
    const ushort* __restrict__ vT, ushort* __restrict__ gated)
{
    __shared__ unsigned char KbB[2][128 * 256];   // K bf16 dbuf (64 KB)
    __shared__ unsigned char PbB[2][64 * 256];    // P bf16 dbuf (32 KB)
    __shared__ float lred[2][64];

    const int t  = threadIdx.x;
    const int w  = t >> 6;
    const int l  = t & 63;
    const int g  = l >> 4;
    const int li = l & 15;

    const int b  = blockIdx.x & 7;
    const int qt = blockIdx.x >> 3;
    const long long rowQ0 = (long long)b * L_ + (long long)qt * 64;
    const long long rowB0 = (long long)b * L_;

    const int rtq = w >> 1;
    const int ch  = w & 1;

    bf16x8 qf[4];
    {
        const ushort* qrow = qk + (rowQ0 + rtq * 16 + li) * 256;
#pragma unroll
        for (int ks = 0; ks < 4; ++ks)
            qf[ks] = *(const bf16x8*)&qrow[ks * 32 + g * 8];
    }

    float l_part[4] = {0.f, 0.f, 0.f, 0.f};

    f32x4 o[4][6];
#pragma unroll
    for (int rt = 0; rt < 4; ++rt)
#pragma unroll
        for (int ct = 0; ct < 6; ++ct)
            o[rt][ct] = (f32x4){0.f, 0.f, 0.f, 0.f};

    const ushort* vrow = vT + ((size_t)b * 768 + w * 96 + li) * 2048 + g * 8;

    const int kr  = t >> 4;
    const int c16 = t & 15;
    const int ksw = (c16 * 16) ^ ((kr & 7) << 4);

    union U16 { uint4 u; bf16x8 bv; };

    // prologue: prefetch K(0), publish into Kb[0], barrier, prefetch K(1)
    uint4 kA = *(const uint4*)&qk[(rowB0 + kr)      * 256 + 128 + c16 * 8];
    uint4 kB = *(const uint4*)&qk[(rowB0 + kr + 32) * 256 + 128 + c16 * 8];
    uint4 kC = *(const uint4*)&qk[(rowB0 + kr + 64) * 256 + 128 + c16 * 8];
    uint4 kD = *(const uint4*)&qk[(rowB0 + kr + 96) * 256 + 128 + c16 * 8];
    *(uint4*)&KbB[0][(kr)      * 256 + ksw] = kA;
    *(uint4*)&KbB[0][(kr + 32) * 256 + ksw] = kB;
    *(uint4*)&KbB[0][(kr + 64) * 256 + ksw] = kC;
    *(uint4*)&KbB[0][(kr + 96) * 256 + ksw] = kD;
    __syncthreads();
    {
        const ushort* kn = qk + (rowB0 + 128 + kr) * 256 + 128 + c16 * 8;
        kA = *(const uint4*)(kn);
        kB = *(const uint4*)(kn + (size_t)32 * 256);
        kC = *(const uint4*)(kn + (size_t)64 * 256);
        kD = *(const uint4*)(kn + (size_t)96 * 256);
    }

    for (int jt = 0; jt < 16; ++jt) {
        const unsigned char* Kb = &KbB[jt & 1][0];
        unsigned char* Pb = &PbB[jt & 1][0];
        const ushort* vj = vrow + jt * 128;

        // ---- QK: 4 S-tiles + exp + Pb write + l accumulation ----
        __builtin_amdgcn_s_setprio(1);
#pragma unroll
        for (int ci = 0; ci < 4; ++ci) {
            const int ct = ch * 4 + ci;
            const int krow = ct * 16 + li;
            const int rs = (krow & 7) << 4;
            f32x4 s = {0.f, 0.f, 0.f, 0.f};
#pragma unroll
            for (int ks = 0; ks < 4; ++ks) {
                bf16x8 kf = *(const bf16x8*)&Kb[krow * 256 + ((ks * 64 + g * 16) ^ rs)];
                s = __builtin_amdgcn_mfma_f32_16x16x32_bf16(qf[ks], kf, s, 0, 0, 0);
            }
#pragma unroll
            for (int r = 0; r < 4; ++r) {
                float p = __expf(SCALE * s[r]);
                l_part[r] += p;
                const int prow = rtq * 16 + g * 4 + r;
                *(ushort*)&Pb[prow * 256 + (((ct * 16 + li) * 2) ^ ((prow & 7) << 4))]
                    = (ushort)bfr(p);
            }
        }
        __builtin_amdgcn_s_setprio(0);

        // ---- publish K(jt+1) into the other buffer (before the barrier) ----
        if (jt + 1 < 16) {
            unsigned char* Kn = &KbB[(jt + 1) & 1][0];
            *(uint4*)&Kn[(kr)      * 256 + ksw] = kA;
            *(uint4*)&Kn[(kr + 32) * 256 + ksw] = kB;
            *(uint4*)&Kn[(kr + 64) * 256 + ksw] = kC;
            *(uint4*)&Kn[(kr + 96) * 256 + ksw] = kD;
        }

        // ---- issue V(ks=0): arrives while waiting at the barrier ----
        U16 xa0, xa1, xa2, xa3, xa4, xa5;      // bank A
        xa0.u = *(const uint4*)(vj + (size_t)(0 * 16) * 2048);
        xa1.u = *(const uint4*)(vj + (size_t)(1 * 16) * 2048);
        xa2.u = *(const uint4*)(vj + (size_t)(2 * 16) * 2048);
        xa3.u = *(const uint4*)(vj + (size_t)(3 * 16) * 2048);
        xa4.u = *(const uint4*)(vj + (size_t)(4 * 16) * 2048);
        xa5.u = *(const uint4*)(vj + (size_t)(5 * 16) * 2048);

        __syncthreads();   // Pb(jt) ready AND K(jt+1) visible; V(ks0) drained

        // ---- prefetch K(jt+2) (drains at NEXT barrier) ----
        if (jt + 2 < 16) {
            const ushort* kn = qk + (rowB0 + (jt + 2) * 128 + kr) * 256 + 128 + c16 * 8;
            kA = *(const uint4*)(kn);
            kB = *(const uint4*)(kn + (size_t)32 * 256);
            kC = *(const uint4*)(kn + (size_t)64 * 256);
            kD = *(const uint4*)(kn + (size_t)96 * 256);
        }

        // ---- PV: 2-deep V rotation; per ks: pa[4] + V[6], 24 MFMA ----
        U16 xb0, xb1, xb2, xb3, xb4, xb5;      // bank B

#define PA_LOAD(KS) \
        bf16x8 pa0 = *(const bf16x8*)&Pb[(0 * 16 + li) * 256 + (((KS) * 64 + g * 16) ^ ((li & 7) << 4))]; \
        bf16x8 pa1 = *(const bf16x8*)&Pb[(1 * 16 + li) * 256 + (((KS) * 64 + g * 16) ^ ((li & 7) << 4))]; \
        bf16x8 pa2 = *(const bf16x8*)&Pb[(2 * 16 + li) * 256 + (((KS) * 64 + g * 16) ^ ((li & 7) << 4))]; \
        bf16x8 pa3 = *(const bf16x8*)&Pb[(3 * 16 + li) * 256 + (((KS) * 64 + g * 16) ^ ((li & 7) << 4))];
#define VISSUE(B0, B1, B2, B3, B4, B5, KS) \
        B0.u = *(const uint4*)(vj + (size_t)(0 * 16) * 2048 + (KS) * 32); \
        B1.u = *(const uint4*)(vj + (size_t)(1 * 16) * 2048 + (KS) * 32); \
        B2.u = *(const uint4*)(vj + (size_t)(2 * 16) * 2048 + (KS) * 32); \
        B3.u = *(const uint4*)(vj + (size_t)(3 * 16) * 2048 + (KS) * 32); \
        B4.u = *(const uint4*)(vj + (size_t)(4 * 16) * 2048 + (KS) * 32); \
        B5.u = *(const uint4*)(vj + (size_t)(5 * 16) * 2048 + (KS) * 32);
#define PV_MFMA(B0, B1, B2, B3, B4, B5) \
        __builtin_amdgcn_s_setprio(1); \
        o[0][0] = __builtin_amdgcn_mfma_f32_16x16x32_bf16(pa0, B0.bv, o[0][0], 0, 0, 0); \
        o[1][0] = __builtin_amdgcn_mfma_f32_16x16x32_bf16(pa1, B0.bv, o[1][0], 0, 0, 0); \
        o[2][0] = __builtin_amdgcn_mfma_f32_16x16x32_bf16(pa2, B0.bv, o[2][0], 0, 0, 0); \
        o[3][0] = __builtin_amdgcn_mfma_f32_16x16x32_bf16(pa3, B0.bv, o[3][0], 0, 0, 0); \
        o[0][1] = __builtin_amdgcn_mfma_f32_16x16x32_bf16(pa0, B1.bv, o[0][1], 0, 0, 0); \
        o[1][1] = __builtin_amdgcn_mfma_f32_16x16x32_bf16(pa1, B1.bv, o[1][1], 0, 0, 0); \
        o[2][1] = __builtin_amdgcn_mfma_f32_16x16x32_bf16(pa2, B1.bv, o[2][1], 0, 0, 0); \
        o[3][1] = __builtin_amdgcn_mfma_f32_16x16x32_bf16(pa3, B1.bv, o[3][1], 0, 0, 0); \
        o[0][2] = __builtin_amdgcn_mfma_f32_16x16x32_bf16(pa0, B2.bv, o[0][2], 0, 0, 0); \
        o[1][2] = __builtin_amdgcn_mfma_f32_16x16x32_bf16(pa1, B2.bv, o[1][2], 0, 0, 0); \
        o[2][2] = __builtin_amdgcn_mfma_f32_16x16x32_bf16(pa2, B2.bv, o[2][2], 0, 0, 0); \
        o[3][2] = __builtin_amdgcn_mfma_f32_16x16x32_bf16(pa3, B2.bv, o[3][2], 0, 0, 0); \
        o[0][3] = __builtin_amdgcn_mfma_f32_16x16x32_bf16(pa0, B3.bv, o[0][3], 0, 0, 0); \
        o[1][3] = __builtin_amdgcn_mfma_f32_16x16x32_bf16(pa1, B3.bv, o[1][3], 0, 0, 0); \
        o[2][3] = __builtin_amdgcn_mfma_f32_16x16x32_bf16(pa2, B3.bv, o[2][3], 0, 0, 0); \
        o[3][3] = __builtin_amdgcn_mfma_f32_16x16x32_bf16(pa3, B3.bv, o[3][3], 0, 0, 0); \
        o[0][4] = __builtin_amdgcn_mfma_f32_16x16x32_bf16(pa0, B4.bv, o[0][4], 0, 0, 0); \
        o[1][4] = __builtin_amdgcn_mfma_f32_16x16x32_bf16(pa1, B4.bv, o[1][4], 0, 0, 0); \
        o[2][4] = __builtin_amdgcn_mfma_f32_16x16x32_bf16(pa2, B4.bv, o[2][4], 0, 0, 0); \
        o[3][4] = __builtin_amdgcn_mfma_f32_16x16x32_bf16(pa3, B4.bv, o[3][4], 0, 0, 0); \
        o[0][5] = __builtin_amdgcn_mfma_f32_16x16x32_bf16(pa0, B5.bv, o[0][5], 0, 0, 0); \
        o[1][5] = __builtin_amdgcn_mfma_f32_16x16x32_bf16(pa1, B5.bv, o[1][5], 0, 0, 0); \
        o[2][5] = __builtin_amdgcn_mfma_f32_16x16x32_bf16(pa2, B5.bv, o[2][5], 0, 0, 0); \
        o[3][5] = __builtin_amdgcn_mfma_f32_16x16x32_bf16(pa3, B5.bv, o[3][5], 0, 0, 0); \
        __builtin_amdgcn_s_setprio(0);

        { // ks = 0: consume A, issue B(ks=1)
            VISSUE(xb0, xb1, xb2, xb3, xb4, xb5, 1)
            PA_LOAD(0)
            PV_MFMA(xa0, xa1, xa2, xa3, xa4, xa5)
        }
        { // ks = 1: consume B, issue A(ks=2)
            VISSUE(xa0, xa1, xa2, xa3, xa4, xa5, 2)
            PA_LOAD(1)
            PV_MFMA(xb0, xb1, xb2, xb3, xb4, xb5)
        }
        { // ks = 2: consume A, issue B(ks=3)
            VISSUE(xb0, xb1, xb2, xb3, xb4, xb5, 3)
            PA_LOAD(2)
            PV_MFMA(xa0, xa1, xa2, xa3, xa4, xa5)
        }
        { // ks = 3: consume B
            PA_LOAD(3)
            PV_MFMA(xb0, xb1, xb2, xb3, xb4, xb5)
        }
#undef PA_LOAD
#undef VISSUE
#undef PV_MFMA
    }

#pragma unroll
    for (int r = 0; r < 4; ++r) {
#pragma unroll
        for (int off = 8; off >= 1; off >>= 1)
            l_part[r] += __shfl_xor(l_part[r], off);
    }
    if (li == 0) {
#pragma unroll
        for (int r = 0; r < 4; ++r)
            lred[ch][rtq * 16 + g * 4 + r] = l_part[r];
    }
    __syncthreads();

    // ---- finalize: /l, gate by bf16 u (read-only), write bf16 gated ----
#pragma unroll
    for (int rt = 0; rt < 4; ++rt) {
#pragma unroll
        for (int r = 0; r < 4; ++r) {
            const int row = rt * 16 + g * 4 + r;
            float inv = 1.0f / (lred[0][row] + lred[1][row]);
            const ushort* ub = u_buf + (rowQ0 + row) * 768;
            ushort* gb = gated + (rowQ0 + row) * 768;
#pragma unroll
            for (int ct = 0; ct < 6; ++ct) {
                int col = w * 96 + ct * 16 + li;
                gb[col] = (ushort)bfr(o[rt][ct][r] * inv * bf2f(ub[col]));
            }
        }
    }
}

extern "C" void kernel_launch(void* const* d_in, const int* in_sizes, int n_in,
                              void* d_out, int out_size, void* d_ws, size_t ws_size,
                              hipStream_t stream)
{
    const float* x    = (const float*)d_in[0];   // [8,2048,384]
    const float* pos  = (const float*)d_in[1];   // [1,2048,256]
    const float* Wuv  = (const float*)d_in[2];   // [384,1792]
    const float* Wout = (const float*)d_in[3];   // [768,384]
    float* out = (float*)d_out;                  // [8,2048,384] f32

    ushort* u_buf = (ushort*)d_ws;                       // 16384*768 bf16 (25.2 MB)
    ushort* qk    = u_buf + (size_t)R_ * HID;            // 16384*256 bf16
    ushort* vT    = qk + (size_t)R_ * 256;               // 8*768*2048 bf16
    ushort* WuvThi  = vT + (size_t)B_ * HID * L_;
    ushort* WuvTlo  = WuvThi + (size_t)NUV * D2;
    ushort* WoutThi = WuvTlo + (size_t)NUV * D2;
    ushort* WoutTlo = WoutThi + (size_t)D2 * HID;
    ushort* gated   = WoutTlo + (size_t)D2 * HID;        // 16384*768 bf16
    ushort* xhi     = gated;                             // alias (dead after gemm1)

    size_t need = ((size_t)R_ * HID + (size_t)R_ * 256 + (size_t)B_ * HID * L_ +
                   2 * (size_t)NUV * D2 + 2 * (size_t)D2 * HID +
                   (size_t)R_ * HID) * 2;                // ~87.9 MB
    if (ws_size < need) return;

    {
        int total = D2 * NUV + HID * D2 + (R_ * D2) / 4;
        conv_all<<<dim3((total + 255) / 256), dim3(256), 0, stream>>>(
            Wuv, WuvThi, WuvTlo, Wout, WoutThi, WoutTlo, x, xhi);
    }

    gemm_2p<1><<<dim3(NUV / 128, R_ / 128), dim3(512), 0, stream>>>(
        xhi, D2, WuvThi, WuvTlo, D2, nullptr, 0, u_buf, qk, vT, D2);

    rope_bf<<<dim3(R_), dim3(128), 0, stream>>>(qk, pos);

    fused_attn17<<<dim3(256), dim3(512), 0, stream>>>(u_buf, qk, vT, gated);

    gemm_2p<0><<<dim3(D2 / 128, R_ / 128), dim3(512), 0, stream>>>(
        gated, HID, WoutThi, WoutTlo, HID, out, D2, nullptr, nullptr, nullptr, HID);
}

// Round 24
// 207.673 us; speedup vs baseline: 1.2942x; 1.0580x over previous
//
#include <hip/hip_runtime.h>
#include <hip/hip_bf16.h>
#include <math.h>

#define B_    8
#define L_    2048
#define HID   768
#define D2    384
#define NUV   1792
#define R_    16384
#define SCALE 0.08838834764831845f  // 128^-0.5

typedef __attribute__((ext_vector_type(8))) short bf16x8;
typedef __attribute__((ext_vector_type(4))) float f32x4;
typedef unsigned int uint32;
typedef unsigned short ushort;

static __device__ __forceinline__ uint32 bfr(float x) {
    uint32 u = __float_as_uint(x);
    return (u + 0x7FFFu + ((u >> 16) & 1u)) >> 16;
}
static __device__ __forceinline__ uint32 pk2(float lo, float hi) {
    return bfr(lo) | (bfr(hi) << 16);
}
static __device__ __forceinline__ float bf2f(ushort u) {
    return __uint_as_float(((uint32)u) << 16);
}
static __device__ __forceinline__ float silu_f(float x) { return x / (1.0f + __expf(-x)); }

// async global->LDS, 16B per lane (dest = wave-uniform base + lane*16)
static __device__ __forceinline__ void gld_lds16(const void* g, void* l) {
    __builtin_amdgcn_global_load_lds(
        (const __attribute__((address_space(1))) unsigned int*)g,
        (__attribute__((address_space(3))) unsigned int*)l,
        16, 0, 0);
}

// ---------------------------------------------------------------------------
// Fused pre-transform, one launch (r19-verified)
// ---------------------------------------------------------------------------
__global__ __launch_bounds__(256) void conv_all(
    const float* __restrict__ Wuv, ushort* __restrict__ WuvThi, ushort* __restrict__ WuvTlo,
    const float* __restrict__ Wout, ushort* __restrict__ WoutThi, ushort* __restrict__ WoutTlo,
    const float* __restrict__ X, ushort* __restrict__ Xhi)
{
    const int N1 = D2 * NUV;
    const int N2 = HID * D2;
    const int N3 = (R_ * D2) / 4;
    int idx = blockIdx.x * 256 + threadIdx.x;

    if (idx < N1) {
        int n = idx / D2, k = idx - n * D2;
        float v = Wuv[(size_t)k * NUV + n];
        uint32 h = bfr(v);
        WuvThi[idx] = (ushort)h;
        WuvTlo[idx] = (ushort)bfr(v - __uint_as_float(h << 16));
        return;
    }
    idx -= N1;
    if (idx < N2) {
        int n = idx / HID, k = idx - n * HID;
        float v = Wout[(size_t)k * D2 + n];
        uint32 h = bfr(v);
        WoutThi[idx] = (ushort)h;
        WoutTlo[idx] = (ushort)bfr(v - __uint_as_float(h << 16));
        return;
    }
    idx -= N2;
    if (idx < N3) {
        float4 v = *(const float4*)(X + (size_t)idx * 4);
        uint2 p; p.x = pk2(v.x, v.y); p.y = pk2(v.z, v.w);
        *(uint2*)(Xhi + (size_t)idx * 4) = p;
    }
}

// ---------------------------------------------------------------------------
// Bf16-A 2-pass GEMM core with global_load_lds staging (rule-21 pattern:
// linear LDS dest + inverse-swizzled per-lane global source + swizzled read).
// EPI 0: plain f32 C.  EPI 1: GAU GEMM1 epilogue (u stored bf16).
// ---------------------------------------------------------------------------
template<int EPI>
__global__ __launch_bounds__(512, 4) void gemm_2p(
    const ushort* __restrict__ Ahi, int lda,
    const ushort* __restrict__ BThi, const ushort* __restrict__ BTlo, int ldbt,
    float* __restrict__ C, int ldc,
    ushort* __restrict__ u_buf, ushort* __restrict__ qk, ushort* __restrict__ vT,
    int K)
{
    __shared__ unsigned char As[128 * 128];
    __shared__ unsigned char Bs[128 * 256];

    const int t  = threadIdx.x;
    const int w  = t >> 6;
    const int l  = t & 63;
    const int g  = l >> 4;
    const int li = l & 15;
    const int wr = w >> 1;
    const int wc = w & 1;
    const int m0 = blockIdx.y * 128;
    const int n0 = blockIdx.x * 128;

    f32x4 acc[2][4];
#pragma unroll
    for (int i = 0; i < 2; ++i)
#pragma unroll
        for (int j = 0; j < 4; ++j) acc[i][j] = (f32x4){0.f, 0.f, 0.f, 0.f};

    // staging geometry (thread-fixed)
    const int arow0 = t >> 3;             // A chunk: [row][c8], linear dest
    const int ac8   = t & 7;
    const int bcol0 = t >> 4;             // B chunk: [c][s16], linear dest
    const int bs16  = t & 15;

    for (int k0 = 0; k0 < K; k0 += 64) {
        // ---- A: 1024 x 16B chunks, direct global->LDS ----
#pragma unroll
        for (int i = 0; i < 2; ++i) {
            int idx = t + i * 512;
            int row = arow0 + i * 64;
            gld_lds16(Ahi + (size_t)(m0 + row) * lda + k0 + ((ac8 ^ (row & 7)) * 8),
                      &As[idx * 16]);
        }
        // ---- B: 2048 x 16B chunks, direct global->LDS (hi/lo by logical chunk) ----
#pragma unroll
        for (int i = 0; i < 4; ++i) {
            int idx = t + i * 512;
            int c   = bcol0 + i * 32;
            int sl  = bs16 ^ (c & 7);     // bit3 (hi/lo) invariant under 3-bit XOR
            const ushort* src = (sl < 8)
                ? (BThi + (long long)(n0 + c) * ldbt + k0 + sl * 8)
                : (BTlo + (long long)(n0 + c) * ldbt + k0 + (sl - 8) * 8);
            gld_lds16(src, &Bs[idx * 16]);
        }
        __syncthreads();   // drains vmcnt (incl. global_load_lds) + barrier

#pragma unroll
        for (int ks = 0; ks < 2; ++ks) {
            bf16x8 ah[2], bh[4], bl[4];
#pragma unroll
            for (int mi = 0; mi < 2; ++mi) {
                int row = wr * 32 + mi * 16 + li;
                ah[mi] = *(const bf16x8*)&As[row * 128 + ((ks * 64 + g * 16) ^ ((row & 7) << 4))];
            }
#pragma unroll
            for (int ni = 0; ni < 4; ++ni) {
                int col = wc * 64 + ni * 16 + li;
                int off = (ks * 64 + g * 16) ^ ((col & 7) << 4);
                bh[ni] = *(const bf16x8*)&Bs[col * 256 + off];
                bl[ni] = *(const bf16x8*)&Bs[col * 256 + 128 + off];
            }
#pragma unroll
            for (int mi = 0; mi < 2; ++mi)
#pragma unroll
                for (int ni = 0; ni < 4; ++ni) {
                    acc[mi][ni] = __builtin_amdgcn_mfma_f32_16x16x32_bf16(ah[mi], bh[ni], acc[mi][ni], 0, 0, 0);
                    acc[mi][ni] = __builtin_amdgcn_mfma_f32_16x16x32_bf16(ah[mi], bl[ni], acc[mi][ni], 0, 0, 0);
                }
        }
        __syncthreads();
    }

    if (EPI == 0) {
#pragma unroll
        for (int mi = 0; mi < 2; ++mi)
#pragma unroll
            for (int ni = 0; ni < 4; ++ni) {
                int col = n0 + wc * 64 + ni * 16 + li;
#pragma unroll
                for (int r = 0; r < 4; ++r) {
                    int row = m0 + wr * 32 + mi * 16 + g * 4 + r;
                    C[(long long)row * ldc + col] = acc[mi][ni][r];
                }
            }
    } else {
        if (n0 < 768) {
#pragma unroll
            for (int mi = 0; mi < 2; ++mi)
#pragma unroll
                for (int ni = 0; ni < 4; ++ni) {
                    int col = n0 + wc * 64 + ni * 16 + li;
#pragma unroll
                    for (int r = 0; r < 4; ++r) {
                        int row = m0 + wr * 32 + mi * 16 + g * 4 + r;
                        u_buf[(size_t)row * 768 + col] = (ushort)bfr(silu_f(acc[mi][ni][r]));
                    }
                }
        } else if (n0 < 1536) {
            int bb = m0 >> 11;
            int llb = (m0 & 2047) + wr * 32 + g * 4;
#pragma unroll
            for (int mi = 0; mi < 2; ++mi) {
                int ll = llb + mi * 16;
#pragma unroll
                for (int ni = 0; ni < 4; ++ni) {
                    int cv = n0 + wc * 64 + ni * 16 + li - 768;
                    ushort* vb = vT + ((size_t)bb * 768 + cv) * 2048 + ll;
                    *(uint32*)(vb)     = pk2(silu_f(acc[mi][ni][0]), silu_f(acc[mi][ni][1]));
                    *(uint32*)(vb + 2) = pk2(silu_f(acc[mi][ni][2]), silu_f(acc[mi][ni][3]));
                }
            }
        } else {
#pragma unroll
            for (int mi = 0; mi < 2; ++mi)
#pragma unroll
                for (int ni = 0; ni < 4; ++ni) {
                    int qcol = n0 + wc * 64 + ni * 16 + li - 1536;
#pragma unroll
                    for (int r = 0; r < 4; ++r) {
                        int row = m0 + wr * 32 + mi * 16 + g * 4 + r;
                        qk[(size_t)row * 256 + qcol] = (ushort)bfr(acc[mi][ni][r]);
                    }
                }
        }
    }
}

// ---------------------------------------------------------------------------
// RoPE in place on bf16 qk buffer
// ---------------------------------------------------------------------------
__global__ __launch_bounds__(128) void rope_bf(ushort* __restrict__ qk,
                                               const float* __restrict__ pos)
{
    int row = blockIdx.x;
    int lpos = row & (L_ - 1);
    int t = threadIdx.x;
    int j = t & 63;
    int isK = t >> 6;
    ushort* base = qk + (size_t)row * 256 + isK * 128;
    float s = pos[lpos * 256 + j];
    float c = pos[lpos * 256 + 64 + j];
    float x1 = bf2f(base[j]);
    float x2 = bf2f(base[64 + j]);
    base[j]      = (ushort)bfr(x1 * c - x2 * s);
    base[64 + j] = (ushort)bfr(x2 * c + x1 * s);
}

// ---------------------------------------------------------------------------
// MFMA flash attention v17 (r23 winner, byte-identical): V software pipeline,
// dbuf K/P, 1 barrier/tile, setprio, bf16 u. Grid 256, 512 thr (8 waves).
// ---------------------------------------------------------------------------
__global__ __launch_bounds__(512) void fused_attn17(
    const ushort* __restrict__ u_buf, const ushort* __restrict__ qk,
    const ushort* __restrict__ vT, ushort* __restrict__ gated)
{
    __shared__ unsigned char KbB[2][128 * 256];   // K bf16 dbuf (64 KB)
    __shared__ unsigned char PbB[2][64 * 256];    // P bf16 dbuf (32 KB)
    __shared__ float lred[2][64];

    const int t  = threadIdx.x;
    const int w  = t >> 6;
    const int l  = t & 63;
    const int g  = l >> 4;
    const int li = l & 15;

    const int b  = blockIdx.x & 7;
    const int qt = blockIdx.x >> 3;
    const long long rowQ0 = (long long)b * L_ + (long long)qt * 64;
    const long long rowB0 = (long long)b * L_;

    const int rtq = w >> 1;
    const int ch  = w & 1;

    bf16x8 qf[4];
    {
        const ushort* qrow = qk + (rowQ0 + rtq * 16 + li) * 256;
#pragma unroll
        for (int ks = 0; ks < 4; ++ks)
            qf[ks] = *(const bf16x8*)&qrow[ks * 32 + g * 8];
    }

    float l_part[4] = {0.f, 0.f, 0.f, 0.f};

    f32x4 o[4][6];
#pragma unroll
    for (int rt = 0; rt < 4; ++rt)
#pragma unroll
        for (int ct = 0; ct < 6; ++ct)
            o[rt][ct] = (f32x4){0.f, 0.f, 0.f, 0.f};

    const ushort* vrow = vT + ((size_t)b * 768 + w * 96 + li) * 2048 + g * 8;

    const int kr  = t >> 4;
    const int c16 = t & 15;
    const int ksw = (c16 * 16) ^ ((kr & 7) << 4);

    union U16 { uint4 u; bf16x8 bv; };

    // prologue: prefetch K(0), publish into Kb[0], barrier, prefetch K(1)
    uint4 kA = *(const uint4*)&qk[(rowB0 + kr)      * 256 + 128 + c16 * 8];
    uint4 kB = *(const uint4*)&qk[(rowB0 + kr + 32) * 256 + 128 + c16 * 8];
    uint4 kC = *(const uint4*)&qk[(rowB0 + kr + 64) * 256 + 128 + c16 * 8];
    uint4 kD = *(const uint4*)&qk[(rowB0 + kr + 96) * 256 + 128 + c16 * 8];
    *(uint4*)&KbB[0][(kr)      * 256 + ksw] = kA;
    *(uint4*)&KbB[0][(kr + 32) * 256 + ksw] = kB;
    *(uint4*)&KbB[0][(kr + 64) * 256 + ksw] = kC;
    *(uint4*)&KbB[0][(kr + 96) * 256 + ksw] = kD;
    __syncthreads();
    {
        const ushort* kn = qk + (rowB0 + 128 + kr) * 256 + 128 + c16 * 8;
        kA = *(const uint4*)(kn);
        kB = *(const uint4*)(kn + (size_t)32 * 256);
        kC = *(const uint4*)(kn + (size_t)64 * 256);
        kD = *(const uint4*)(kn + (size_t)96 * 256);
    }

    for (int jt = 0; jt < 16; ++jt) {
        const unsigned char* Kb = &KbB[jt & 1][0];
        unsigned char* Pb = &PbB[jt & 1][0];
        const ushort* vj = vrow + jt * 128;

        // ---- QK: 4 S-tiles + exp + Pb write + l accumulation ----
        __builtin_amdgcn_s_setprio(1);
#pragma unroll
        for (int ci = 0; ci < 4; ++ci) {
            const int ct = ch * 4 + ci;
            const int krow = ct * 16 + li;
            const int rs = (krow & 7) << 4;
            f32x4 s = {0.f, 0.f, 0.f, 0.f};
#pragma unroll
            for (int ks = 0; ks < 4; ++ks) {
                bf16x8 kf = *(const bf16x8*)&Kb[krow * 256 + ((ks * 64 + g * 16) ^ rs)];
                s = __builtin_amdgcn_mfma_f32_16x16x32_bf16(qf[ks], kf, s, 0, 0, 0);
            }
#pragma unroll
            for (int r = 0; r < 4; ++r) {
                float p = __expf(SCALE * s[r]);
                l_part[r] += p;
                const int prow = rtq * 16 + g * 4 + r;
                *(ushort*)&Pb[prow * 256 + (((ct * 16 + li) * 2) ^ ((prow & 7) << 4))]
                    = (ushort)bfr(p);
            }
        }
        __builtin_amdgcn_s_setprio(0);

        // ---- publish K(jt+1) into the other buffer (before the barrier) ----
        if (jt + 1 < 16) {
            unsigned char* Kn = &KbB[(jt + 1) & 1][0];
            *(uint4*)&Kn[(kr)      * 256 + ksw] = kA;
            *(uint4*)&Kn[(kr + 32) * 256 + ksw] = kB;
            *(uint4*)&Kn[(kr + 64) * 256 + ksw] = kC;
            *(uint4*)&Kn[(kr + 96) * 256 + ksw] = kD;
        }

        // ---- issue V(ks=0): arrives while waiting at the barrier ----
        U16 xa0, xa1, xa2, xa3, xa4, xa5;      // bank A
        xa0.u = *(const uint4*)(vj + (size_t)(0 * 16) * 2048);
        xa1.u = *(const uint4*)(vj + (size_t)(1 * 16) * 2048);
        xa2.u = *(const uint4*)(vj + (size_t)(2 * 16) * 2048);
        xa3.u = *(const uint4*)(vj + (size_t)(3 * 16) * 2048);
        xa4.u = *(const uint4*)(vj + (size_t)(4 * 16) * 2048);
        xa5.u = *(const uint4*)(vj + (size_t)(5 * 16) * 2048);

        __syncthreads();   // Pb(jt) ready AND K(jt+1) visible; V(ks0) drained

        // ---- prefetch K(jt+2) (drains at NEXT barrier) ----
        if (jt + 2 < 16) {
            const ushort* kn = qk + (rowB0 + (jt + 2) * 128 + kr) * 256 + 128 + c16 * 8;
            kA = *(const uint4*)(kn);
            kB = *(const uint4*)(kn + (size_t)32 * 256);
            kC = *(const uint4*)(kn + (size_t)64 * 256);
            kD = *(const uint4*)(kn + (size_t)96 * 256);
        }

        // ---- PV: 2-deep V rotation; per ks: pa[4] + V[6], 24 MFMA ----
        U16 xb0, xb1, xb2, xb3, xb4, xb5;      // bank B

#define PA_LOAD(KS) \
        bf16x8 pa0 = *(const bf16x8*)&Pb[(0 * 16 + li) * 256 + (((KS) * 64 + g * 16) ^ ((li & 7) << 4))]; \
        bf16x8 pa1 = *(const bf16x8*)&Pb[(1 * 16 + li) * 256 + (((KS) * 64 + g * 16) ^ ((li & 7) << 4))]; \
        bf16x8 pa2 = *(const bf16x8*)&Pb[(2 * 16 + li) * 256 + (((KS) * 64 + g * 16) ^ ((li & 7) << 4))]; \
        bf16x8 pa3 = *(const bf16x8*)&Pb[(3 * 16 + li) * 256 + (((KS) * 64 + g * 16) ^ ((li & 7) << 4))];
#define VISSUE(B0, B1, B2, B3, B4, B5, KS) \
        B0.u = *(const uint4*)(vj + (size_t)(0 * 16) * 2048 + (KS) * 32); \
        B1.u = *(const uint4*)(vj + (size_t)(1 * 16) * 2048 + (KS) * 32); \
        B2.u = *(const uint4*)(vj + (size_t)(2 * 16) * 2048 + (KS) * 32); \
        B3.u = *(const uint4*)(vj + (size_t)(3 * 16) * 2048 + (KS) * 32); \
        B4.u = *(const uint4*)(vj + (size_t)(4 * 16) * 2048 + (KS) * 32); \
        B5.u = *(const uint4*)(vj + (size_t)(5 * 16) * 2048 + (KS) * 32);
#define PV_MFMA(B0, B1, B2, B3, B4, B5) \
        __builtin_amdgcn_s_setprio(1); \
        o[0][0] = __builtin_amdgcn_mfma_f32_16x16x32_bf16(pa0, B0.bv, o[0][0], 0, 0, 0); \
        o[1][0] = __builtin_amdgcn_mfma_f32_16x16x32_bf16(pa1, B0.bv, o[1][0], 0, 0, 0); \
        o[2][0] = __builtin_amdgcn_mfma_f32_16x16x32_bf16(pa2, B0.bv, o[2][0], 0, 0, 0); \
        o[3][0] = __builtin_amdgcn_mfma_f32_16x16x32_bf16(pa3, B0.bv, o[3][0], 0, 0, 0); \
        o[0][1] = __builtin_amdgcn_mfma_f32_16x16x32_bf16(pa0, B1.bv, o[0][1], 0, 0, 0); \
        o[1][1] = __builtin_amdgcn_mfma_f32_16x16x32_bf16(pa1, B1.bv, o[1][1], 0, 0, 0); \
        o[2][1] = __builtin_amdgcn_mfma_f32_16x16x32_bf16(pa2, B1.bv, o[2][1], 0, 0, 0); \
        o[3][1] = __builtin_amdgcn_mfma_f32_16x16x32_bf16(pa3, B1.bv, o[3][1], 0, 0, 0); \
        o[0][2] = __builtin_amdgcn_mfma_f32_16x16x32_bf16(pa0, B2.bv, o[0][2], 0, 0, 0); \
        o[1][2] = __builtin_amdgcn_mfma_f32_16x16x32_bf16(pa1, B2.bv, o[1][2], 0, 0, 0); \
        o[2][2] = __builtin_amdgcn_mfma_f32_16x16x32_bf16(pa2, B2.bv, o[2][2], 0, 0, 0); \
        o[3][2] = __builtin_amdgcn_mfma_f32_16x16x32_bf16(pa3, B2.bv, o[3][2], 0, 0, 0); \
        o[0][3] = __builtin_amdgcn_mfma_f32_16x16x32_bf16(pa0, B3.bv, o[0][3], 0, 0, 0); \
        o[1][3] = __builtin_amdgcn_mfma_f32_16x16x32_bf16(pa1, B3.bv, o[1][3], 0, 0, 0); \
        o[2][3] = __builtin_amdgcn_mfma_f32_16x16x32_bf16(pa2, B3.bv, o[2][3], 0, 0, 0); \
        o[3][3] = __builtin_amdgcn_mfma_f32_16x16x32_bf16(pa3, B3.bv, o[3][3], 0, 0, 0); \
        o[0][4] = __builtin_amdgcn_mfma_f32_16x16x32_bf16(pa0, B4.bv, o[0][4], 0, 0, 0); \
        o[1][4] = __builtin_amdgcn_mfma_f32_16x16x32_bf16(pa1, B4.bv, o[1][4], 0, 0, 0); \
        o[2][4] = __builtin_amdgcn_mfma_f32_16x16x32_bf16(pa2, B4.bv, o[2][4], 0, 0, 0); \
        o[3][4] = __builtin_amdgcn_mfma_f32_16x16x32_bf16(pa3, B4.bv, o[3][4], 0, 0, 0); \
        o[0][5] = __builtin_amdgcn_mfma_f32_16x16x32_bf16(pa0, B5.bv, o[0][5], 0, 0, 0); \
        o[1][5] = __builtin_amdgcn_mfma_f32_16x16x32_bf16(pa1, B5.bv, o[1][5], 0, 0, 0); \
        o[2][5] = __builtin_amdgcn_mfma_f32_16x16x32_bf16(pa2, B5.bv, o[2][5], 0, 0, 0); \
        o[3][5] = __builtin_amdgcn_mfma_f32_16x16x32_bf16(pa3, B5.bv, o[3][5], 0, 0, 0); \
        __builtin_amdgcn_s_setprio(0);

        { // ks = 0: consume A, issue B(ks=1)
            VISSUE(xb0, xb1, xb2, xb3, xb4, xb5, 1)
            PA_LOAD(0)
            PV_MFMA(xa0, xa1, xa2, xa3, xa4, xa5)
        }
        { // ks = 1: consume B, issue A(ks=2)
            VISSUE(xa0, xa1, xa2, xa3, xa4, xa5, 2)
            PA_LOAD(1)
            PV_MFMA(xb0, xb1, xb2, xb3, xb4, xb5)
        }
        { // ks = 2: consume A, issue B(ks=3)
            VISSUE(xb0, xb1, xb2, xb3, xb4, xb5, 3)
            PA_LOAD(2)
            PV_MFMA(xa0, xa1, xa2, xa3, xa4, xa5)
        }
        { // ks = 3: consume B
            PA_LOAD(3)
            PV_MFMA(xb0, xb1, xb2, xb3, xb4, xb5)
        }
#undef PA_LOAD
#undef VISSUE
#undef PV_MFMA
    }

#pragma unroll
    for (int r = 0; r < 4; ++r) {
#pragma unroll
        for (int off = 8; off >= 1; off >>= 1)
            l_part[r] += __shfl_xor(l_part[r], off);
    }
    if (li == 0) {
#pragma unroll
        for (int r = 0; r < 4; ++r)
            lred[ch][rtq * 16 + g * 4 + r] = l_part[r];
    }
    __syncthreads();

    // ---- finalize: /l, gate by bf16 u (read-only), write bf16 gated ----
#pragma unroll
    for (int rt = 0; rt < 4; ++rt) {
#pragma unroll
        for (int r = 0; r < 4; ++r) {
            const int row = rt * 16 + g * 4 + r;
            float inv = 1.0f / (lred[0][row] + lred[1][row]);
            const ushort* ub = u_buf + (rowQ0 + row) * 768;
            ushort* gb = gated + (rowQ0 + row) * 768;
#pragma unroll
            for (int ct = 0; ct < 6; ++ct) {
                int col = w * 96 + ct * 16 + li;
                gb[col] = (ushort)bfr(o[rt][ct][r] * inv * bf2f(ub[col]));
            }
        }
    }
}

extern "C" void kernel_launch(void* const* d_in, const int* in_sizes, int n_in,
                              void* d_out, int out_size, void* d_ws, size_t ws_size,
                              hipStream_t stream)
{
    const float* x    = (const float*)d_in[0];   // [8,2048,384]
    const float* pos  = (const float*)d_in[1];   // [1,2048,256]
    const float* Wuv  = (const float*)d_in[2];   // [384,1792]
    const float* Wout = (const float*)d_in[3];   // [768,384]
    float* out = (float*)d_out;                  // [8,2048,384] f32

    ushort* u_buf = (ushort*)d_ws;                       // 16384*768 bf16
    ushort* qk    = u_buf + (size_t)R_ * HID;            // 16384*256 bf16
    ushort* vT    = qk + (size_t)R_ * 256;               // 8*768*2048 bf16
    ushort* WuvThi  = vT + (size_t)B_ * HID * L_;
    ushort* WuvTlo  = WuvThi + (size_t)NUV * D2;
    ushort* WoutThi = WuvTlo + (size_t)NUV * D2;
    ushort* WoutTlo = WoutThi + (size_t)D2 * HID;
    ushort* gated   = WoutTlo + (size_t)D2 * HID;        // 16384*768 bf16
    ushort* xhi     = gated;                             // alias (dead after gemm1)

    size_t need = ((size_t)R_ * HID + (size_t)R_ * 256 + (size_t)B_ * HID * L_ +
                   2 * (size_t)NUV * D2 + 2 * (size_t)D2 * HID +
                   (size_t)R_ * HID) * 2;                // ~87.9 MB
    if (ws_size < need) return;

    {
        int total = D2 * NUV + HID * D2 + (R_ * D2) / 4;
        conv_all<<<dim3((total + 255) / 256), dim3(256), 0, stream>>>(
            Wuv, WuvThi, WuvTlo, Wout, WoutThi, WoutTlo, x, xhi);
    }

    gemm_2p<1><<<dim3(NUV / 128, R_ / 128), dim3(512), 0, stream>>>(
        xhi, D2, WuvThi, WuvTlo, D2, nullptr, 0, u_buf, qk, vT, D2);

    rope_bf<<<dim3(R_), dim3(128), 0, stream>>>(qk, pos);

    fused_attn17<<<dim3(256), dim3(512), 0, stream>>>(u_buf, qk, vT, gated);

    gemm_2p<0><<<dim3(D2 / 128, R_ / 128), dim3(512), 0, stream>>>(
        gated, HID, WoutThi, WoutTlo, HID, out, D2, nullptr, nullptr, nullptr, HID);
}

// Round 25
// 203.464 us; speedup vs baseline: 1.3210x; 1.0207x over previous
//
#include <hip/hip_runtime.h>
#include <hip/hip_bf16.h>
#include <math.h>

#define B_    8
#define L_    2048
#define HID   768
#define D2    384
#define NUV   1792
#define R_    16384
#define SCALE 0.08838834764831845f  // 128^-0.5

typedef __attribute__((ext_vector_type(8))) short bf16x8;
typedef __attribute__((ext_vector_type(4))) float f32x4;
typedef unsigned int uint32;
typedef unsigned short ushort;

static __device__ __forceinline__ uint32 bfr(float x) {
    uint32 u = __float_as_uint(x);
    return (u + 0x7FFFu + ((u >> 16) & 1u)) >> 16;
}
static __device__ __forceinline__ uint32 pk2(float lo, float hi) {
    return bfr(lo) | (bfr(hi) << 16);
}
static __device__ __forceinline__ float bf2f(ushort u) {
    return __uint_as_float(((uint32)u) << 16);
}
static __device__ __forceinline__ float silu_f(float x) { return x / (1.0f + __expf(-x)); }

// async global->LDS, 16B per lane (dest = wave-uniform base + lane*16)
static __device__ __forceinline__ void gld_lds16(const void* g, void* l) {
    __builtin_amdgcn_global_load_lds(
        (const __attribute__((address_space(1))) unsigned int*)g,
        (__attribute__((address_space(3))) unsigned int*)l,
        16, 0, 0);
}

// ---------------------------------------------------------------------------
// Fused pre-transform, one launch (r19-verified)
// ---------------------------------------------------------------------------
__global__ __launch_bounds__(256) void conv_all(
    const float* __restrict__ Wuv, ushort* __restrict__ WuvThi, ushort* __restrict__ WuvTlo,
    const float* __restrict__ Wout, ushort* __restrict__ WoutThi, ushort* __restrict__ WoutTlo,
    const float* __restrict__ X, ushort* __restrict__ Xhi)
{
    const int N1 = D2 * NUV;
    const int N2 = HID * D2;
    const int N3 = (R_ * D2) / 4;
    int idx = blockIdx.x * 256 + threadIdx.x;

    if (idx < N1) {
        int n = idx / D2, k = idx - n * D2;
        float v = Wuv[(size_t)k * NUV + n];
        uint32 h = bfr(v);
        WuvThi[idx] = (ushort)h;
        WuvTlo[idx] = (ushort)bfr(v - __uint_as_float(h << 16));
        return;
    }
    idx -= N1;
    if (idx < N2) {
        int n = idx / HID, k = idx - n * HID;
        float v = Wout[(size_t)k * D2 + n];
        uint32 h = bfr(v);
        WoutThi[idx] = (ushort)h;
        WoutTlo[idx] = (ushort)bfr(v - __uint_as_float(h << 16));
        return;
    }
    idx -= N2;
    if (idx < N3) {
        float4 v = *(const float4*)(X + (size_t)idx * 4);
        uint2 p; p.x = pk2(v.x, v.y); p.y = pk2(v.z, v.w);
        *(uint2*)(Xhi + (size_t)idx * 4) = p;
    }
}

// ---------------------------------------------------------------------------
// Bf16-A 2-pass GEMM with global_load_lds staging (r24-verified).
// EPI 0: plain f32 C.
// EPI 1: GAU GEMM1 epilogue — u bf16, vT transposed, q/k with FUSED RoPE
//        (bf16 tile staged in Bs, halves exchanged, pos applied in f32).
// ---------------------------------------------------------------------------
template<int EPI>
__global__ __launch_bounds__(512, 4) void gemm_2p(
    const ushort* __restrict__ Ahi, int lda,
    const ushort* __restrict__ BThi, const ushort* __restrict__ BTlo, int ldbt,
    float* __restrict__ C, int ldc,
    ushort* __restrict__ u_buf, ushort* __restrict__ qk, ushort* __restrict__ vT,
    const float* __restrict__ pos, int K)
{
    __shared__ unsigned char As[128 * 128];
    __shared__ unsigned char Bs[128 * 256];

    const int t  = threadIdx.x;
    const int w  = t >> 6;
    const int l  = t & 63;
    const int g  = l >> 4;
    const int li = l & 15;
    const int wr = w >> 1;
    const int wc = w & 1;
    const int m0 = blockIdx.y * 128;
    const int n0 = blockIdx.x * 128;

    f32x4 acc[2][4];
#pragma unroll
    for (int i = 0; i < 2; ++i)
#pragma unroll
        for (int j = 0; j < 4; ++j) acc[i][j] = (f32x4){0.f, 0.f, 0.f, 0.f};

    // staging geometry (thread-fixed)
    const int arow0 = t >> 3;
    const int ac8   = t & 7;
    const int bcol0 = t >> 4;
    const int bs16  = t & 15;

    for (int k0 = 0; k0 < K; k0 += 64) {
#pragma unroll
        for (int i = 0; i < 2; ++i) {
            int idx = t + i * 512;
            int row = arow0 + i * 64;
            gld_lds16(Ahi + (size_t)(m0 + row) * lda + k0 + ((ac8 ^ (row & 7)) * 8),
                      &As[idx * 16]);
        }
#pragma unroll
        for (int i = 0; i < 4; ++i) {
            int idx = t + i * 512;
            int c   = bcol0 + i * 32;
            int sl  = bs16 ^ (c & 7);
            const ushort* src = (sl < 8)
                ? (BThi + (long long)(n0 + c) * ldbt + k0 + sl * 8)
                : (BTlo + (long long)(n0 + c) * ldbt + k0 + (sl - 8) * 8);
            gld_lds16(src, &Bs[idx * 16]);
        }
        __syncthreads();

#pragma unroll
        for (int ks = 0; ks < 2; ++ks) {
            bf16x8 ah[2], bh[4], bl[4];
#pragma unroll
            for (int mi = 0; mi < 2; ++mi) {
                int row = wr * 32 + mi * 16 + li;
                ah[mi] = *(const bf16x8*)&As[row * 128 + ((ks * 64 + g * 16) ^ ((row & 7) << 4))];
            }
#pragma unroll
            for (int ni = 0; ni < 4; ++ni) {
                int col = wc * 64 + ni * 16 + li;
                int off = (ks * 64 + g * 16) ^ ((col & 7) << 4);
                bh[ni] = *(const bf16x8*)&Bs[col * 256 + off];
                bl[ni] = *(const bf16x8*)&Bs[col * 256 + 128 + off];
            }
#pragma unroll
            for (int mi = 0; mi < 2; ++mi)
#pragma unroll
                for (int ni = 0; ni < 4; ++ni) {
                    acc[mi][ni] = __builtin_amdgcn_mfma_f32_16x16x32_bf16(ah[mi], bh[ni], acc[mi][ni], 0, 0, 0);
                    acc[mi][ni] = __builtin_amdgcn_mfma_f32_16x16x32_bf16(ah[mi], bl[ni], acc[mi][ni], 0, 0, 0);
                }
        }
        __syncthreads();
    }

    if (EPI == 0) {
#pragma unroll
        for (int mi = 0; mi < 2; ++mi)
#pragma unroll
            for (int ni = 0; ni < 4; ++ni) {
                int col = n0 + wc * 64 + ni * 16 + li;
#pragma unroll
                for (int r = 0; r < 4; ++r) {
                    int row = m0 + wr * 32 + mi * 16 + g * 4 + r;
                    C[(long long)row * ldc + col] = acc[mi][ni][r];
                }
            }
    } else {
        if (n0 < 768) {
#pragma unroll
            for (int mi = 0; mi < 2; ++mi)
#pragma unroll
                for (int ni = 0; ni < 4; ++ni) {
                    int col = n0 + wc * 64 + ni * 16 + li;
#pragma unroll
                    for (int r = 0; r < 4; ++r) {
                        int row = m0 + wr * 32 + mi * 16 + g * 4 + r;
                        u_buf[(size_t)row * 768 + col] = (ushort)bfr(silu_f(acc[mi][ni][r]));
                    }
                }
        } else if (n0 < 1536) {
            int bb = m0 >> 11;
            int llb = (m0 & 2047) + wr * 32 + g * 4;
#pragma unroll
            for (int mi = 0; mi < 2; ++mi) {
                int ll = llb + mi * 16;
#pragma unroll
                for (int ni = 0; ni < 4; ++ni) {
                    int cv = n0 + wc * 64 + ni * 16 + li - 768;
                    ushort* vb = vT + ((size_t)bb * 768 + cv) * 2048 + ll;
                    *(uint32*)(vb)     = pk2(silu_f(acc[mi][ni][0]), silu_f(acc[mi][ni][1]));
                    *(uint32*)(vb + 2) = pk2(silu_f(acc[mi][ni][2]), silu_f(acc[mi][ni][3]));
                }
            }
        } else {
            // q/k with FUSED RoPE. Stage bf16 tile in Bs (32KB, free after
            // final k-loop barrier), exchange (j, j+64) halves, apply rope.
            // Numerics identical to the standalone rope_bf path.
            ushort* Qs = (ushort*)Bs;   // [128 rows][128 cols]
#pragma unroll
            for (int mi = 0; mi < 2; ++mi)
#pragma unroll
                for (int ni = 0; ni < 4; ++ni) {
                    int coll = wc * 64 + ni * 16 + li;
#pragma unroll
                    for (int r = 0; r < 4; ++r) {
                        int rowl = wr * 32 + mi * 16 + g * 4 + r;
                        Qs[rowl * 128 + coll] = (ushort)bfr(acc[mi][ni][r]);
                    }
                }
            __syncthreads();
            const int qcol0 = n0 - 1536;   // 0 for q, 128 for k
#pragma unroll
            for (int mi = 0; mi < 2; ++mi)
#pragma unroll
                for (int ni = 0; ni < 4; ++ni) {
                    int coll = wc * 64 + ni * 16 + li;
                    int j = coll & 63;
#pragma unroll
                    for (int r = 0; r < 4; ++r) {
                        int rowl = wr * 32 + mi * 16 + g * 4 + r;
                        int rowg = m0 + rowl;
                        int lpos = rowg & (L_ - 1);
                        float sn = pos[lpos * 256 + j];
                        float cs = pos[lpos * 256 + 64 + j];
                        float x1 = bf2f(Qs[rowl * 128 + j]);
                        float x2 = bf2f(Qs[rowl * 128 + 64 + j]);
                        float v = (coll < 64) ? (x1 * cs - x2 * sn)
                                              : (x2 * cs + x1 * sn);
                        qk[(size_t)rowg * 256 + qcol0 + coll] = (ushort)bfr(v);
                    }
                }
        }
    }
}

// ---------------------------------------------------------------------------
// MFMA flash attention v17 (r23/r24 winner, byte-identical): V software
// pipeline, dbuf K/P, 1 barrier/tile, setprio, bf16 u. Grid 256, 512 thr.
// ---------------------------------------------------------------------------
__global__ __launch_bounds__(512) void fused_attn17(
    const ushort* __restrict__ u_buf, const ushort* __restrict__ qk,
    const ushort* __restrict__ vT, ushort* __restrict__ gated)
{
    __shared__ unsigned char KbB[2][128 * 256];   // K bf16 dbuf (64 KB)
    __shared__ unsigned char PbB[2][64 * 256];    // P bf16 dbuf (32 KB)
    __shared__ float lred[2][64];

    const int t  = threadIdx.x;
    const int w  = t >> 6;
    const int l  = t & 63;
    const int g  = l >> 4;
    const int li = l & 15;

    const int b  = blockIdx.x & 7;
    const int qt = blockIdx.x >> 3;
    const long long rowQ0 = (long long)b * L_ + (long long)qt * 64;
    const long long rowB0 = (long long)b * L_;

    const int rtq = w >> 1;
    const int ch  = w & 1;

    bf16x8 qf[4];
    {
        const ushort* qrow = qk + (rowQ0 + rtq * 16 + li) * 256;
#pragma unroll
        for (int ks = 0; ks < 4; ++ks)
            qf[ks] = *(const bf16x8*)&qrow[ks * 32 + g * 8];
    }

    float l_part[4] = {0.f, 0.f, 0.f, 0.f};

    f32x4 o[4][6];
#pragma unroll
    for (int rt = 0; rt < 4; ++rt)
#pragma unroll
        for (int ct = 0; ct < 6; ++ct)
            o[rt][ct] = (f32x4){0.f, 0.f, 0.f, 0.f};

    const ushort* vrow = vT + ((size_t)b * 768 + w * 96 + li) * 2048 + g * 8;

    const int kr  = t >> 4;
    const int c16 = t & 15;
    const int ksw = (c16 * 16) ^ ((kr & 7) << 4);

    union U16 { uint4 u; bf16x8 bv; };

    // prologue: prefetch K(0), publish into Kb[0], barrier, prefetch K(1)
    uint4 kA = *(const uint4*)&qk[(rowB0 + kr)      * 256 + 128 + c16 * 8];
    uint4 kB = *(const uint4*)&qk[(rowB0 + kr + 32) * 256 + 128 + c16 * 8];
    uint4 kC = *(const uint4*)&qk[(rowB0 + kr + 64) * 256 + 128 + c16 * 8];
    uint4 kD = *(const uint4*)&qk[(rowB0 + kr + 96) * 256 + 128 + c16 * 8];
    *(uint4*)&KbB[0][(kr)      * 256 + ksw] = kA;
    *(uint4*)&KbB[0][(kr + 32) * 256 + ksw] = kB;
    *(uint4*)&KbB[0][(kr + 64) * 256 + ksw] = kC;
    *(uint4*)&KbB[0][(kr + 96) * 256 + ksw] = kD;
    __syncthreads();
    {
        const ushort* kn = qk + (rowB0 + 128 + kr) * 256 + 128 + c16 * 8;
        kA = *(const uint4*)(kn);
        kB = *(const uint4*)(kn + (size_t)32 * 256);
        kC = *(const uint4*)(kn + (size_t)64 * 256);
        kD = *(const uint4*)(kn + (size_t)96 * 256);
    }

    for (int jt = 0; jt < 16; ++jt) {
        const unsigned char* Kb = &KbB[jt & 1][0];
        unsigned char* Pb = &PbB[jt & 1][0];
        const ushort* vj = vrow + jt * 128;

        // ---- QK: 4 S-tiles + exp + Pb write + l accumulation ----
        __builtin_amdgcn_s_setprio(1);
#pragma unroll
        for (int ci = 0; ci < 4; ++ci) {
            const int ct = ch * 4 + ci;
            const int krow = ct * 16 + li;
            const int rs = (krow & 7) << 4;
            f32x4 s = {0.f, 0.f, 0.f, 0.f};
#pragma unroll
            for (int ks = 0; ks < 4; ++ks) {
                bf16x8 kf = *(const bf16x8*)&Kb[krow * 256 + ((ks * 64 + g * 16) ^ rs)];
                s = __builtin_amdgcn_mfma_f32_16x16x32_bf16(qf[ks], kf, s, 0, 0, 0);
            }
#pragma unroll
            for (int r = 0; r < 4; ++r) {
                float p = __expf(SCALE * s[r]);
                l_part[r] += p;
                const int prow = rtq * 16 + g * 4 + r;
                *(ushort*)&Pb[prow * 256 + (((ct * 16 + li) * 2) ^ ((prow & 7) << 4))]
                    = (ushort)bfr(p);
            }
        }
        __builtin_amdgcn_s_setprio(0);

        // ---- publish K(jt+1) into the other buffer (before the barrier) ----
        if (jt + 1 < 16) {
            unsigned char* Kn = &KbB[(jt + 1) & 1][0];
            *(uint4*)&Kn[(kr)      * 256 + ksw] = kA;
            *(uint4*)&Kn[(kr + 32) * 256 + ksw] = kB;
            *(uint4*)&Kn[(kr + 64) * 256 + ksw] = kC;
            *(uint4*)&Kn[(kr + 96) * 256 + ksw] = kD;
        }

        // ---- issue V(ks=0): arrives while waiting at the barrier ----
        U16 xa0, xa1, xa2, xa3, xa4, xa5;
        xa0.u = *(const uint4*)(vj + (size_t)(0 * 16) * 2048);
        xa1.u = *(const uint4*)(vj + (size_t)(1 * 16) * 2048);
        xa2.u = *(const uint4*)(vj + (size_t)(2 * 16) * 2048);
        xa3.u = *(const uint4*)(vj + (size_t)(3 * 16) * 2048);
        xa4.u = *(const uint4*)(vj + (size_t)(4 * 16) * 2048);
        xa5.u = *(const uint4*)(vj + (size_t)(5 * 16) * 2048);

        __syncthreads();   // Pb(jt) ready AND K(jt+1) visible; V(ks0) drained

        // ---- prefetch K(jt+2) (drains at NEXT barrier) ----
        if (jt + 2 < 16) {
            const ushort* kn = qk + (rowB0 + (jt + 2) * 128 + kr) * 256 + 128 + c16 * 8;
            kA = *(const uint4*)(kn);
            kB = *(const uint4*)(kn + (size_t)32 * 256);
            kC = *(const uint4*)(kn + (size_t)64 * 256);
            kD = *(const uint4*)(kn + (size_t)96 * 256);
        }

        // ---- PV: 2-deep V rotation; per ks: pa[4] + V[6], 24 MFMA ----
        U16 xb0, xb1, xb2, xb3, xb4, xb5;

#define PA_LOAD(KS) \
        bf16x8 pa0 = *(const bf16x8*)&Pb[(0 * 16 + li) * 256 + (((KS) * 64 + g * 16) ^ ((li & 7) << 4))]; \
        bf16x8 pa1 = *(const bf16x8*)&Pb[(1 * 16 + li) * 256 + (((KS) * 64 + g * 16) ^ ((li & 7) << 4))]; \
        bf16x8 pa2 = *(const bf16x8*)&Pb[(2 * 16 + li) * 256 + (((KS) * 64 + g * 16) ^ ((li & 7) << 4))]; \
        bf16x8 pa3 = *(const bf16x8*)&Pb[(3 * 16 + li) * 256 + (((KS) * 64 + g * 16) ^ ((li & 7) << 4))];
#define VISSUE(B0, B1, B2, B3, B4, B5, KS) \
        B0.u = *(const uint4*)(vj + (size_t)(0 * 16) * 2048 + (KS) * 32); \
        B1.u = *(const uint4*)(vj + (size_t)(1 * 16) * 2048 + (KS) * 32); \
        B2.u = *(const uint4*)(vj + (size_t)(2 * 16) * 2048 + (KS) * 32); \
        B3.u = *(const uint4*)(vj + (size_t)(3 * 16) * 2048 + (KS) * 32); \
        B4.u = *(const uint4*)(vj + (size_t)(4 * 16) * 2048 + (KS) * 32); \
        B5.u = *(const uint4*)(vj + (size_t)(5 * 16) * 2048 + (KS) * 32);
#define PV_MFMA(B0, B1, B2, B3, B4, B5) \
        __builtin_amdgcn_s_setprio(1); \
        o[0][0] = __builtin_amdgcn_mfma_f32_16x16x32_bf16(pa0, B0.bv, o[0][0], 0, 0, 0); \
        o[1][0] = __builtin_amdgcn_mfma_f32_16x16x32_bf16(pa1, B0.bv, o[1][0], 0, 0, 0); \
        o[2][0] = __builtin_amdgcn_mfma_f32_16x16x32_bf16(pa2, B0.bv, o[2][0], 0, 0, 0); \
        o[3][0] = __builtin_amdgcn_mfma_f32_16x16x32_bf16(pa3, B0.bv, o[3][0], 0, 0, 0); \
        o[0][1] = __builtin_amdgcn_mfma_f32_16x16x32_bf16(pa0, B1.bv, o[0][1], 0, 0, 0); \
        o[1][1] = __builtin_amdgcn_mfma_f32_16x16x32_bf16(pa1, B1.bv, o[1][1], 0, 0, 0); \
        o[2][1] = __builtin_amdgcn_mfma_f32_16x16x32_bf16(pa2, B1.bv, o[2][1], 0, 0, 0); \
        o[3][1] = __builtin_amdgcn_mfma_f32_16x16x32_bf16(pa3, B1.bv, o[3][1], 0, 0, 0); \
        o[0][2] = __builtin_amdgcn_mfma_f32_16x16x32_bf16(pa0, B2.bv, o[0][2], 0, 0, 0); \
        o[1][2] = __builtin_amdgcn_mfma_f32_16x16x32_bf16(pa1, B2.bv, o[1][2], 0, 0, 0); \
        o[2][2] = __builtin_amdgcn_mfma_f32_16x16x32_bf16(pa2, B2.bv, o[2][2], 0, 0, 0); \
        o[3][2] = __builtin_amdgcn_mfma_f32_16x16x32_bf16(pa3, B2.bv, o[3][2], 0, 0, 0); \
        o[0][3] = __builtin_amdgcn_mfma_f32_16x16x32_bf16(pa0, B3.bv, o[0][3], 0, 0, 0); \
        o[1][3] = __builtin_amdgcn_mfma_f32_16x16x32_bf16(pa1, B3.bv, o[1][3], 0, 0, 0); \
        o[2][3] = __builtin_amdgcn_mfma_f32_16x16x32_bf16(pa2, B3.bv, o[2][3], 0, 0, 0); \
        o[3][3] = __builtin_amdgcn_mfma_f32_16x16x32_bf16(pa3, B3.bv, o[3][3], 0, 0, 0); \
        o[0][4] = __builtin_amdgcn_mfma_f32_16x16x32_bf16(pa0, B4.bv, o[0][4], 0, 0, 0); \
        o[1][4] = __builtin_amdgcn_mfma_f32_16x16x32_bf16(pa1, B4.bv, o[1][4], 0, 0, 0); \
        o[2][4] = __builtin_amdgcn_mfma_f32_16x16x32_bf16(pa2, B4.bv, o[2][4], 0, 0, 0); \
        o[3][4] = __builtin_amdgcn_mfma_f32_16x16x32_bf16(pa3, B4.bv, o[3][4], 0, 0, 0); \
        o[0][5] = __builtin_amdgcn_mfma_f32_16x16x32_bf16(pa0, B5.bv, o[0][5], 0, 0, 0); \
        o[1][5] = __builtin_amdgcn_mfma_f32_16x16x32_bf16(pa1, B5.bv, o[1][5], 0, 0, 0); \
        o[2][5] = __builtin_amdgcn_mfma_f32_16x16x32_bf16(pa2, B5.bv, o[2][5], 0, 0, 0); \
        o[3][5] = __builtin_amdgcn_mfma_f32_16x16x32_bf16(pa3, B5.bv, o[3][5], 0, 0, 0); \
        __builtin_amdgcn_s_setprio(0);

        {
            VISSUE(xb0, xb1, xb2, xb3, xb4, xb5, 1)
            PA_LOAD(0)
            PV_MFMA(xa0, xa1, xa2, xa3, xa4, xa5)
        }
        {
            VISSUE(xa0, xa1, xa2, xa3, xa4, xa5, 2)
            PA_LOAD(1)
            PV_MFMA(xb0, xb1, xb2, xb3, xb4, xb5)
        }
        {
            VISSUE(xb0, xb1, xb2, xb3, xb4, xb5, 3)
            PA_LOAD(2)
            PV_MFMA(xa0, xa1, xa2, xa3, xa4, xa5)
        }
        {
            PA_LOAD(3)
            PV_MFMA(xb0, xb1, xb2, xb3, xb4, xb5)
        }
#undef PA_LOAD
#undef VISSUE
#undef PV_MFMA
    }

#pragma unroll
    for (int r = 0; r < 4; ++r) {
#pragma unroll
        for (int off = 8; off >= 1; off >>= 1)
            l_part[r] += __shfl_xor(l_part[r], off);
    }
    if (li == 0) {
#pragma unroll
        for (int r = 0; r < 4; ++r)
            lred[ch][rtq * 16 + g * 4 + r] = l_part[r];
    }
    __syncthreads();

    // ---- finalize: /l, gate by bf16 u (read-only), write bf16 gated ----
#pragma unroll
    for (int rt = 0; rt < 4; ++rt) {
#pragma unroll
        for (int r = 0; r < 4; ++r) {
            const int row = rt * 16 + g * 4 + r;
            float inv = 1.0f / (lred[0][row] + lred[1][row]);
            const ushort* ub = u_buf + (rowQ0 + row) * 768;
            ushort* gb = gated + (rowQ0 + row) * 768;
#pragma unroll
            for (int ct = 0; ct < 6; ++ct) {
                int col = w * 96 + ct * 16 + li;
                gb[col] = (ushort)bfr(o[rt][ct][r] * inv * bf2f(ub[col]));
            }
        }
    }
}

extern "C" void kernel_launch(void* const* d_in, const int* in_sizes, int n_in,
                              void* d_out, int out_size, void* d_ws, size_t ws_size,
                              hipStream_t stream)
{
    const float* x    = (const float*)d_in[0];   // [8,2048,384]
    const float* pos  = (const float*)d_in[1];   // [1,2048,256]
    const float* Wuv  = (const float*)d_in[2];   // [384,1792]
    const float* Wout = (const float*)d_in[3];   // [768,384]
    float* out = (float*)d_out;                  // [8,2048,384] f32

    ushort* u_buf = (ushort*)d_ws;                       // 16384*768 bf16
    ushort* qk    = u_buf + (size_t)R_ * HID;            // 16384*256 bf16
    ushort* vT    = qk + (size_t)R_ * 256;               // 8*768*2048 bf16
    ushort* WuvThi  = vT + (size_t)B_ * HID * L_;
    ushort* WuvTlo  = WuvThi + (size_t)NUV * D2;
    ushort* WoutThi = WuvTlo + (size_t)NUV * D2;
    ushort* WoutTlo = WoutThi + (size_t)D2 * HID;
    ushort* gated   = WoutTlo + (size_t)D2 * HID;        // 16384*768 bf16
    ushort* xhi     = gated;                             // alias (dead after gemm1)

    size_t need = ((size_t)R_ * HID + (size_t)R_ * 256 + (size_t)B_ * HID * L_ +
                   2 * (size_t)NUV * D2 + 2 * (size_t)D2 * HID +
                   (size_t)R_ * HID) * 2;                // ~87.9 MB
    if (ws_size < need) return;

    {
        int total = D2 * NUV + HID * D2 + (R_ * D2) / 4;
        conv_all<<<dim3((total + 255) / 256), dim3(256), 0, stream>>>(
            Wuv, WuvThi, WuvTlo, Wout, WoutThi, WoutTlo, x, xhi);
    }

    // GEMM1 with fused RoPE in the q/k epilogue (rope_bf kernel eliminated)
    gemm_2p<1><<<dim3(NUV / 128, R_ / 128), dim3(512), 0, stream>>>(
        xhi, D2, WuvThi, WuvTlo, D2, nullptr, 0, u_buf, qk, vT, pos, D2);

    fused_attn17<<<dim3(256), dim3(512), 0, stream>>>(u_buf, qk, vT, gated);

    gemm_2p<0><<<dim3(D2 / 128, R_ / 128), dim3(512), 0, stream>>>(
        gated, HID, WoutThi, WoutTlo, HID, out, D2, nullptr, nullptr, nullptr, nullptr, HID);
}

// Round 27
// 196.697 us; speedup vs baseline: 1.3664x; 1.0344x over previous
//
#include <hip/hip_runtime.h>
#include <hip/hip_bf16.h>
#include <math.h>

#define B_    8
#define L_    2048
#define HID   768
#define D2    384
#define NUV   1792
#define R_    16384
#define SCALE 0.08838834764831845f  // 128^-0.5

typedef __attribute__((ext_vector_type(8))) short bf16x8;
typedef __attribute__((ext_vector_type(4))) float f32x4;
typedef unsigned int uint32;
typedef unsigned short ushort;

static __device__ __forceinline__ uint32 bfr(float x) {
    uint32 u = __float_as_uint(x);
    return (u + 0x7FFFu + ((u >> 16) & 1u)) >> 16;
}
static __device__ __forceinline__ uint32 pk2(float lo, float hi) {
    return bfr(lo) | (bfr(hi) << 16);
}
static __device__ __forceinline__ float bf2f(ushort u) {
    return __uint_as_float(((uint32)u) << 16);
}
static __device__ __forceinline__ float silu_f(float x) { return x / (1.0f + __expf(-x)); }

// async global->LDS, 16B per lane. NOTE: must be issued with FULL exec
// (first active lane == lane 0) — dest is readfirstlane(base) + lane*16.
static __device__ __forceinline__ void gld_lds16(const void* g, void* l) {
    __builtin_amdgcn_global_load_lds(
        (const __attribute__((address_space(1))) unsigned int*)g,
        (__attribute__((address_space(3))) unsigned int*)l,
        16, 0, 0);
}

// ---------------------------------------------------------------------------
// Fused pre-transform, one launch (r19-verified)
// ---------------------------------------------------------------------------
__global__ __launch_bounds__(256) void conv_all(
    const float* __restrict__ Wuv, ushort* __restrict__ WuvThi, ushort* __restrict__ WuvTlo,
    const float* __restrict__ Wout, ushort* __restrict__ WoutThi, ushort* __restrict__ WoutTlo,
    const float* __restrict__ X, ushort* __restrict__ Xhi)
{
    const int N1 = D2 * NUV;
    const int N2 = HID * D2;
    const int N3 = (R_ * D2) / 4;
    int idx = blockIdx.x * 256 + threadIdx.x;

    if (idx < N1) {
        int n = idx / D2, k = idx - n * D2;
        float v = Wuv[(size_t)k * NUV + n];
        uint32 h = bfr(v);
        WuvThi[idx] = (ushort)h;
        WuvTlo[idx] = (ushort)bfr(v - __uint_as_float(h << 16));
        return;
    }
    idx -= N1;
    if (idx < N2) {
        int n = idx / HID, k = idx - n * HID;
        float v = Wout[(size_t)k * D2 + n];
        uint32 h = bfr(v);
        WoutThi[idx] = (ushort)h;
        WoutTlo[idx] = (ushort)bfr(v - __uint_as_float(h << 16));
        return;
    }
    idx -= N2;
    if (idx < N3) {
        float4 v = *(const float4*)(X + (size_t)idx * 4);
        uint2 p; p.x = pk2(v.x, v.y); p.y = pk2(v.z, v.w);
        *(uint2*)(Xhi + (size_t)idx * 4) = p;
    }
}

// ---------------------------------------------------------------------------
// Bf16-A GEMM with global_load_lds staging (r24-verified, UNCONDITIONAL
// full-exec staging). Pass policy applied in the MFMA loop only:
//   EPI 0 (GEMM2): 2-pass.  EPI 1: 2-pass for q/k, 1-pass hi-only for u/v.
// EPI 1 epilogue: u bf16, vT transposed, q/k with FUSED RoPE.
// ---------------------------------------------------------------------------
template<int EPI>
__global__ __launch_bounds__(512, 4) void gemm_2p(
    const ushort* __restrict__ Ahi, int lda,
    const ushort* __restrict__ BThi, const ushort* __restrict__ BTlo, int ldbt,
    float* __restrict__ C, int ldc,
    ushort* __restrict__ u_buf, ushort* __restrict__ qk, ushort* __restrict__ vT,
    const float* __restrict__ pos, int K)
{
    __shared__ unsigned char As[128 * 128];
    __shared__ unsigned char Bs[128 * 256];

    const int t  = threadIdx.x;
    const int w  = t >> 6;
    const int l  = t & 63;
    const int g  = l >> 4;
    const int li = l & 15;
    const int wr = w >> 1;
    const int wc = w & 1;
    const int m0 = blockIdx.y * 128;
    const int n0 = blockIdx.x * 128;

    const bool lo_on = (EPI == 0) || (n0 >= 1536);   // block-uniform

    f32x4 acc[2][4];
#pragma unroll
    for (int i = 0; i < 2; ++i)
#pragma unroll
        for (int j = 0; j < 4; ++j) acc[i][j] = (f32x4){0.f, 0.f, 0.f, 0.f};

    // staging geometry (thread-fixed)
    const int arow0 = t >> 3;
    const int ac8   = t & 7;
    const int bcol0 = t >> 4;
    const int bs16  = t & 15;

    for (int k0 = 0; k0 < K; k0 += 64) {
#pragma unroll
        for (int i = 0; i < 2; ++i) {
            int idx = t + i * 512;
            int row = arow0 + i * 64;
            gld_lds16(Ahi + (size_t)(m0 + row) * lda + k0 + ((ac8 ^ (row & 7)) * 8),
                      &As[idx * 16]);
        }
        // unconditional (full-exec) staging — r24-verified correct
#pragma unroll
        for (int i = 0; i < 4; ++i) {
            int idx = t + i * 512;
            int c   = bcol0 + i * 32;
            int sl  = bs16 ^ (c & 7);
            const ushort* src = (sl < 8)
                ? (BThi + (long long)(n0 + c) * ldbt + k0 + sl * 8)
                : (BTlo + (long long)(n0 + c) * ldbt + k0 + (sl - 8) * 8);
            gld_lds16(src, &Bs[idx * 16]);
        }
        __syncthreads();

#pragma unroll
        for (int ks = 0; ks < 2; ++ks) {
            bf16x8 ah[2], bh[4];
#pragma unroll
            for (int mi = 0; mi < 2; ++mi) {
                int row = wr * 32 + mi * 16 + li;
                ah[mi] = *(const bf16x8*)&As[row * 128 + ((ks * 64 + g * 16) ^ ((row & 7) << 4))];
            }
#pragma unroll
            for (int ni = 0; ni < 4; ++ni) {
                int col = wc * 64 + ni * 16 + li;
                int off = (ks * 64 + g * 16) ^ ((col & 7) << 4);
                bh[ni] = *(const bf16x8*)&Bs[col * 256 + off];
            }
#pragma unroll
            for (int mi = 0; mi < 2; ++mi)
#pragma unroll
                for (int ni = 0; ni < 4; ++ni)
                    acc[mi][ni] = __builtin_amdgcn_mfma_f32_16x16x32_bf16(ah[mi], bh[ni], acc[mi][ni], 0, 0, 0);
            if (lo_on) {
                bf16x8 bl[4];
#pragma unroll
                for (int ni = 0; ni < 4; ++ni) {
                    int col = wc * 64 + ni * 16 + li;
                    int off = (ks * 64 + g * 16) ^ ((col & 7) << 4);
                    bl[ni] = *(const bf16x8*)&Bs[col * 256 + 128 + off];
                }
#pragma unroll
                for (int mi = 0; mi < 2; ++mi)
#pragma unroll
                    for (int ni = 0; ni < 4; ++ni)
                        acc[mi][ni] = __builtin_amdgcn_mfma_f32_16x16x32_bf16(ah[mi], bl[ni], acc[mi][ni], 0, 0, 0);
            }
        }
        __syncthreads();
    }

    if (EPI == 0) {
#pragma unroll
        for (int mi = 0; mi < 2; ++mi)
#pragma unroll
            for (int ni = 0; ni < 4; ++ni) {
                int col = n0 + wc * 64 + ni * 16 + li;
#pragma unroll
                for (int r = 0; r < 4; ++r) {
                    int row = m0 + wr * 32 + mi * 16 + g * 4 + r;
                    C[(long long)row * ldc + col] = acc[mi][ni][r];
                }
            }
    } else {
        if (n0 < 768) {
#pragma unroll
            for (int mi = 0; mi < 2; ++mi)
#pragma unroll
                for (int ni = 0; ni < 4; ++ni) {
                    int col = n0 + wc * 64 + ni * 16 + li;
#pragma unroll
                    for (int r = 0; r < 4; ++r) {
                        int row = m0 + wr * 32 + mi * 16 + g * 4 + r;
                        u_buf[(size_t)row * 768 + col] = (ushort)bfr(silu_f(acc[mi][ni][r]));
                    }
                }
        } else if (n0 < 1536) {
            int bb = m0 >> 11;
            int llb = (m0 & 2047) + wr * 32 + g * 4;
#pragma unroll
            for (int mi = 0; mi < 2; ++mi) {
                int ll = llb + mi * 16;
#pragma unroll
                for (int ni = 0; ni < 4; ++ni) {
                    int cv = n0 + wc * 64 + ni * 16 + li - 768;
                    ushort* vb = vT + ((size_t)bb * 768 + cv) * 2048 + ll;
                    *(uint32*)(vb)     = pk2(silu_f(acc[mi][ni][0]), silu_f(acc[mi][ni][1]));
                    *(uint32*)(vb + 2) = pk2(silu_f(acc[mi][ni][2]), silu_f(acc[mi][ni][3]));
                }
            }
        } else {
            // q/k with FUSED RoPE (2-pass precision preserved here).
            ushort* Qs = (ushort*)Bs;   // [128 rows][128 cols]
#pragma unroll
            for (int mi = 0; mi < 2; ++mi)
#pragma unroll
                for (int ni = 0; ni < 4; ++ni) {
                    int coll = wc * 64 + ni * 16 + li;
#pragma unroll
                    for (int r = 0; r < 4; ++r) {
                        int rowl = wr * 32 + mi * 16 + g * 4 + r;
                        Qs[rowl * 128 + coll] = (ushort)bfr(acc[mi][ni][r]);
                    }
                }
            __syncthreads();
            const int qcol0 = n0 - 1536;   // 0 for q, 128 for k
#pragma unroll
            for (int mi = 0; mi < 2; ++mi)
#pragma unroll
                for (int ni = 0; ni < 4; ++ni) {
                    int coll = wc * 64 + ni * 16 + li;
                    int j = coll & 63;
#pragma unroll
                    for (int r = 0; r < 4; ++r) {
                        int rowl = wr * 32 + mi * 16 + g * 4 + r;
                        int rowg = m0 + rowl;
                        int lpos = rowg & (L_ - 1);
                        float sn = pos[lpos * 256 + j];
                        float cs = pos[lpos * 256 + 64 + j];
                        float x1 = bf2f(Qs[rowl * 128 + j]);
                        float x2 = bf2f(Qs[rowl * 128 + 64 + j]);
                        float v = (coll < 64) ? (x1 * cs - x2 * sn)
                                              : (x2 * cs + x1 * sn);
                        qk[(size_t)rowg * 256 + qcol0 + coll] = (ushort)bfr(v);
                    }
                }
        }
    }
}

// ---------------------------------------------------------------------------
// MFMA flash attention v17 (r23/r24/r25 winner, byte-identical).
// ---------------------------------------------------------------------------
__global__ __launch_bounds__(512) void fused_attn17(
    const ushort* __restrict__ u_buf, const ushort* __restrict__ qk,
    const ushort* __restrict__ vT, ushort* __restrict__ gated)
{
    __shared__ unsigned char KbB[2][128 * 256];   // K bf16 dbuf (64 KB)
    __shared__ unsigned char PbB[2][64 * 256];    // P bf16 dbuf (32 KB)
    __shared__ float lred[2][64];

    const int t  = threadIdx.x;
    const int w  = t >> 6;
    const int l  = t & 63;
    const int g  = l >> 4;
    const int li = l & 15;

    const int b  = blockIdx.x & 7;
    const int qt = blockIdx.x >> 3;
    const long long rowQ0 = (long long)b * L_ + (long long)qt * 64;
    const long long rowB0 = (long long)b * L_;

    const int rtq = w >> 1;
    const int ch  = w & 1;

    bf16x8 qf[4];
    {
        const ushort* qrow = qk + (rowQ0 + rtq * 16 + li) * 256;
#pragma unroll
        for (int ks = 0; ks < 4; ++ks)
            qf[ks] = *(const bf16x8*)&qrow[ks * 32 + g * 8];
    }

    float l_part[4] = {0.f, 0.f, 0.f, 0.f};

    f32x4 o[4][6];
#pragma unroll
    for (int rt = 0; rt < 4; ++rt)
#pragma unroll
        for (int ct = 0; ct < 6; ++ct)
            o[rt][ct] = (f32x4){0.f, 0.f, 0.f, 0.f};

    const ushort* vrow = vT + ((size_t)b * 768 + w * 96 + li) * 2048 + g * 8;

    const int kr  = t >> 4;
    const int c16 = t & 15;
    const int ksw = (c16 * 16) ^ ((kr & 7) << 4);

    union U16 { uint4 u; bf16x8 bv; };

    // prologue: prefetch K(0), publish into Kb[0], barrier, prefetch K(1)
    uint4 kA = *(const uint4*)&qk[(rowB0 + kr)      * 256 + 128 + c16 * 8];
    uint4 kB = *(const uint4*)&qk[(rowB0 + kr + 32) * 256 + 128 + c16 * 8];
    uint4 kC = *(const uint4*)&qk[(rowB0 + kr + 64) * 256 + 128 + c16 * 8];
    uint4 kD = *(const uint4*)&qk[(rowB0 + kr + 96) * 256 + 128 + c16 * 8];
    *(uint4*)&KbB[0][(kr)      * 256 + ksw] = kA;
    *(uint4*)&KbB[0][(kr + 32) * 256 + ksw] = kB;
    *(uint4*)&KbB[0][(kr + 64) * 256 + ksw] = kC;
    *(uint4*)&KbB[0][(kr + 96) * 256 + ksw] = kD;
    __syncthreads();
    {
        const ushort* kn = qk + (rowB0 + 128 + kr) * 256 + 128 + c16 * 8;
        kA = *(const uint4*)(kn);
        kB = *(const uint4*)(kn + (size_t)32 * 256);
        kC = *(const uint4*)(kn + (size_t)64 * 256);
        kD = *(const uint4*)(kn + (size_t)96 * 256);
    }

    for (int jt = 0; jt < 16; ++jt) {
        const unsigned char* Kb = &KbB[jt & 1][0];
        unsigned char* Pb = &PbB[jt & 1][0];
        const ushort* vj = vrow + jt * 128;

        // ---- QK: 4 S-tiles + exp + Pb write + l accumulation ----
        __builtin_amdgcn_s_setprio(1);
#pragma unroll
        for (int ci = 0; ci < 4; ++ci) {
            const int ct = ch * 4 + ci;
            const int krow = ct * 16 + li;
            const int rs = (krow & 7) << 4;
            f32x4 s = {0.f, 0.f, 0.f, 0.f};
#pragma unroll
            for (int ks = 0; ks < 4; ++ks) {
                bf16x8 kf = *(const bf16x8*)&Kb[krow * 256 + ((ks * 64 + g * 16) ^ rs)];
                s = __builtin_amdgcn_mfma_f32_16x16x32_bf16(qf[ks], kf, s, 0, 0, 0);
            }
#pragma unroll
            for (int r = 0; r < 4; ++r) {
                float p = __expf(SCALE * s[r]);
                l_part[r] += p;
                const int prow = rtq * 16 + g * 4 + r;
                *(ushort*)&Pb[prow * 256 + (((ct * 16 + li) * 2) ^ ((prow & 7) << 4))]
                    = (ushort)bfr(p);
            }
        }
        __builtin_amdgcn_s_setprio(0);

        // ---- publish K(jt+1) into the other buffer (before the barrier) ----
        if (jt + 1 < 16) {
            unsigned char* Kn = &KbB[(jt + 1) & 1][0];
            *(uint4*)&Kn[(kr)      * 256 + ksw] = kA;
            *(uint4*)&Kn[(kr + 32) * 256 + ksw] = kB;
            *(uint4*)&Kn[(kr + 64) * 256 + ksw] = kC;
            *(uint4*)&Kn[(kr + 96) * 256 + ksw] = kD;
        }

        // ---- issue V(ks=0): arrives while waiting at the barrier ----
        U16 xa0, xa1, xa2, xa3, xa4, xa5;
        xa0.u = *(const uint4*)(vj + (size_t)(0 * 16) * 2048);
        xa1.u = *(const uint4*)(vj + (size_t)(1 * 16) * 2048);
        xa2.u = *(const uint4*)(vj + (size_t)(2 * 16) * 2048);
        xa3.u = *(const uint4*)(vj + (size_t)(3 * 16) * 2048);
        xa4.u = *(const uint4*)(vj + (size_t)(4 * 16) * 2048);
        xa5.u = *(const uint4*)(vj + (size_t)(5 * 16) * 2048);

        __syncthreads();   // Pb(jt) ready AND K(jt+1) visible; V(ks0) drained

        // ---- prefetch K(jt+2) (drains at NEXT barrier) ----
        if (jt + 2 < 16) {
            const ushort* kn = qk + (rowB0 + (jt + 2) * 128 + kr) * 256 + 128 + c16 * 8;
            kA = *(const uint4*)(kn);
            kB = *(const uint4*)(kn + (size_t)32 * 256);
            kC = *(const uint4*)(kn + (size_t)64 * 256);
            kD = *(const uint4*)(kn + (size_t)96 * 256);
        }

        // ---- PV: 2-deep V rotation; per ks: pa[4] + V[6], 24 MFMA ----
        U16 xb0, xb1, xb2, xb3, xb4, xb5;

#define PA_LOAD(KS) \
        bf16x8 pa0 = *(const bf16x8*)&Pb[(0 * 16 + li) * 256 + (((KS) * 64 + g * 16) ^ ((li & 7) << 4))]; \
        bf16x8 pa1 = *(const bf16x8*)&Pb[(1 * 16 + li) * 256 + (((KS) * 64 + g * 16) ^ ((li & 7) << 4))]; \
        bf16x8 pa2 = *(const bf16x8*)&Pb[(2 * 16 + li) * 256 + (((KS) * 64 + g * 16) ^ ((li & 7) << 4))]; \
        bf16x8 pa3 = *(const bf16x8*)&Pb[(3 * 16 + li) * 256 + (((KS) * 64 + g * 16) ^ ((li & 7) << 4))];
#define VISSUE(B0, B1, B2, B3, B4, B5, KS) \
        B0.u = *(const uint4*)(vj + (size_t)(0 * 16) * 2048 + (KS) * 32); \
        B1.u = *(const uint4*)(vj + (size_t)(1 * 16) * 2048 + (KS) * 32); \
        B2.u = *(const uint4*)(vj + (size_t)(2 * 16) * 2048 + (KS) * 32); \
        B3.u = *(const uint4*)(vj + (size_t)(3 * 16) * 2048 + (KS) * 32); \
        B4.u = *(const uint4*)(vj + (size_t)(4 * 16) * 2048 + (KS) * 32); \
        B5.u = *(const uint4*)(vj + (size_t)(5 * 16) * 2048 + (KS) * 32);
#define PV_MFMA(B0, B1, B2, B3, B4, B5) \
        __builtin_amdgcn_s_setprio(1); \
        o[0][0] = __builtin_amdgcn_mfma_f32_16x16x32_bf16(pa0, B0.bv, o[0][0], 0, 0, 0); \
        o[1][0] = __builtin_amdgcn_mfma_f32_16x16x32_bf16(pa1, B0.bv, o[1][0], 0, 0, 0); \
        o[2][0] = __builtin_amdgcn_mfma_f32_16x16x32_bf16(pa2, B0.bv, o[2][0], 0, 0, 0); \
        o[3][0] = __builtin_amdgcn_mfma_f32_16x16x32_bf16(pa3, B0.bv, o[3][0], 0, 0, 0); \
        o[0][1] = __builtin_amdgcn_mfma_f32_16x16x32_bf16(pa0, B1.bv, o[0][1], 0, 0, 0); \
        o[1][1] = __builtin_amdgcn_mfma_f32_16x16x32_bf16(pa1, B1.bv, o[1][1], 0, 0, 0); \
        o[2][1] = __builtin_amdgcn_mfma_f32_16x16x32_bf16(pa2, B1.bv, o[2][1], 0, 0, 0); \
        o[3][1] = __builtin_amdgcn_mfma_f32_16x16x32_bf16(pa3, B1.bv, o[3][1], 0, 0, 0); \
        o[0][2] = __builtin_amdgcn_mfma_f32_16x16x32_bf16(pa0, B2.bv, o[0][2], 0, 0, 0); \
        o[1][2] = __builtin_amdgcn_mfma_f32_16x16x32_bf16(pa1, B2.bv, o[1][2], 0, 0, 0); \
        o[2][2] = __builtin_amdgcn_mfma_f32_16x16x32_bf16(pa2, B2.bv, o[2][2], 0, 0, 0); \
        o[3][2] = __builtin_amdgcn_mfma_f32_16x16x32_bf16(pa3, B2.bv, o[3][2], 0, 0, 0); \
        o[0][3] = __builtin_amdgcn_mfma_f32_16x16x32_bf16(pa0, B3.bv, o[0][3], 0, 0, 0); \
        o[1][3] = __builtin_amdgcn_mfma_f32_16x16x32_bf16(pa1, B3.bv, o[1][3], 0, 0, 0); \
        o[2][3] = __builtin_amdgcn_mfma_f32_16x16x32_bf16(pa2, B3.bv, o[2][3], 0, 0, 0); \
        o[3][3] = __builtin_amdgcn_mfma_f32_16x16x32_bf16(pa3, B3.bv, o[3][3], 0, 0, 0); \
        o[0][4] = __builtin_amdgcn_mfma_f32_16x16x32_bf16(pa0, B4.bv, o[0][4], 0, 0, 0); \
        o[1][4] = __builtin_amdgcn_mfma_f32_16x16x32_bf16(pa1, B4.bv, o[1][4], 0, 0, 0); \
        o[2][4] = __builtin_amdgcn_mfma_f32_16x16x32_bf16(pa2, B4.bv, o[2][4], 0, 0, 0); \
        o[3][4] = __builtin_amdgcn_mfma_f32_16x16x32_bf16(pa3, B4.bv, o[3][4], 0, 0, 0); \
        o[0][5] = __builtin_amdgcn_mfma_f32_16x16x32_bf16(pa0, B5.bv, o[0][5], 0, 0, 0); \
        o[1][5] = __builtin_amdgcn_mfma_f32_16x16x32_bf16(pa1, B5.bv, o[1][5], 0, 0, 0); \
        o[2][5] = __builtin_amdgcn_mfma_f32_16x16x32_bf16(pa2, B5.bv, o[2][5], 0, 0, 0); \
        o[3][5] = __builtin_amdgcn_mfma_f32_16x16x32_bf16(pa3, B5.bv, o[3][5], 0, 0, 0); \
        __builtin_amdgcn_s_setprio(0);

        {
            VISSUE(xb0, xb1, xb2, xb3, xb4, xb5, 1)
            PA_LOAD(0)
            PV_MFMA(xa0, xa1, xa2, xa3, xa4, xa5)
        }
        {
            VISSUE(xa0, xa1, xa2, xa3, xa4, xa5, 2)
            PA_LOAD(1)
            PV_MFMA(xb0, xb1, xb2, xb3, xb4, xb5)
        }
        {
            VISSUE(xb0, xb1, xb2, xb3, xb4, xb5, 3)
            PA_LOAD(2)
            PV_MFMA(xa0, xa1, xa2, xa3, xa4, xa5)
        }
        {
            PA_LOAD(3)
            PV_MFMA(xb0, xb1, xb2, xb3, xb4, xb5)
        }
#undef PA_LOAD
#undef VISSUE
#undef PV_MFMA
    }

#pragma unroll
    for (int r = 0; r < 4; ++r) {
#pragma unroll
        for (int off = 8; off >= 1; off >>= 1)
            l_part[r] += __shfl_xor(l_part[r], off);
    }
    if (li == 0) {
#pragma unroll
        for (int r = 0; r < 4; ++r)
            lred[ch][rtq * 16 + g * 4 + r] = l_part[r];
    }
    __syncthreads();

    // ---- finalize: /l, gate by bf16 u (read-only), write bf16 gated ----
#pragma unroll
    for (int rt = 0; rt < 4; ++rt) {
#pragma unroll
        for (int r = 0; r < 4; ++r) {
            const int row = rt * 16 + g * 4 + r;
            float inv = 1.0f / (lred[0][row] + lred[1][row]);
            const ushort* ub = u_buf + (rowQ0 + row) * 768;
            ushort* gb = gated + (rowQ0 + row) * 768;
#pragma unroll
            for (int ct = 0; ct < 6; ++ct) {
                int col = w * 96 + ct * 16 + li;
                gb[col] = (ushort)bfr(o[rt][ct][r] * inv * bf2f(ub[col]));
            }
        }
    }
}

extern "C" void kernel_launch(void* const* d_in, const int* in_sizes, int n_in,
                              void* d_out, int out_size, void* d_ws, size_t ws_size,
                              hipStream_t stream)
{
    const float* x    = (const float*)d_in[0];   // [8,2048,384]
    const float* pos  = (const float*)d_in[1];   // [1,2048,256]
    const float* Wuv  = (const float*)d_in[2];   // [384,1792]
    const float* Wout = (const float*)d_in[3];   // [768,384]
    float* out = (float*)d_out;                  // [8,2048,384] f32

    ushort* u_buf = (ushort*)d_ws;                       // 16384*768 bf16
    ushort* qk    = u_buf + (size_t)R_ * HID;            // 16384*256 bf16
    ushort* vT    = qk + (size_t)R_ * 256;               // 8*768*2048 bf16
    ushort* WuvThi  = vT + (size_t)B_ * HID * L_;
    ushort* WuvTlo  = WuvThi + (size_t)NUV * D2;
    ushort* WoutThi = WuvTlo + (size_t)NUV * D2;
    ushort* WoutTlo = WoutThi + (size_t)D2 * HID;
    ushort* gated   = WoutTlo + (size_t)D2 * HID;        // 16384*768 bf16
    ushort* xhi     = gated;                             // alias (dead after gemm1)

    size_t need = ((size_t)R_ * HID + (size_t)R_ * 256 + (size_t)B_ * HID * L_ +
                   2 * (size_t)NUV * D2 + 2 * (size_t)D2 * HID +
                   (size_t)R_ * HID) * 2;                // ~87.9 MB
    if (ws_size < need) return;

    {
        int total = D2 * NUV + HID * D2 + (R_ * D2) / 4;
        conv_all<<<dim3((total + 255) / 256), dim3(256), 0, stream>>>(
            Wuv, WuvThi, WuvTlo, Wout, WoutThi, WoutTlo, x, xhi);
    }

    // GEMM1: MFMA-only hybrid pass policy (1-pass u/v, 2-pass q/k) + fused RoPE
    gemm_2p<1><<<dim3(NUV / 128, R_ / 128), dim3(512), 0, stream>>>(
        xhi, D2, WuvThi, WuvTlo, D2, nullptr, 0, u_buf, qk, vT, pos, D2);

    fused_attn17<<<dim3(256), dim3(512), 0, stream>>>(u_buf, qk, vT, gated);

    gemm_2p<0><<<dim3(D2 / 128, R_ / 128), dim3(512), 0, stream>>>(
        gated, HID, WoutThi, WoutTlo, HID, out, D2, nullptr, nullptr, nullptr, nullptr, HID);
}

// Round 28
// 190.244 us; speedup vs baseline: 1.4128x; 1.0339x over previous
//
#include <hip/hip_runtime.h>
#include <hip/hip_bf16.h>
#include <math.h>

#define B_    8
#define L_    2048
#define HID   768
#define D2    384
#define NUV   1792
#define R_    16384
#define SCALE 0.08838834764831845f  // 128^-0.5

typedef __attribute__((ext_vector_type(8))) short bf16x8;
typedef __attribute__((ext_vector_type(4))) float f32x4;
typedef unsigned int uint32;
typedef unsigned short ushort;

static __device__ __forceinline__ uint32 bfr(float x) {
    uint32 u = __float_as_uint(x);
    return (u + 0x7FFFu + ((u >> 16) & 1u)) >> 16;
}
static __device__ __forceinline__ uint32 pk2(float lo, float hi) {
    return bfr(lo) | (bfr(hi) << 16);
}
static __device__ __forceinline__ float bf2f(ushort u) {
    return __uint_as_float(((uint32)u) << 16);
}
static __device__ __forceinline__ float silu_f(float x) { return x / (1.0f + __expf(-x)); }

// async global->LDS, 16B per lane. Must be issued with FULL exec
// (dest = readfirstlane(base) + lane*16).
static __device__ __forceinline__ void gld_lds16(const void* g, void* l) {
    __builtin_amdgcn_global_load_lds(
        (const __attribute__((address_space(1))) unsigned int*)g,
        (__attribute__((address_space(3))) unsigned int*)l,
        16, 0, 0);
}

// ---------------------------------------------------------------------------
// Fused pre-transform, one launch (r19-verified)
// ---------------------------------------------------------------------------
__global__ __launch_bounds__(256) void conv_all(
    const float* __restrict__ Wuv, ushort* __restrict__ WuvThi, ushort* __restrict__ WuvTlo,
    const float* __restrict__ Wout, ushort* __restrict__ WoutThi, ushort* __restrict__ WoutTlo,
    const float* __restrict__ X, ushort* __restrict__ Xhi)
{
    const int N1 = D2 * NUV;
    const int N2 = HID * D2;
    const int N3 = (R_ * D2) / 4;
    int idx = blockIdx.x * 256 + threadIdx.x;

    if (idx < N1) {
        int n = idx / D2, k = idx - n * D2;
        float v = Wuv[(size_t)k * NUV + n];
        uint32 h = bfr(v);
        WuvThi[idx] = (ushort)h;
        WuvTlo[idx] = (ushort)bfr(v - __uint_as_float(h << 16));
        return;
    }
    idx -= N1;
    if (idx < N2) {
        int n = idx / HID, k = idx - n * HID;
        float v = Wout[(size_t)k * D2 + n];
        uint32 h = bfr(v);
        WoutThi[idx] = (ushort)h;
        WoutTlo[idx] = (ushort)bfr(v - __uint_as_float(h << 16));
        return;
    }
    idx -= N2;
    if (idx < N3) {
        float4 v = *(const float4*)(X + (size_t)idx * 4);
        uint2 p; p.x = pk2(v.x, v.y); p.y = pk2(v.z, v.w);
        *(uint2*)(Xhi + (size_t)idx * 4) = p;
    }
}

// ---------------------------------------------------------------------------
// Bf16-A GEMM with global_load_lds staging.
// TWOPASS=1 (GEMM1): stage hi+lo; MFMA hybrid (lo only for q/k n0>=1536);
//                    GAU epilogue (u bf16, vT transposed, q/k fused RoPE).
// TWOPASS=0 (GEMM2): stage hi only (16KB), MFMA hi-only, plain f32 C.
// ---------------------------------------------------------------------------
template<int EPI, int TWOPASS>
__global__ __launch_bounds__(512, 4) void gemm_2p(
    const ushort* __restrict__ Ahi, int lda,
    const ushort* __restrict__ BThi, const ushort* __restrict__ BTlo, int ldbt,
    float* __restrict__ C, int ldc,
    ushort* __restrict__ u_buf, ushort* __restrict__ qk, ushort* __restrict__ vT,
    const float* __restrict__ pos, int K)
{
    __shared__ unsigned char As[128 * 128];
    __shared__ unsigned char Bs[128 * 256];

    const int t  = threadIdx.x;
    const int w  = t >> 6;
    const int l  = t & 63;
    const int g  = l >> 4;
    const int li = l & 15;
    const int wr = w >> 1;
    const int wc = w & 1;
    const int m0 = blockIdx.y * 128;
    const int n0 = blockIdx.x * 128;

    const bool lo_on = TWOPASS && ((EPI == 0) || (n0 >= 1536));   // block-uniform
    const int  BROW  = TWOPASS ? 256 : 128;                       // Bs row stride

    f32x4 acc[2][4];
#pragma unroll
    for (int i = 0; i < 2; ++i)
#pragma unroll
        for (int j = 0; j < 4; ++j) acc[i][j] = (f32x4){0.f, 0.f, 0.f, 0.f};

    // staging geometry (thread-fixed)
    const int arow0 = t >> 3;
    const int ac8   = t & 7;

    for (int k0 = 0; k0 < K; k0 += 64) {
#pragma unroll
        for (int i = 0; i < 2; ++i) {
            int idx = t + i * 512;
            int row = arow0 + i * 64;
            gld_lds16(Ahi + (size_t)(m0 + row) * lda + k0 + ((ac8 ^ (row & 7)) * 8),
                      &As[idx * 16]);
        }
        if (TWOPASS) {
            // hi+lo: 2048 chunks, [c][s16] with s16 = logical ^ (c&7)
            const int bcol0 = t >> 4;
            const int bs16  = t & 15;
#pragma unroll
            for (int i = 0; i < 4; ++i) {
                int idx = t + i * 512;
                int c   = bcol0 + i * 32;
                int sl  = bs16 ^ (c & 7);
                const ushort* src = (sl < 8)
                    ? (BThi + (long long)(n0 + c) * ldbt + k0 + sl * 8)
                    : (BTlo + (long long)(n0 + c) * ldbt + k0 + (sl - 8) * 8);
                gld_lds16(src, &Bs[idx * 16]);
            }
        } else {
            // hi only: 1024 chunks, [c][s8], same pattern as A staging
#pragma unroll
            for (int i = 0; i < 2; ++i) {
                int idx = t + i * 512;
                int c   = arow0 + i * 64;
                gld_lds16(BThi + (long long)(n0 + c) * ldbt + k0 + ((ac8 ^ (c & 7)) * 8),
                          &Bs[idx * 16]);
            }
        }
        __syncthreads();

#pragma unroll
        for (int ks = 0; ks < 2; ++ks) {
            bf16x8 ah[2], bh[4];
#pragma unroll
            for (int mi = 0; mi < 2; ++mi) {
                int row = wr * 32 + mi * 16 + li;
                ah[mi] = *(const bf16x8*)&As[row * 128 + ((ks * 64 + g * 16) ^ ((row & 7) << 4))];
            }
#pragma unroll
            for (int ni = 0; ni < 4; ++ni) {
                int col = wc * 64 + ni * 16 + li;
                int off = (ks * 64 + g * 16) ^ ((col & 7) << 4);
                bh[ni] = *(const bf16x8*)&Bs[col * BROW + off];
            }
#pragma unroll
            for (int mi = 0; mi < 2; ++mi)
#pragma unroll
                for (int ni = 0; ni < 4; ++ni)
                    acc[mi][ni] = __builtin_amdgcn_mfma_f32_16x16x32_bf16(ah[mi], bh[ni], acc[mi][ni], 0, 0, 0);
            if (lo_on) {
                bf16x8 bl[4];
#pragma unroll
                for (int ni = 0; ni < 4; ++ni) {
                    int col = wc * 64 + ni * 16 + li;
                    int off = (ks * 64 + g * 16) ^ ((col & 7) << 4);
                    bl[ni] = *(const bf16x8*)&Bs[col * 256 + 128 + off];
                }
#pragma unroll
                for (int mi = 0; mi < 2; ++mi)
#pragma unroll
                    for (int ni = 0; ni < 4; ++ni)
                        acc[mi][ni] = __builtin_amdgcn_mfma_f32_16x16x32_bf16(ah[mi], bl[ni], acc[mi][ni], 0, 0, 0);
            }
        }
        __syncthreads();
    }

    if (EPI == 0) {
#pragma unroll
        for (int mi = 0; mi < 2; ++mi)
#pragma unroll
            for (int ni = 0; ni < 4; ++ni) {
                int col = n0 + wc * 64 + ni * 16 + li;
#pragma unroll
                for (int r = 0; r < 4; ++r) {
                    int row = m0 + wr * 32 + mi * 16 + g * 4 + r;
                    C[(long long)row * ldc + col] = acc[mi][ni][r];
                }
            }
    } else {
        if (n0 < 768) {
#pragma unroll
            for (int mi = 0; mi < 2; ++mi)
#pragma unroll
                for (int ni = 0; ni < 4; ++ni) {
                    int col = n0 + wc * 64 + ni * 16 + li;
#pragma unroll
                    for (int r = 0; r < 4; ++r) {
                        int row = m0 + wr * 32 + mi * 16 + g * 4 + r;
                        u_buf[(size_t)row * 768 + col] = (ushort)bfr(silu_f(acc[mi][ni][r]));
                    }
                }
        } else if (n0 < 1536) {
            int bb = m0 >> 11;
            int llb = (m0 & 2047) + wr * 32 + g * 4;
#pragma unroll
            for (int mi = 0; mi < 2; ++mi) {
                int ll = llb + mi * 16;
#pragma unroll
                for (int ni = 0; ni < 4; ++ni) {
                    int cv = n0 + wc * 64 + ni * 16 + li - 768;
                    ushort* vb = vT + ((size_t)bb * 768 + cv) * 2048 + ll;
                    *(uint32*)(vb)     = pk2(silu_f(acc[mi][ni][0]), silu_f(acc[mi][ni][1]));
                    *(uint32*)(vb + 2) = pk2(silu_f(acc[mi][ni][2]), silu_f(acc[mi][ni][3]));
                }
            }
        } else {
            // q/k with FUSED RoPE (2-pass precision preserved here).
            ushort* Qs = (ushort*)Bs;   // [128 rows][128 cols]
#pragma unroll
            for (int mi = 0; mi < 2; ++mi)
#pragma unroll
                for (int ni = 0; ni < 4; ++ni) {
                    int coll = wc * 64 + ni * 16 + li;
#pragma unroll
                    for (int r = 0; r < 4; ++r) {
                        int rowl = wr * 32 + mi * 16 + g * 4 + r;
                        Qs[rowl * 128 + coll] = (ushort)bfr(acc[mi][ni][r]);
                    }
                }
            __syncthreads();
            const int qcol0 = n0 - 1536;   // 0 for q, 128 for k
#pragma unroll
            for (int mi = 0; mi < 2; ++mi)
#pragma unroll
                for (int ni = 0; ni < 4; ++ni) {
                    int coll = wc * 64 + ni * 16 + li;
                    int j = coll & 63;
#pragma unroll
                    for (int r = 0; r < 4; ++r) {
                        int rowl = wr * 32 + mi * 16 + g * 4 + r;
                        int rowg = m0 + rowl;
                        int lpos = rowg & (L_ - 1);
                        float sn = pos[lpos * 256 + j];
                        float cs = pos[lpos * 256 + 64 + j];
                        float x1 = bf2f(Qs[rowl * 128 + j]);
                        float x2 = bf2f(Qs[rowl * 128 + 64 + j]);
                        float v = (coll < 64) ? (x1 * cs - x2 * sn)
                                              : (x2 * cs + x1 * sn);
                        qk[(size_t)rowg * 256 + qcol0 + coll] = (ushort)bfr(v);
                    }
                }
        }
    }
}

// ---------------------------------------------------------------------------
// MFMA flash attention v17 (r23-r27 winner, byte-identical).
// ---------------------------------------------------------------------------
__global__ __launch_bounds__(512) void fused_attn17(
    const ushort* __restrict__ u_buf, const ushort* __restrict__ qk,
    const ushort* __restrict__ vT, ushort* __restrict__ gated)
{
    __shared__ unsigned char KbB[2][128 * 256];   // K bf16 dbuf (64 KB)
    __shared__ unsigned char PbB[2][64 * 256];    // P bf16 dbuf (32 KB)
    __shared__ float lred[2][64];

    const int t  = threadIdx.x;
    const int w  = t >> 6;
    const int l  = t & 63;
    const int g  = l >> 4;
    const int li = l & 15;

    const int b  = blockIdx.x & 7;
    const int qt = blockIdx.x >> 3;
    const long long rowQ0 = (long long)b * L_ + (long long)qt * 64;
    const long long rowB0 = (long long)b * L_;

    const int rtq = w >> 1;
    const int ch  = w & 1;

    bf16x8 qf[4];
    {
        const ushort* qrow = qk + (rowQ0 + rtq * 16 + li) * 256;
#pragma unroll
        for (int ks = 0; ks < 4; ++ks)
            qf[ks] = *(const bf16x8*)&qrow[ks * 32 + g * 8];
    }

    float l_part[4] = {0.f, 0.f, 0.f, 0.f};

    f32x4 o[4][6];
#pragma unroll
    for (int rt = 0; rt < 4; ++rt)
#pragma unroll
        for (int ct = 0; ct < 6; ++ct)
            o[rt][ct] = (f32x4){0.f, 0.f, 0.f, 0.f};

    const ushort* vrow = vT + ((size_t)b * 768 + w * 96 + li) * 2048 + g * 8;

    const int kr  = t >> 4;
    const int c16 = t & 15;
    const int ksw = (c16 * 16) ^ ((kr & 7) << 4);

    union U16 { uint4 u; bf16x8 bv; };

    // prologue: prefetch K(0), publish into Kb[0], barrier, prefetch K(1)
    uint4 kA = *(const uint4*)&qk[(rowB0 + kr)      * 256 + 128 + c16 * 8];
    uint4 kB = *(const uint4*)&qk[(rowB0 + kr + 32) * 256 + 128 + c16 * 8];
    uint4 kC = *(const uint4*)&qk[(rowB0 + kr + 64) * 256 + 128 + c16 * 8];
    uint4 kD = *(const uint4*)&qk[(rowB0 + kr + 96) * 256 + 128 + c16 * 8];
    *(uint4*)&KbB[0][(kr)      * 256 + ksw] = kA;
    *(uint4*)&KbB[0][(kr + 32) * 256 + ksw] = kB;
    *(uint4*)&KbB[0][(kr + 64) * 256 + ksw] = kC;
    *(uint4*)&KbB[0][(kr + 96) * 256 + ksw] = kD;
    __syncthreads();
    {
        const ushort* kn = qk + (rowB0 + 128 + kr) * 256 + 128 + c16 * 8;
        kA = *(const uint4*)(kn);
        kB = *(const uint4*)(kn + (size_t)32 * 256);
        kC = *(const uint4*)(kn + (size_t)64 * 256);
        kD = *(const uint4*)(kn + (size_t)96 * 256);
    }

    for (int jt = 0; jt < 16; ++jt) {
        const unsigned char* Kb = &KbB[jt & 1][0];
        unsigned char* Pb = &PbB[jt & 1][0];
        const ushort* vj = vrow + jt * 128;

        // ---- QK: 4 S-tiles + exp + Pb write + l accumulation ----
        __builtin_amdgcn_s_setprio(1);
#pragma unroll
        for (int ci = 0; ci < 4; ++ci) {
            const int ct = ch * 4 + ci;
            const int krow = ct * 16 + li;
            const int rs = (krow & 7) << 4;
            f32x4 s = {0.f, 0.f, 0.f, 0.f};
#pragma unroll
            for (int ks = 0; ks < 4; ++ks) {
                bf16x8 kf = *(const bf16x8*)&Kb[krow * 256 + ((ks * 64 + g * 16) ^ rs)];
                s = __builtin_amdgcn_mfma_f32_16x16x32_bf16(qf[ks], kf, s, 0, 0, 0);
            }
#pragma unroll
            for (int r = 0; r < 4; ++r) {
                float p = __expf(SCALE * s[r]);
                l_part[r] += p;
                const int prow = rtq * 16 + g * 4 + r;
                *(ushort*)&Pb[prow * 256 + (((ct * 16 + li) * 2) ^ ((prow & 7) << 4))]
                    = (ushort)bfr(p);
            }
        }
        __builtin_amdgcn_s_setprio(0);

        // ---- publish K(jt+1) into the other buffer (before the barrier) ----
        if (jt + 1 < 16) {
            unsigned char* Kn = &KbB[(jt + 1) & 1][0];
            *(uint4*)&Kn[(kr)      * 256 + ksw] = kA;
            *(uint4*)&Kn[(kr + 32) * 256 + ksw] = kB;
            *(uint4*)&Kn[(kr + 64) * 256 + ksw] = kC;
            *(uint4*)&Kn[(kr + 96) * 256 + ksw] = kD;
        }

        // ---- issue V(ks=0): arrives while waiting at the barrier ----
        U16 xa0, xa1, xa2, xa3, xa4, xa5;
        xa0.u = *(const uint4*)(vj + (size_t)(0 * 16) * 2048);
        xa1.u = *(const uint4*)(vj + (size_t)(1 * 16) * 2048);
        xa2.u = *(const uint4*)(vj + (size_t)(2 * 16) * 2048);
        xa3.u = *(const uint4*)(vj + (size_t)(3 * 16) * 2048);
        xa4.u = *(const uint4*)(vj + (size_t)(4 * 16) * 2048);
        xa5.u = *(const uint4*)(vj + (size_t)(5 * 16) * 2048);

        __syncthreads();   // Pb(jt) ready AND K(jt+1) visible; V(ks0) drained

        // ---- prefetch K(jt+2) (drains at NEXT barrier) ----
        if (jt + 2 < 16) {
            const ushort* kn = qk + (rowB0 + (jt + 2) * 128 + kr) * 256 + 128 + c16 * 8;
            kA = *(const uint4*)(kn);
            kB = *(const uint4*)(kn + (size_t)32 * 256);
            kC = *(const uint4*)(kn + (size_t)64 * 256);
            kD = *(const uint4*)(kn + (size_t)96 * 256);
        }

        // ---- PV: 2-deep V rotation; per ks: pa[4] + V[6], 24 MFMA ----
        U16 xb0, xb1, xb2, xb3, xb4, xb5;

#define PA_LOAD(KS) \
        bf16x8 pa0 = *(const bf16x8*)&Pb[(0 * 16 + li) * 256 + (((KS) * 64 + g * 16) ^ ((li & 7) << 4))]; \
        bf16x8 pa1 = *(const bf16x8*)&Pb[(1 * 16 + li) * 256 + (((KS) * 64 + g * 16) ^ ((li & 7) << 4))]; \
        bf16x8 pa2 = *(const bf16x8*)&Pb[(2 * 16 + li) * 256 + (((KS) * 64 + g * 16) ^ ((li & 7) << 4))]; \
        bf16x8 pa3 = *(const bf16x8*)&Pb[(3 * 16 + li) * 256 + (((KS) * 64 + g * 16) ^ ((li & 7) << 4))];
#define VISSUE(B0, B1, B2, B3, B4, B5, KS) \
        B0.u = *(const uint4*)(vj + (size_t)(0 * 16) * 2048 + (KS) * 32); \
        B1.u = *(const uint4*)(vj + (size_t)(1 * 16) * 2048 + (KS) * 32); \
        B2.u = *(const uint4*)(vj + (size_t)(2 * 16) * 2048 + (KS) * 32); \
        B3.u = *(const uint4*)(vj + (size_t)(3 * 16) * 2048 + (KS) * 32); \
        B4.u = *(const uint4*)(vj + (size_t)(4 * 16) * 2048 + (KS) * 32); \
        B5.u = *(const uint4*)(vj + (size_t)(5 * 16) * 2048 + (KS) * 32);
#define PV_MFMA(B0, B1, B2, B3, B4, B5) \
        __builtin_amdgcn_s_setprio(1); \
        o[0][0] = __builtin_amdgcn_mfma_f32_16x16x32_bf16(pa0, B0.bv, o[0][0], 0, 0, 0); \
        o[1][0] = __builtin_amdgcn_mfma_f32_16x16x32_bf16(pa1, B0.bv, o[1][0], 0, 0, 0); \
        o[2][0] = __builtin_amdgcn_mfma_f32_16x16x32_bf16(pa2, B0.bv, o[2][0], 0, 0, 0); \
        o[3][0] = __builtin_amdgcn_mfma_f32_16x16x32_bf16(pa3, B0.bv, o[3][0], 0, 0, 0); \
        o[0][1] = __builtin_amdgcn_mfma_f32_16x16x32_bf16(pa0, B1.bv, o[0][1], 0, 0, 0); \
        o[1][1] = __builtin_amdgcn_mfma_f32_16x16x32_bf16(pa1, B1.bv, o[1][1], 0, 0, 0); \
        o[2][1] = __builtin_amdgcn_mfma_f32_16x16x32_bf16(pa2, B1.bv, o[2][1], 0, 0, 0); \
        o[3][1] = __builtin_amdgcn_mfma_f32_16x16x32_bf16(pa3, B1.bv, o[3][1], 0, 0, 0); \
        o[0][2] = __builtin_amdgcn_mfma_f32_16x16x32_bf16(pa0, B2.bv, o[0][2], 0, 0, 0); \
        o[1][2] = __builtin_amdgcn_mfma_f32_16x16x32_bf16(pa1, B2.bv, o[1][2], 0, 0, 0); \
        o[2][2] = __builtin_amdgcn_mfma_f32_16x16x32_bf16(pa2, B2.bv, o[2][2], 0, 0, 0); \
        o[3][2] = __builtin_amdgcn_mfma_f32_16x16x32_bf16(pa3, B2.bv, o[3][2], 0, 0, 0); \
        o[0][3] = __builtin_amdgcn_mfma_f32_16x16x32_bf16(pa0, B3.bv, o[0][3], 0, 0, 0); \
        o[1][3] = __builtin_amdgcn_mfma_f32_16x16x32_bf16(pa1, B3.bv, o[1][3], 0, 0, 0); \
        o[2][3] = __builtin_amdgcn_mfma_f32_16x16x32_bf16(pa2, B3.bv, o[2][3], 0, 0, 0); \
        o[3][3] = __builtin_amdgcn_mfma_f32_16x16x32_bf16(pa3, B3.bv, o[3][3], 0, 0, 0); \
        o[0][4] = __builtin_amdgcn_mfma_f32_16x16x32_bf16(pa0, B4.bv, o[0][4], 0, 0, 0); \
        o[1][4] = __builtin_amdgcn_mfma_f32_16x16x32_bf16(pa1, B4.bv, o[1][4], 0, 0, 0); \
        o[2][4] = __builtin_amdgcn_mfma_f32_16x16x32_bf16(pa2, B4.bv, o[2][4], 0, 0, 0); \
        o[3][4] = __builtin_amdgcn_mfma_f32_16x16x32_bf16(pa3, B4.bv, o[3][4], 0, 0, 0); \
        o[0][5] = __builtin_amdgcn_mfma_f32_16x16x32_bf16(pa0, B5.bv, o[0][5], 0, 0, 0); \
        o[1][5] = __builtin_amdgcn_mfma_f32_16x16x32_bf16(pa1, B5.bv, o[1][5], 0, 0, 0); \
        o[2][5] = __builtin_amdgcn_mfma_f32_16x16x32_bf16(pa2, B5.bv, o[2][5], 0, 0, 0); \
        o[3][5] = __builtin_amdgcn_mfma_f32_16x16x32_bf16(pa3, B5.bv, o[3][5], 0, 0, 0); \
        __builtin_amdgcn_s_setprio(0);

        {
            VISSUE(xb0, xb1, xb2, xb3, xb4, xb5, 1)
            PA_LOAD(0)
            PV_MFMA(xa0, xa1, xa2, xa3, xa4, xa5)
        }
        {
            VISSUE(xa0, xa1, xa2, xa3, xa4, xa5, 2)
            PA_LOAD(1)
            PV_MFMA(xb0, xb1, xb2, xb3, xb4, xb5)
        }
        {
            VISSUE(xb0, xb1, xb2, xb3, xb4, xb5, 3)
            PA_LOAD(2)
            PV_MFMA(xa0, xa1, xa2, xa3, xa4, xa5)
        }
        {
            PA_LOAD(3)
            PV_MFMA(xb0, xb1, xb2, xb3, xb4, xb5)
        }
#undef PA_LOAD
#undef VISSUE
#undef PV_MFMA
    }

#pragma unroll
    for (int r = 0; r < 4; ++r) {
#pragma unroll
        for (int off = 8; off >= 1; off >>= 1)
            l_part[r] += __shfl_xor(l_part[r], off);
    }
    if (li == 0) {
#pragma unroll
        for (int r = 0; r < 4; ++r)
            lred[ch][rtq * 16 + g * 4 + r] = l_part[r];
    }
    __syncthreads();

    // ---- finalize: /l, gate by bf16 u (read-only), write bf16 gated ----
#pragma unroll
    for (int rt = 0; rt < 4; ++rt) {
#pragma unroll
        for (int r = 0; r < 4; ++r) {
            const int row = rt * 16 + g * 4 + r;
            float inv = 1.0f / (lred[0][row] + lred[1][row]);
            const ushort* ub = u_buf + (rowQ0 + row) * 768;
            ushort* gb = gated + (rowQ0 + row) * 768;
#pragma unroll
            for (int ct = 0; ct < 6; ++ct) {
                int col = w * 96 + ct * 16 + li;
                gb[col] = (ushort)bfr(o[rt][ct][r] * inv * bf2f(ub[col]));
            }
        }
    }
}

extern "C" void kernel_launch(void* const* d_in, const int* in_sizes, int n_in,
                              void* d_out, int out_size, void* d_ws, size_t ws_size,
                              hipStream_t stream)
{
    const float* x    = (const float*)d_in[0];   // [8,2048,384]
    const float* pos  = (const float*)d_in[1];   // [1,2048,256]
    const float* Wuv  = (const float*)d_in[2];   // [384,1792]
    const float* Wout = (const float*)d_in[3];   // [768,384]
    float* out = (float*)d_out;                  // [8,2048,384] f32

    ushort* u_buf = (ushort*)d_ws;                       // 16384*768 bf16
    ushort* qk    = u_buf + (size_t)R_ * HID;            // 16384*256 bf16
    ushort* vT    = qk + (size_t)R_ * 256;               // 8*768*2048 bf16
    ushort* WuvThi  = vT + (size_t)B_ * HID * L_;
    ushort* WuvTlo  = WuvThi + (size_t)NUV * D2;
    ushort* WoutThi = WuvTlo + (size_t)NUV * D2;
    ushort* WoutTlo = WoutThi + (size_t)D2 * HID;
    ushort* gated   = WoutTlo + (size_t)D2 * HID;        // 16384*768 bf16
    ushort* xhi     = gated;                             // alias (dead after gemm1)

    size_t need = ((size_t)R_ * HID + (size_t)R_ * 256 + (size_t)B_ * HID * L_ +
                   2 * (size_t)NUV * D2 + 2 * (size_t)D2 * HID +
                   (size_t)R_ * HID) * 2;                // ~87.9 MB
    if (ws_size < need) return;

    {
        int total = D2 * NUV + HID * D2 + (R_ * D2) / 4;
        conv_all<<<dim3((total + 255) / 256), dim3(256), 0, stream>>>(
            Wuv, WuvThi, WuvTlo, Wout, WoutThi, WoutTlo, x, xhi);
    }

    // GEMM1: hybrid (1-pass u/v MFMA, 2-pass q/k) + fused RoPE
    gemm_2p<1, 1><<<dim3(NUV / 128, R_ / 128), dim3(512), 0, stream>>>(
        xhi, D2, WuvThi, WuvTlo, D2, nullptr, 0, u_buf, qk, vT, pos, D2);

    fused_attn17<<<dim3(256), dim3(512), 0, stream>>>(u_buf, qk, vT, gated);

    // GEMM2: 1-pass hi-only (gated input already bf16-quantized)
    gemm_2p<0, 0><<<dim3(D2 / 128, R_ / 128), dim3(512), 0, stream>>>(
        gated, HID, WoutThi, WoutTlo, HID, out, D2, nullptr, nullptr, nullptr, nullptr, HID);
}

// Round 29
// 186.687 us; speedup vs baseline: 1.4397x; 1.0191x over previous
//
#include <hip/hip_runtime.h>
#include <hip/hip_bf16.h>
#include <math.h>

#define B_    8
#define L_    2048
#define HID   768
#define D2    384
#define NUV   1792
#define R_    16384
#define SCALE 0.08838834764831845f  // 128^-0.5

typedef __attribute__((ext_vector_type(8))) short bf16x8;
typedef __attribute__((ext_vector_type(4))) float f32x4;
typedef unsigned int uint32;
typedef unsigned short ushort;

static __device__ __forceinline__ uint32 bfr(float x) {
    uint32 u = __float_as_uint(x);
    return (u + 0x7FFFu + ((u >> 16) & 1u)) >> 16;
}
static __device__ __forceinline__ uint32 pk2(float lo, float hi) {
    return bfr(lo) | (bfr(hi) << 16);
}
static __device__ __forceinline__ float bf2f(ushort u) {
    return __uint_as_float(((uint32)u) << 16);
}
static __device__ __forceinline__ float silu_f(float x) { return x / (1.0f + __expf(-x)); }

// async global->LDS, 16B per lane. Must be issued with FULL exec
// (dest = readfirstlane(base) + lane*16).
static __device__ __forceinline__ void gld_lds16(const void* g, void* l) {
    __builtin_amdgcn_global_load_lds(
        (const __attribute__((address_space(1))) unsigned int*)g,
        (__attribute__((address_space(3))) unsigned int*)l,
        16, 0, 0);
}

// ---------------------------------------------------------------------------
// Fused pre-transform v2: coalesced 32x32 LDS tile transpose for weights.
//   blocks [0, NT1):        Wuv  -> WuvThi/WuvTlo  ([n][k] hi/lo split)
//   blocks [NT1, NT1+NT2):  Wout -> WoutThi/WoutTlo
//   rest:                   x -> xhi (float4 vectorized, coalesced)
// ---------------------------------------------------------------------------
__global__ __launch_bounds__(256) void conv_all2(
    const float* __restrict__ Wuv, ushort* __restrict__ WuvThi, ushort* __restrict__ WuvTlo,
    const float* __restrict__ Wout, ushort* __restrict__ WoutThi, ushort* __restrict__ WoutTlo,
    const float* __restrict__ X, ushort* __restrict__ Xhi)
{
    const int NT1 = (D2 / 32) * (NUV / 32);   // 12*56 = 672
    const int NT2 = (HID / 32) * (D2 / 32);   // 24*12 = 288

    __shared__ float Ts[32][33];

    const int t   = threadIdx.x;
    const int blk = blockIdx.x;

    const float* W = nullptr;
    ushort *Thi = nullptr, *Tlo = nullptr;
    int ldw = 0, ldt = 0, k0 = 0, n0 = 0;

    if (blk < NT1) {
        W = Wuv; Thi = WuvThi; Tlo = WuvTlo; ldw = NUV; ldt = D2;
        k0 = (blk % (D2 / 32)) * 32;
        n0 = (blk / (D2 / 32)) * 32;
    } else if (blk < NT1 + NT2) {
        int b2 = blk - NT1;
        W = Wout; Thi = WoutThi; Tlo = WoutTlo; ldw = D2; ldt = HID;
        k0 = (b2 % (HID / 32)) * 32;
        n0 = (b2 / (HID / 32)) * 32;
    } else {
        size_t idx = (size_t)(blk - NT1 - NT2) * 256 + t;
        if (idx < (size_t)(R_ * D2) / 4) {
            float4 v = *(const float4*)(X + idx * 4);
            uint2 p; p.x = pk2(v.x, v.y); p.y = pk2(v.z, v.w);
            *(uint2*)(Xhi + idx * 4) = p;
        }
        return;
    }

    // read W tile, coalesced (consecutive t -> consecutive n)
    {
        const int c = t & 31;
#pragma unroll
        for (int i = 0; i < 4; ++i) {
            int r = (t >> 5) + i * 8;
            Ts[r][c] = W[(size_t)(k0 + r) * ldw + n0 + c];
        }
    }
    __syncthreads();
    // write Thi/Tlo rows, coalesced (consecutive t -> consecutive k)
    {
        const int kc = t & 31;
#pragma unroll
        for (int i = 0; i < 4; ++i) {
            int nr = (t >> 5) + i * 8;
            float v = Ts[kc][nr];
            uint32 h = bfr(v);
            size_t o = (size_t)(n0 + nr) * ldt + k0 + kc;
            Thi[o] = (ushort)h;
            Tlo[o] = (ushort)bfr(v - __uint_as_float(h << 16));
        }
    }
}

// ---------------------------------------------------------------------------
// Bf16-A GEMM with global_load_lds staging (r27/r28-verified).
// TWOPASS=1 (GEMM1): stage hi+lo; MFMA hybrid (lo only for q/k n0>=1536);
//                    GAU epilogue (u bf16, vT transposed, q/k fused RoPE).
// TWOPASS=0 (GEMM2): stage hi only (16KB), MFMA hi-only, plain f32 C.
// ---------------------------------------------------------------------------
template<int EPI, int TWOPASS>
__global__ __launch_bounds__(512, 4) void gemm_2p(
    const ushort* __restrict__ Ahi, int lda,
    const ushort* __restrict__ BThi, const ushort* __restrict__ BTlo, int ldbt,
    float* __restrict__ C, int ldc,
    ushort* __restrict__ u_buf, ushort* __restrict__ qk, ushort* __restrict__ vT,
    const float* __restrict__ pos, int K)
{
    __shared__ unsigned char As[128 * 128];
    __shared__ unsigned char Bs[128 * 256];

    const int t  = threadIdx.x;
    const int w  = t >> 6;
    const int l  = t & 63;
    const int g  = l >> 4;
    const int li = l & 15;
    const int wr = w >> 1;
    const int wc = w & 1;
    const int m0 = blockIdx.y * 128;
    const int n0 = blockIdx.x * 128;

    const bool lo_on = TWOPASS && ((EPI == 0) || (n0 >= 1536));
    const int  BROW  = TWOPASS ? 256 : 128;

    f32x4 acc[2][4];
#pragma unroll
    for (int i = 0; i < 2; ++i)
#pragma unroll
        for (int j = 0; j < 4; ++j) acc[i][j] = (f32x4){0.f, 0.f, 0.f, 0.f};

    const int arow0 = t >> 3;
    const int ac8   = t & 7;

    for (int k0 = 0; k0 < K; k0 += 64) {
#pragma unroll
        for (int i = 0; i < 2; ++i) {
            int idx = t + i * 512;
            int row = arow0 + i * 64;
            gld_lds16(Ahi + (size_t)(m0 + row) * lda + k0 + ((ac8 ^ (row & 7)) * 8),
                      &As[idx * 16]);
        }
        if (TWOPASS) {
            const int bcol0 = t >> 4;
            const int bs16  = t & 15;
#pragma unroll
            for (int i = 0; i < 4; ++i) {
                int idx = t + i * 512;
                int c   = bcol0 + i * 32;
                int sl  = bs16 ^ (c & 7);
                const ushort* src = (sl < 8)
                    ? (BThi + (long long)(n0 + c) * ldbt + k0 + sl * 8)
                    : (BTlo + (long long)(n0 + c) * ldbt + k0 + (sl - 8) * 8);
                gld_lds16(src, &Bs[idx * 16]);
            }
        } else {
#pragma unroll
            for (int i = 0; i < 2; ++i) {
                int idx = t + i * 512;
                int c   = arow0 + i * 64;
                gld_lds16(BThi + (long long)(n0 + c) * ldbt + k0 + ((ac8 ^ (c & 7)) * 8),
                          &Bs[idx * 16]);
            }
        }
        __syncthreads();

#pragma unroll
        for (int ks = 0; ks < 2; ++ks) {
            bf16x8 ah[2], bh[4];
#pragma unroll
            for (int mi = 0; mi < 2; ++mi) {
                int row = wr * 32 + mi * 16 + li;
                ah[mi] = *(const bf16x8*)&As[row * 128 + ((ks * 64 + g * 16) ^ ((row & 7) << 4))];
            }
#pragma unroll
            for (int ni = 0; ni < 4; ++ni) {
                int col = wc * 64 + ni * 16 + li;
                int off = (ks * 64 + g * 16) ^ ((col & 7) << 4);
                bh[ni] = *(const bf16x8*)&Bs[col * BROW + off];
            }
#pragma unroll
            for (int mi = 0; mi < 2; ++mi)
#pragma unroll
                for (int ni = 0; ni < 4; ++ni)
                    acc[mi][ni] = __builtin_amdgcn_mfma_f32_16x16x32_bf16(ah[mi], bh[ni], acc[mi][ni], 0, 0, 0);
            if (lo_on) {
                bf16x8 bl[4];
#pragma unroll
                for (int ni = 0; ni < 4; ++ni) {
                    int col = wc * 64 + ni * 16 + li;
                    int off = (ks * 64 + g * 16) ^ ((col & 7) << 4);
                    bl[ni] = *(const bf16x8*)&Bs[col * 256 + 128 + off];
                }
#pragma unroll
                for (int mi = 0; mi < 2; ++mi)
#pragma unroll
                    for (int ni = 0; ni < 4; ++ni)
                        acc[mi][ni] = __builtin_amdgcn_mfma_f32_16x16x32_bf16(ah[mi], bl[ni], acc[mi][ni], 0, 0, 0);
            }
        }
        __syncthreads();
    }

    if (EPI == 0) {
#pragma unroll
        for (int mi = 0; mi < 2; ++mi)
#pragma unroll
            for (int ni = 0; ni < 4; ++ni) {
                int col = n0 + wc * 64 + ni * 16 + li;
#pragma unroll
                for (int r = 0; r < 4; ++r) {
                    int row = m0 + wr * 32 + mi * 16 + g * 4 + r;
                    C[(long long)row * ldc + col] = acc[mi][ni][r];
                }
            }
    } else {
        if (n0 < 768) {
#pragma unroll
            for (int mi = 0; mi < 2; ++mi)
#pragma unroll
                for (int ni = 0; ni < 4; ++ni) {
                    int col = n0 + wc * 64 + ni * 16 + li;
#pragma unroll
                    for (int r = 0; r < 4; ++r) {
                        int row = m0 + wr * 32 + mi * 16 + g * 4 + r;
                        u_buf[(size_t)row * 768 + col] = (ushort)bfr(silu_f(acc[mi][ni][r]));
                    }
                }
        } else if (n0 < 1536) {
            int bb = m0 >> 11;
            int llb = (m0 & 2047) + wr * 32 + g * 4;
#pragma unroll
            for (int mi = 0; mi < 2; ++mi) {
                int ll = llb + mi * 16;
#pragma unroll
                for (int ni = 0; ni < 4; ++ni) {
                    int cv = n0 + wc * 64 + ni * 16 + li - 768;
                    ushort* vb = vT + ((size_t)bb * 768 + cv) * 2048 + ll;
                    *(uint32*)(vb)     = pk2(silu_f(acc[mi][ni][0]), silu_f(acc[mi][ni][1]));
                    *(uint32*)(vb + 2) = pk2(silu_f(acc[mi][ni][2]), silu_f(acc[mi][ni][3]));
                }
            }
        } else {
            // q/k with FUSED RoPE (2-pass precision preserved here).
            ushort* Qs = (ushort*)Bs;   // [128 rows][128 cols]
#pragma unroll
            for (int mi = 0; mi < 2; ++mi)
#pragma unroll
                for (int ni = 0; ni < 4; ++ni) {
                    int coll = wc * 64 + ni * 16 + li;
#pragma unroll
                    for (int r = 0; r < 4; ++r) {
                        int rowl = wr * 32 + mi * 16 + g * 4 + r;
                        Qs[rowl * 128 + coll] = (ushort)bfr(acc[mi][ni][r]);
                    }
                }
            __syncthreads();
            const int qcol0 = n0 - 1536;   // 0 for q, 128 for k
#pragma unroll
            for (int mi = 0; mi < 2; ++mi)
#pragma unroll
                for (int ni = 0; ni < 4; ++ni) {
                    int coll = wc * 64 + ni * 16 + li;
                    int j = coll & 63;
#pragma unroll
                    for (int r = 0; r < 4; ++r) {
                        int rowl = wr * 32 + mi * 16 + g * 4 + r;
                        int rowg = m0 + rowl;
                        int lpos = rowg & (L_ - 1);
                        float sn = pos[lpos * 256 + j];
                        float cs = pos[lpos * 256 + 64 + j];
                        float x1 = bf2f(Qs[rowl * 128 + j]);
                        float x2 = bf2f(Qs[rowl * 128 + 64 + j]);
                        float v = (coll < 64) ? (x1 * cs - x2 * sn)
                                              : (x2 * cs + x1 * sn);
                        qk[(size_t)rowg * 256 + qcol0 + coll] = (ushort)bfr(v);
                    }
                }
        }
    }
}

// ---------------------------------------------------------------------------
// MFMA flash attention v17 (r23-r28 winner, byte-identical).
// ---------------------------------------------------------------------------
__global__ __launch_bounds__(512) void fused_attn17(
    const ushort* __restrict__ u_buf, const ushort* __restrict__ qk,
    const ushort* __restrict__ vT, ushort* __restrict__ gated)
{
    __shared__ unsigned char KbB[2][128 * 256];   // K bf16 dbuf (64 KB)
    __shared__ unsigned char PbB[2][64 * 256];    // P bf16 dbuf (32 KB)
    __shared__ float lred[2][64];

    const int t  = threadIdx.x;
    const int w  = t >> 6;
    const int l  = t & 63;
    const int g  = l >> 4;
    const int li = l & 15;

    const int b  = blockIdx.x & 7;
    const int qt = blockIdx.x >> 3;
    const long long rowQ0 = (long long)b * L_ + (long long)qt * 64;
    const long long rowB0 = (long long)b * L_;

    const int rtq = w >> 1;
    const int ch  = w & 1;

    bf16x8 qf[4];
    {
        const ushort* qrow = qk + (rowQ0 + rtq * 16 + li) * 256;
#pragma unroll
        for (int ks = 0; ks < 4; ++ks)
            qf[ks] = *(const bf16x8*)&qrow[ks * 32 + g * 8];
    }

    float l_part[4] = {0.f, 0.f, 0.f, 0.f};

    f32x4 o[4][6];
#pragma unroll
    for (int rt = 0; rt < 4; ++rt)
#pragma unroll
        for (int ct = 0; ct < 6; ++ct)
            o[rt][ct] = (f32x4){0.f, 0.f, 0.f, 0.f};

    const ushort* vrow = vT + ((size_t)b * 768 + w * 96 + li) * 2048 + g * 8;

    const int kr  = t >> 4;
    const int c16 = t & 15;
    const int ksw = (c16 * 16) ^ ((kr & 7) << 4);

    union U16 { uint4 u; bf16x8 bv; };

    // prologue: prefetch K(0), publish into Kb[0], barrier, prefetch K(1)
    uint4 kA = *(const uint4*)&qk[(rowB0 + kr)      * 256 + 128 + c16 * 8];
    uint4 kB = *(const uint4*)&qk[(rowB0 + kr + 32) * 256 + 128 + c16 * 8];
    uint4 kC = *(const uint4*)&qk[(rowB0 + kr + 64) * 256 + 128 + c16 * 8];
    uint4 kD = *(const uint4*)&qk[(rowB0 + kr + 96) * 256 + 128 + c16 * 8];
    *(uint4*)&KbB[0][(kr)      * 256 + ksw] = kA;
    *(uint4*)&KbB[0][(kr + 32) * 256 + ksw] = kB;
    *(uint4*)&KbB[0][(kr + 64) * 256 + ksw] = kC;
    *(uint4*)&KbB[0][(kr + 96) * 256 + ksw] = kD;
    __syncthreads();
    {
        const ushort* kn = qk + (rowB0 + 128 + kr) * 256 + 128 + c16 * 8;
        kA = *(const uint4*)(kn);
        kB = *(const uint4*)(kn + (size_t)32 * 256);
        kC = *(const uint4*)(kn + (size_t)64 * 256);
        kD = *(const uint4*)(kn + (size_t)96 * 256);
    }

    for (int jt = 0; jt < 16; ++jt) {
        const unsigned char* Kb = &KbB[jt & 1][0];
        unsigned char* Pb = &PbB[jt & 1][0];
        const ushort* vj = vrow + jt * 128;

        // ---- QK: 4 S-tiles + exp + Pb write + l accumulation ----
        __builtin_amdgcn_s_setprio(1);
#pragma unroll
        for (int ci = 0; ci < 4; ++ci) {
            const int ct = ch * 4 + ci;
            const int krow = ct * 16 + li;
            const int rs = (krow & 7) << 4;
            f32x4 s = {0.f, 0.f, 0.f, 0.f};
#pragma unroll
            for (int ks = 0; ks < 4; ++ks) {
                bf16x8 kf = *(const bf16x8*)&Kb[krow * 256 + ((ks * 64 + g * 16) ^ rs)];
                s = __builtin_amdgcn_mfma_f32_16x16x32_bf16(qf[ks], kf, s, 0, 0, 0);
            }
#pragma unroll
            for (int r = 0; r < 4; ++r) {
                float p = __expf(SCALE * s[r]);
                l_part[r] += p;
                const int prow = rtq * 16 + g * 4 + r;
                *(ushort*)&Pb[prow * 256 + (((ct * 16 + li) * 2) ^ ((prow & 7) << 4))]
                    = (ushort)bfr(p);
            }
        }
        __builtin_amdgcn_s_setprio(0);

        // ---- publish K(jt+1) into the other buffer (before the barrier) ----
        if (jt + 1 < 16) {
            unsigned char* Kn = &KbB[(jt + 1) & 1][0];
            *(uint4*)&Kn[(kr)      * 256 + ksw] = kA;
            *(uint4*)&Kn[(kr + 32) * 256 + ksw] = kB;
            *(uint4*)&Kn[(kr + 64) * 256 + ksw] = kC;
            *(uint4*)&Kn[(kr + 96) * 256 + ksw] = kD;
        }

        // ---- issue V(ks=0): arrives while waiting at the barrier ----
        U16 xa0, xa1, xa2, xa3, xa4, xa5;
        xa0.u = *(const uint4*)(vj + (size_t)(0 * 16) * 2048);
        xa1.u = *(const uint4*)(vj + (size_t)(1 * 16) * 2048);
        xa2.u = *(const uint4*)(vj + (size_t)(2 * 16) * 2048);
        xa3.u = *(const uint4*)(vj + (size_t)(3 * 16) * 2048);
        xa4.u = *(const uint4*)(vj + (size_t)(4 * 16) * 2048);
        xa5.u = *(const uint4*)(vj + (size_t)(5 * 16) * 2048);

        __syncthreads();   // Pb(jt) ready AND K(jt+1) visible; V(ks0) drained

        // ---- prefetch K(jt+2) (drains at NEXT barrier) ----
        if (jt + 2 < 16) {
            const ushort* kn = qk + (rowB0 + (jt + 2) * 128 + kr) * 256 + 128 + c16 * 8;
            kA = *(const uint4*)(kn);
            kB = *(const uint4*)(kn + (size_t)32 * 256);
            kC = *(const uint4*)(kn + (size_t)64 * 256);
            kD = *(const uint4*)(kn + (size_t)96 * 256);
        }

        // ---- PV: 2-deep V rotation; per ks: pa[4] + V[6], 24 MFMA ----
        U16 xb0, xb1, xb2, xb3, xb4, xb5;

#define PA_LOAD(KS) \
        bf16x8 pa0 = *(const bf16x8*)&Pb[(0 * 16 + li) * 256 + (((KS) * 64 + g * 16) ^ ((li & 7) << 4))]; \
        bf16x8 pa1 = *(const bf16x8*)&Pb[(1 * 16 + li) * 256 + (((KS) * 64 + g * 16) ^ ((li & 7) << 4))]; \
        bf16x8 pa2 = *(const bf16x8*)&Pb[(2 * 16 + li) * 256 + (((KS) * 64 + g * 16) ^ ((li & 7) << 4))]; \
        bf16x8 pa3 = *(const bf16x8*)&Pb[(3 * 16 + li) * 256 + (((KS) * 64 + g * 16) ^ ((li & 7) << 4))];
#define VISSUE(B0, B1, B2, B3, B4, B5, KS) \
        B0.u = *(const uint4*)(vj + (size_t)(0 * 16) * 2048 + (KS) * 32); \
        B1.u = *(const uint4*)(vj + (size_t)(1 * 16) * 2048 + (KS) * 32); \
        B2.u = *(const uint4*)(vj + (size_t)(2 * 16) * 2048 + (KS) * 32); \
        B3.u = *(const uint4*)(vj + (size_t)(3 * 16) * 2048 + (KS) * 32); \
        B4.u = *(const uint4*)(vj + (size_t)(4 * 16) * 2048 + (KS) * 32); \
        B5.u = *(const uint4*)(vj + (size_t)(5 * 16) * 2048 + (KS) * 32);
#define PV_MFMA(B0, B1, B2, B3, B4, B5) \
        __builtin_amdgcn_s_setprio(1); \
        o[0][0] = __builtin_amdgcn_mfma_f32_16x16x32_bf16(pa0, B0.bv, o[0][0], 0, 0, 0); \
        o[1][0] = __builtin_amdgcn_mfma_f32_16x16x32_bf16(pa1, B0.bv, o[1][0], 0, 0, 0); \
        o[2][0] = __builtin_amdgcn_mfma_f32_16x16x32_bf16(pa2, B0.bv, o[2][0], 0, 0, 0); \
        o[3][0] = __builtin_amdgcn_mfma_f32_16x16x32_bf16(pa3, B0.bv, o[3][0], 0, 0, 0); \
        o[0][1] = __builtin_amdgcn_mfma_f32_16x16x32_bf16(pa0, B1.bv, o[0][1], 0, 0, 0); \
        o[1][1] = __builtin_amdgcn_mfma_f32_16x16x32_bf16(pa1, B1.bv, o[1][1], 0, 0, 0); \
        o[2][1] = __builtin_amdgcn_mfma_f32_16x16x32_bf16(pa2, B1.bv, o[2][1], 0, 0, 0); \
        o[3][1] = __builtin_amdgcn_mfma_f32_16x16x32_bf16(pa3, B1.bv, o[3][1], 0, 0, 0); \
        o[0][2] = __builtin_amdgcn_mfma_f32_16x16x32_bf16(pa0, B2.bv, o[0][2], 0, 0, 0); \
        o[1][2] = __builtin_amdgcn_mfma_f32_16x16x32_bf16(pa1, B2.bv, o[1][2], 0, 0, 0); \
        o[2][2] = __builtin_amdgcn_mfma_f32_16x16x32_bf16(pa2, B2.bv, o[2][2], 0, 0, 0); \
        o[3][2] = __builtin_amdgcn_mfma_f32_16x16x32_bf16(pa3, B2.bv, o[3][2], 0, 0, 0); \
        o[0][3] = __builtin_amdgcn_mfma_f32_16x16x32_bf16(pa0, B3.bv, o[0][3], 0, 0, 0); \
        o[1][3] = __builtin_amdgcn_mfma_f32_16x16x32_bf16(pa1, B3.bv, o[1][3], 0, 0, 0); \
        o[2][3] = __builtin_amdgcn_mfma_f32_16x16x32_bf16(pa2, B3.bv, o[2][3], 0, 0, 0); \
        o[3][3] = __builtin_amdgcn_mfma_f32_16x16x32_bf16(pa3, B3.bv, o[3][3], 0, 0, 0); \
        o[0][4] = __builtin_amdgcn_mfma_f32_16x16x32_bf16(pa0, B4.bv, o[0][4], 0, 0, 0); \
        o[1][4] = __builtin_amdgcn_mfma_f32_16x16x32_bf16(pa1, B4.bv, o[1][4], 0, 0, 0); \
        o[2][4] = __builtin_amdgcn_mfma_f32_16x16x32_bf16(pa2, B4.bv, o[2][4], 0, 0, 0); \
        o[3][4] = __builtin_amdgcn_mfma_f32_16x16x32_bf16(pa3, B4.bv, o[3][4], 0, 0, 0); \
        o[0][5] = __builtin_amdgcn_mfma_f32_16x16x32_bf16(pa0, B5.bv, o[0][5], 0, 0, 0); \
        o[1][5] = __builtin_amdgcn_mfma_f32_16x16x32_bf16(pa1, B5.bv, o[1][5], 0, 0, 0); \
        o[2][5] = __builtin_amdgcn_mfma_f32_16x16x32_bf16(pa2, B5.bv, o[2][5], 0, 0, 0); \
        o[3][5] = __builtin_amdgcn_mfma_f32_16x16x32_bf16(pa3, B5.bv, o[3][5], 0, 0, 0); \
        __builtin_amdgcn_s_setprio(0);

        {
            VISSUE(xb0, xb1, xb2, xb3, xb4, xb5, 1)
            PA_LOAD(0)
            PV_MFMA(xa0, xa1, xa2, xa3, xa4, xa5)
        }
        {
            VISSUE(xa0, xa1, xa2, xa3, xa4, xa5, 2)
            PA_LOAD(1)
            PV_MFMA(xb0, xb1, xb2, xb3, xb4, xb5)
        }
        {
            VISSUE(xb0, xb1, xb2, xb3, xb4, xb5, 3)
            PA_LOAD(2)
            PV_MFMA(xa0, xa1, xa2, xa3, xa4, xa5)
        }
        {
            PA_LOAD(3)
            PV_MFMA(xb0, xb1, xb2, xb3, xb4, xb5)
        }
#undef PA_LOAD
#undef VISSUE
#undef PV_MFMA
    }

#pragma unroll
    for (int r = 0; r < 4; ++r) {
#pragma unroll
        for (int off = 8; off >= 1; off >>= 1)
            l_part[r] += __shfl_xor(l_part[r], off);
    }
    if (li == 0) {
#pragma unroll
        for (int r = 0; r < 4; ++r)
            lred[ch][rtq * 16 + g * 4 + r] = l_part[r];
    }
    __syncthreads();

    // ---- finalize: /l, gate by bf16 u (read-only), write bf16 gated ----
#pragma unroll
    for (int rt = 0; rt < 4; ++rt) {
#pragma unroll
        for (int r = 0; r < 4; ++r) {
            const int row = rt * 16 + g * 4 + r;
            float inv = 1.0f / (lred[0][row] + lred[1][row]);
            const ushort* ub = u_buf + (rowQ0 + row) * 768;
            ushort* gb = gated + (rowQ0 + row) * 768;
#pragma unroll
            for (int ct = 0; ct < 6; ++ct) {
                int col = w * 96 + ct * 16 + li;
                gb[col] = (ushort)bfr(o[rt][ct][r] * inv * bf2f(ub[col]));
            }
        }
    }
}

extern "C" void kernel_launch(void* const* d_in, const int* in_sizes, int n_in,
                              void* d_out, int out_size, void* d_ws, size_t ws_size,
                              hipStream_t stream)
{
    const float* x    = (const float*)d_in[0];   // [8,2048,384]
    const float* pos  = (const float*)d_in[1];   // [1,2048,256]
    const float* Wuv  = (const float*)d_in[2];   // [384,1792]
    const float* Wout = (const float*)d_in[3];   // [768,384]
    float* out = (float*)d_out;                  // [8,2048,384] f32

    ushort* u_buf = (ushort*)d_ws;                       // 16384*768 bf16
    ushort* qk    = u_buf + (size_t)R_ * HID;            // 16384*256 bf16
    ushort* vT    = qk + (size_t)R_ * 256;               // 8*768*2048 bf16
    ushort* WuvThi  = vT + (size_t)B_ * HID * L_;
    ushort* WuvTlo  = WuvThi + (size_t)NUV * D2;
    ushort* WoutThi = WuvTlo + (size_t)NUV * D2;
    ushort* WoutTlo = WoutThi + (size_t)D2 * HID;
    ushort* gated   = WoutTlo + (size_t)D2 * HID;        // 16384*768 bf16
    ushort* xhi     = gated;                             // alias (dead after gemm1)

    size_t need = ((size_t)R_ * HID + (size_t)R_ * 256 + (size_t)B_ * HID * L_ +
                   2 * (size_t)NUV * D2 + 2 * (size_t)D2 * HID +
                   (size_t)R_ * HID) * 2;                // ~87.9 MB
    if (ws_size < need) return;

    {
        const int NT1 = (D2 / 32) * (NUV / 32);          // 672
        const int NT2 = (HID / 32) * (D2 / 32);          // 288
        const int NX  = ((R_ * D2) / 4 + 255) / 256;     // 6144
        conv_all2<<<dim3(NT1 + NT2 + NX), dim3(256), 0, stream>>>(
            Wuv, WuvThi, WuvTlo, Wout, WoutThi, WoutTlo, x, xhi);
    }

    // GEMM1: hybrid (1-pass u/v MFMA, 2-pass q/k) + fused RoPE
    gemm_2p<1, 1><<<dim3(NUV / 128, R_ / 128), dim3(512), 0, stream>>>(
        xhi, D2, WuvThi, WuvTlo, D2, nullptr, 0, u_buf, qk, vT, pos, D2);

    fused_attn17<<<dim3(256), dim3(512), 0, stream>>>(u_buf, qk, vT, gated);

    // GEMM2: 1-pass hi-only (gated input already bf16-quantized)
    gemm_2p<0, 0><<<dim3(D2 / 128, R_ / 128), dim3(512), 0, stream>>>(
        gated, HID, WoutThi, WoutTlo, HID, out, D2, nullptr, nullptr, nullptr, nullptr, HID);
}

// Round 30
// 186.508 us; speedup vs baseline: 1.4411x; 1.0010x over previous
//
#include <hip/hip_runtime.h>
#include <hip/hip_bf16.h>
#include <math.h>

#define B_    8
#define L_    2048
#define HID   768
#define D2    384
#define NUV   1792
#define R_    16384
#define SCALE 0.08838834764831845f  // 128^-0.5

typedef __attribute__((ext_vector_type(8))) short bf16x8;
typedef __attribute__((ext_vector_type(4))) float f32x4;
typedef unsigned int uint32;
typedef unsigned short ushort;

static __device__ __forceinline__ uint32 bfr(float x) {
    uint32 u = __float_as_uint(x);
    return (u + 0x7FFFu + ((u >> 16) & 1u)) >> 16;
}
static __device__ __forceinline__ uint32 pk2(float lo, float hi) {
    return bfr(lo) | (bfr(hi) << 16);
}
static __device__ __forceinline__ float bf2f(ushort u) {
    return __uint_as_float(((uint32)u) << 16);
}
static __device__ __forceinline__ float silu_f(float x) { return x / (1.0f + __expf(-x)); }

// async global->LDS, 16B per lane. Must be issued with FULL exec
// (dest = readfirstlane(base) + lane*16).
static __device__ __forceinline__ void gld_lds16(const void* g, void* l) {
    __builtin_amdgcn_global_load_lds(
        (const __attribute__((address_space(1))) unsigned int*)g,
        (__attribute__((address_space(3))) unsigned int*)l,
        16, 0, 0);
}

// ---------------------------------------------------------------------------
// Fused pre-transform v2 (r29-verified): coalesced 32x32 LDS tile transpose.
// ---------------------------------------------------------------------------
__global__ __launch_bounds__(256) void conv_all2(
    const float* __restrict__ Wuv, ushort* __restrict__ WuvThi, ushort* __restrict__ WuvTlo,
    const float* __restrict__ Wout, ushort* __restrict__ WoutThi, ushort* __restrict__ WoutTlo,
    const float* __restrict__ X, ushort* __restrict__ Xhi)
{
    const int NT1 = (D2 / 32) * (NUV / 32);   // 672
    const int NT2 = (HID / 32) * (D2 / 32);   // 288

    __shared__ float Ts[32][33];

    const int t   = threadIdx.x;
    const int blk = blockIdx.x;

    const float* W = nullptr;
    ushort *Thi = nullptr, *Tlo = nullptr;
    int ldw = 0, ldt = 0, k0 = 0, n0 = 0;

    if (blk < NT1) {
        W = Wuv; Thi = WuvThi; Tlo = WuvTlo; ldw = NUV; ldt = D2;
        k0 = (blk % (D2 / 32)) * 32;
        n0 = (blk / (D2 / 32)) * 32;
    } else if (blk < NT1 + NT2) {
        int b2 = blk - NT1;
        W = Wout; Thi = WoutThi; Tlo = WoutTlo; ldw = D2; ldt = HID;
        k0 = (b2 % (HID / 32)) * 32;
        n0 = (b2 / (HID / 32)) * 32;
    } else {
        size_t idx = (size_t)(blk - NT1 - NT2) * 256 + t;
        if (idx < (size_t)(R_ * D2) / 4) {
            float4 v = *(const float4*)(X + idx * 4);
            uint2 p; p.x = pk2(v.x, v.y); p.y = pk2(v.z, v.w);
            *(uint2*)(Xhi + idx * 4) = p;
        }
        return;
    }

    {
        const int c = t & 31;
#pragma unroll
        for (int i = 0; i < 4; ++i) {
            int r = (t >> 5) + i * 8;
            Ts[r][c] = W[(size_t)(k0 + r) * ldw + n0 + c];
        }
    }
    __syncthreads();
    {
        const int kc = t & 31;
#pragma unroll
        for (int i = 0; i < 4; ++i) {
            int nr = (t >> 5) + i * 8;
            float v = Ts[kc][nr];
            uint32 h = bfr(v);
            size_t o = (size_t)(n0 + nr) * ldt + k0 + kc;
            Thi[o] = (ushort)h;
            Tlo[o] = (ushort)bfr(v - __uint_as_float(h << 16));
        }
    }
}

// ---------------------------------------------------------------------------
// Bf16-A GEMM with global_load_lds staging.
// TWOPASS=1: stage hi+lo (32KB), 2-pass MFMA.
// TWOPASS=0: stage hi only (16KB), 1-pass MFMA.
// EPI 0: plain f32 C.  EPI 1: GAU epilogue (u bf16 / vT / q-k fused RoPE),
//        with n0b grid offset so u/v and q/k can be separate launches.
// All staging is unconditional full-exec (r26 lesson).
// ---------------------------------------------------------------------------
template<int EPI, int TWOPASS>
__global__ __launch_bounds__(512, 4) void gemm_2p(
    const ushort* __restrict__ Ahi, int lda,
    const ushort* __restrict__ BThi, const ushort* __restrict__ BTlo, int ldbt,
    float* __restrict__ C, int ldc,
    ushort* __restrict__ u_buf, ushort* __restrict__ qk, ushort* __restrict__ vT,
    const float* __restrict__ pos, int n0b, int K)
{
    __shared__ unsigned char As[128 * 128];
    __shared__ unsigned char Bs[128 * 256];

    const int t  = threadIdx.x;
    const int w  = t >> 6;
    const int l  = t & 63;
    const int g  = l >> 4;
    const int li = l & 15;
    const int wr = w >> 1;
    const int wc = w & 1;
    const int m0 = blockIdx.y * 128;
    const int n0 = n0b + blockIdx.x * 128;

    const int BROW = TWOPASS ? 256 : 128;

    f32x4 acc[2][4];
#pragma unroll
    for (int i = 0; i < 2; ++i)
#pragma unroll
        for (int j = 0; j < 4; ++j) acc[i][j] = (f32x4){0.f, 0.f, 0.f, 0.f};

    const int arow0 = t >> 3;
    const int ac8   = t & 7;

    for (int k0 = 0; k0 < K; k0 += 64) {
#pragma unroll
        for (int i = 0; i < 2; ++i) {
            int idx = t + i * 512;
            int row = arow0 + i * 64;
            gld_lds16(Ahi + (size_t)(m0 + row) * lda + k0 + ((ac8 ^ (row & 7)) * 8),
                      &As[idx * 16]);
        }
        if (TWOPASS) {
            const int bcol0 = t >> 4;
            const int bs16  = t & 15;
#pragma unroll
            for (int i = 0; i < 4; ++i) {
                int idx = t + i * 512;
                int c   = bcol0 + i * 32;
                int sl  = bs16 ^ (c & 7);
                const ushort* src = (sl < 8)
                    ? (BThi + (long long)(n0 + c) * ldbt + k0 + sl * 8)
                    : (BTlo + (long long)(n0 + c) * ldbt + k0 + (sl - 8) * 8);
                gld_lds16(src, &Bs[idx * 16]);
            }
        } else {
#pragma unroll
            for (int i = 0; i < 2; ++i) {
                int idx = t + i * 512;
                int c   = arow0 + i * 64;
                gld_lds16(BThi + (long long)(n0 + c) * ldbt + k0 + ((ac8 ^ (c & 7)) * 8),
                          &Bs[idx * 16]);
            }
        }
        __syncthreads();

#pragma unroll
        for (int ks = 0; ks < 2; ++ks) {
            bf16x8 ah[2], bh[4];
#pragma unroll
            for (int mi = 0; mi < 2; ++mi) {
                int row = wr * 32 + mi * 16 + li;
                ah[mi] = *(const bf16x8*)&As[row * 128 + ((ks * 64 + g * 16) ^ ((row & 7) << 4))];
            }
#pragma unroll
            for (int ni = 0; ni < 4; ++ni) {
                int col = wc * 64 + ni * 16 + li;
                int off = (ks * 64 + g * 16) ^ ((col & 7) << 4);
                bh[ni] = *(const bf16x8*)&Bs[col * BROW + off];
            }
#pragma unroll
            for (int mi = 0; mi < 2; ++mi)
#pragma unroll
                for (int ni = 0; ni < 4; ++ni)
                    acc[mi][ni] = __builtin_amdgcn_mfma_f32_16x16x32_bf16(ah[mi], bh[ni], acc[mi][ni], 0, 0, 0);
            if (TWOPASS) {
                bf16x8 bl[4];
#pragma unroll
                for (int ni = 0; ni < 4; ++ni) {
                    int col = wc * 64 + ni * 16 + li;
                    int off = (ks * 64 + g * 16) ^ ((col & 7) << 4);
                    bl[ni] = *(const bf16x8*)&Bs[col * 256 + 128 + off];
                }
#pragma unroll
                for (int mi = 0; mi < 2; ++mi)
#pragma unroll
                    for (int ni = 0; ni < 4; ++ni)
                        acc[mi][ni] = __builtin_amdgcn_mfma_f32_16x16x32_bf16(ah[mi], bl[ni], acc[mi][ni], 0, 0, 0);
            }
        }
        __syncthreads();
    }

    if (EPI == 0) {
#pragma unroll
        for (int mi = 0; mi < 2; ++mi)
#pragma unroll
            for (int ni = 0; ni < 4; ++ni) {
                int col = n0 + wc * 64 + ni * 16 + li;
#pragma unroll
                for (int r = 0; r < 4; ++r) {
                    int row = m0 + wr * 32 + mi * 16 + g * 4 + r;
                    C[(long long)row * ldc + col] = acc[mi][ni][r];
                }
            }
    } else {
        if (n0 < 768) {
#pragma unroll
            for (int mi = 0; mi < 2; ++mi)
#pragma unroll
                for (int ni = 0; ni < 4; ++ni) {
                    int col = n0 + wc * 64 + ni * 16 + li;
#pragma unroll
                    for (int r = 0; r < 4; ++r) {
                        int row = m0 + wr * 32 + mi * 16 + g * 4 + r;
                        u_buf[(size_t)row * 768 + col] = (ushort)bfr(silu_f(acc[mi][ni][r]));
                    }
                }
        } else if (n0 < 1536) {
            int bb = m0 >> 11;
            int llb = (m0 & 2047) + wr * 32 + g * 4;
#pragma unroll
            for (int mi = 0; mi < 2; ++mi) {
                int ll = llb + mi * 16;
#pragma unroll
                for (int ni = 0; ni < 4; ++ni) {
                    int cv = n0 + wc * 64 + ni * 16 + li - 768;
                    ushort* vb = vT + ((size_t)bb * 768 + cv) * 2048 + ll;
                    *(uint32*)(vb)     = pk2(silu_f(acc[mi][ni][0]), silu_f(acc[mi][ni][1]));
                    *(uint32*)(vb + 2) = pk2(silu_f(acc[mi][ni][2]), silu_f(acc[mi][ni][3]));
                }
            }
        } else {
            // q/k with FUSED RoPE (2-pass precision preserved here).
            ushort* Qs = (ushort*)Bs;   // [128 rows][128 cols]
#pragma unroll
            for (int mi = 0; mi < 2; ++mi)
#pragma unroll
                for (int ni = 0; ni < 4; ++ni) {
                    int coll = wc * 64 + ni * 16 + li;
#pragma unroll
                    for (int r = 0; r < 4; ++r) {
                        int rowl = wr * 32 + mi * 16 + g * 4 + r;
                        Qs[rowl * 128 + coll] = (ushort)bfr(acc[mi][ni][r]);
                    }
                }
            __syncthreads();
            const int qcol0 = n0 - 1536;   // 0 for q, 128 for k
#pragma unroll
            for (int mi = 0; mi < 2; ++mi)
#pragma unroll
                for (int ni = 0; ni < 4; ++ni) {
                    int coll = wc * 64 + ni * 16 + li;
                    int j = coll & 63;
#pragma unroll
                    for (int r = 0; r < 4; ++r) {
                        int rowl = wr * 32 + mi * 16 + g * 4 + r;
                        int rowg = m0 + rowl;
                        int lpos = rowg & (L_ - 1);
                        float sn = pos[lpos * 256 + j];
                        float cs = pos[lpos * 256 + 64 + j];
                        float x1 = bf2f(Qs[rowl * 128 + j]);
                        float x2 = bf2f(Qs[rowl * 128 + 64 + j]);
                        float v = (coll < 64) ? (x1 * cs - x2 * sn)
                                              : (x2 * cs + x1 * sn);
                        qk[(size_t)rowg * 256 + qcol0 + coll] = (ushort)bfr(v);
                    }
                }
        }
    }
}

// ---------------------------------------------------------------------------
// MFMA flash attention v17 (r23-r29 winner, byte-identical).
// ---------------------------------------------------------------------------
__global__ __launch_bounds__(512) void fused_attn17(
    const ushort* __restrict__ u_buf, const ushort* __restrict__ qk,
    const ushort* __restrict__ vT, ushort* __restrict__ gated)
{
    __shared__ unsigned char KbB[2][128 * 256];   // K bf16 dbuf (64 KB)
    __shared__ unsigned char PbB[2][64 * 256];    // P bf16 dbuf (32 KB)
    __shared__ float lred[2][64];

    const int t  = threadIdx.x;
    const int w  = t >> 6;
    const int l  = t & 63;
    const int g  = l >> 4;
    const int li = l & 15;

    const int b  = blockIdx.x & 7;
    const int qt = blockIdx.x >> 3;
    const long long rowQ0 = (long long)b * L_ + (long long)qt * 64;
    const long long rowB0 = (long long)b * L_;

    const int rtq = w >> 1;
    const int ch  = w & 1;

    bf16x8 qf[4];
    {
        const ushort* qrow = qk + (rowQ0 + rtq * 16 + li) * 256;
#pragma unroll
        for (int ks = 0; ks < 4; ++ks)
            qf[ks] = *(const bf16x8*)&qrow[ks * 32 + g * 8];
    }

    float l_part[4] = {0.f, 0.f, 0.f, 0.f};

    f32x4 o[4][6];
#pragma unroll
    for (int rt = 0; rt < 4; ++rt)
#pragma unroll
        for (int ct = 0; ct < 6; ++ct)
            o[rt][ct] = (f32x4){0.f, 0.f, 0.f, 0.f};

    const ushort* vrow = vT + ((size_t)b * 768 + w * 96 + li) * 2048 + g * 8;

    const int kr  = t >> 4;
    const int c16 = t & 15;
    const int ksw = (c16 * 16) ^ ((kr & 7) << 4);

    union U16 { uint4 u; bf16x8 bv; };

    // prologue: prefetch K(0), publish into Kb[0], barrier, prefetch K(1)
    uint4 kA = *(const uint4*)&qk[(rowB0 + kr)      * 256 + 128 + c16 * 8];
    uint4 kB = *(const uint4*)&qk[(rowB0 + kr + 32) * 256 + 128 + c16 * 8];
    uint4 kC = *(const uint4*)&qk[(rowB0 + kr + 64) * 256 + 128 + c16 * 8];
    uint4 kD = *(const uint4*)&qk[(rowB0 + kr + 96) * 256 + 128 + c16 * 8];
    *(uint4*)&KbB[0][(kr)      * 256 + ksw] = kA;
    *(uint4*)&KbB[0][(kr + 32) * 256 + ksw] = kB;
    *(uint4*)&KbB[0][(kr + 64) * 256 + ksw] = kC;
    *(uint4*)&KbB[0][(kr + 96) * 256 + ksw] = kD;
    __syncthreads();
    {
        const ushort* kn = qk + (rowB0 + 128 + kr) * 256 + 128 + c16 * 8;
        kA = *(const uint4*)(kn);
        kB = *(const uint4*)(kn + (size_t)32 * 256);
        kC = *(const uint4*)(kn + (size_t)64 * 256);
        kD = *(const uint4*)(kn + (size_t)96 * 256);
    }

    for (int jt = 0; jt < 16; ++jt) {
        const unsigned char* Kb = &KbB[jt & 1][0];
        unsigned char* Pb = &PbB[jt & 1][0];
        const ushort* vj = vrow + jt * 128;

        // ---- QK: 4 S-tiles + exp + Pb write + l accumulation ----
        __builtin_amdgcn_s_setprio(1);
#pragma unroll
        for (int ci = 0; ci < 4; ++ci) {
            const int ct = ch * 4 + ci;
            const int krow = ct * 16 + li;
            const int rs = (krow & 7) << 4;
            f32x4 s = {0.f, 0.f, 0.f, 0.f};
#pragma unroll
            for (int ks = 0; ks < 4; ++ks) {
                bf16x8 kf = *(const bf16x8*)&Kb[krow * 256 + ((ks * 64 + g * 16) ^ rs)];
                s = __builtin_amdgcn_mfma_f32_16x16x32_bf16(qf[ks], kf, s, 0, 0, 0);
            }
#pragma unroll
            for (int r = 0; r < 4; ++r) {
                float p = __expf(SCALE * s[r]);
                l_part[r] += p;
                const int prow = rtq * 16 + g * 4 + r;
                *(ushort*)&Pb[prow * 256 + (((ct * 16 + li) * 2) ^ ((prow & 7) << 4))]
                    = (ushort)bfr(p);
            }
        }
        __builtin_amdgcn_s_setprio(0);

        // ---- publish K(jt+1) into the other buffer (before the barrier) ----
        if (jt + 1 < 16) {
            unsigned char* Kn = &KbB[(jt + 1) & 1][0];
            *(uint4*)&Kn[(kr)      * 256 + ksw] = kA;
            *(uint4*)&Kn[(kr + 32) * 256 + ksw] = kB;
            *(uint4*)&Kn[(kr + 64) * 256 + ksw] = kC;
            *(uint4*)&Kn[(kr + 96) * 256 + ksw] = kD;
        }

        // ---- issue V(ks=0): arrives while waiting at the barrier ----
        U16 xa0, xa1, xa2, xa3, xa4, xa5;
        xa0.u = *(const uint4*)(vj + (size_t)(0 * 16) * 2048);
        xa1.u = *(const uint4*)(vj + (size_t)(1 * 16) * 2048);
        xa2.u = *(const uint4*)(vj + (size_t)(2 * 16) * 2048);
        xa3.u = *(const uint4*)(vj + (size_t)(3 * 16) * 2048);
        xa4.u = *(const uint4*)(vj + (size_t)(4 * 16) * 2048);
        xa5.u = *(const uint4*)(vj + (size_t)(5 * 16) * 2048);

        __syncthreads();   // Pb(jt) ready AND K(jt+1) visible; V(ks0) drained

        // ---- prefetch K(jt+2) (drains at NEXT barrier) ----
        if (jt + 2 < 16) {
            const ushort* kn = qk + (rowB0 + (jt + 2) * 128 + kr) * 256 + 128 + c16 * 8;
            kA = *(const uint4*)(kn);
            kB = *(const uint4*)(kn + (size_t)32 * 256);
            kC = *(const uint4*)(kn + (size_t)64 * 256);
            kD = *(const uint4*)(kn + (size_t)96 * 256);
        }

        // ---- PV: 2-deep V rotation; per ks: pa[4] + V[6], 24 MFMA ----
        U16 xb0, xb1, xb2, xb3, xb4, xb5;

#define PA_LOAD(KS) \
        bf16x8 pa0 = *(const bf16x8*)&Pb[(0 * 16 + li) * 256 + (((KS) * 64 + g * 16) ^ ((li & 7) << 4))]; \
        bf16x8 pa1 = *(const bf16x8*)&Pb[(1 * 16 + li) * 256 + (((KS) * 64 + g * 16) ^ ((li & 7) << 4))]; \
        bf16x8 pa2 = *(const bf16x8*)&Pb[(2 * 16 + li) * 256 + (((KS) * 64 + g * 16) ^ ((li & 7) << 4))]; \
        bf16x8 pa3 = *(const bf16x8*)&Pb[(3 * 16 + li) * 256 + (((KS) * 64 + g * 16) ^ ((li & 7) << 4))];
#define VISSUE(B0, B1, B2, B3, B4, B5, KS) \
        B0.u = *(const uint4*)(vj + (size_t)(0 * 16) * 2048 + (KS) * 32); \
        B1.u = *(const uint4*)(vj + (size_t)(1 * 16) * 2048 + (KS) * 32); \
        B2.u = *(const uint4*)(vj + (size_t)(2 * 16) * 2048 + (KS) * 32); \
        B3.u = *(const uint4*)(vj + (size_t)(3 * 16) * 2048 + (KS) * 32); \
        B4.u = *(const uint4*)(vj + (size_t)(4 * 16) * 2048 + (KS) * 32); \
        B5.u = *(const uint4*)(vj + (size_t)(5 * 16) * 2048 + (KS) * 32);
#define PV_MFMA(B0, B1, B2, B3, B4, B5) \
        __builtin_amdgcn_s_setprio(1); \
        o[0][0] = __builtin_amdgcn_mfma_f32_16x16x32_bf16(pa0, B0.bv, o[0][0], 0, 0, 0); \
        o[1][0] = __builtin_amdgcn_mfma_f32_16x16x32_bf16(pa1, B0.bv, o[1][0], 0, 0, 0); \
        o[2][0] = __builtin_amdgcn_mfma_f32_16x16x32_bf16(pa2, B0.bv, o[2][0], 0, 0, 0); \
        o[3][0] = __builtin_amdgcn_mfma_f32_16x16x32_bf16(pa3, B0.bv, o[3][0], 0, 0, 0); \
        o[0][1] = __builtin_amdgcn_mfma_f32_16x16x32_bf16(pa0, B1.bv, o[0][1], 0, 0, 0); \
        o[1][1] = __builtin_amdgcn_mfma_f32_16x16x32_bf16(pa1, B1.bv, o[1][1], 0, 0, 0); \
        o[2][1] = __builtin_amdgcn_mfma_f32_16x16x32_bf16(pa2, B1.bv, o[2][1], 0, 0, 0); \
        o[3][1] = __builtin_amdgcn_mfma_f32_16x16x32_bf16(pa3, B1.bv, o[3][1], 0, 0, 0); \
        o[0][2] = __builtin_amdgcn_mfma_f32_16x16x32_bf16(pa0, B2.bv, o[0][2], 0, 0, 0); \
        o[1][2] = __builtin_amdgcn_mfma_f32_16x16x32_bf16(pa1, B2.bv, o[1][2], 0, 0, 0); \
        o[2][2] = __builtin_amdgcn_mfma_f32_16x16x32_bf16(pa2, B2.bv, o[2][2], 0, 0, 0); \
        o[3][2] = __builtin_amdgcn_mfma_f32_16x16x32_bf16(pa3, B2.bv, o[3][2], 0, 0, 0); \
        o[0][3] = __builtin_amdgcn_mfma_f32_16x16x32_bf16(pa0, B3.bv, o[0][3], 0, 0, 0); \
        o[1][3] = __builtin_amdgcn_mfma_f32_16x16x32_bf16(pa1, B3.bv, o[1][3], 0, 0, 0); \
        o[2][3] = __builtin_amdgcn_mfma_f32_16x16x32_bf16(pa2, B3.bv, o[2][3], 0, 0, 0); \
        o[3][3] = __builtin_amdgcn_mfma_f32_16x16x32_bf16(pa3, B3.bv, o[3][3], 0, 0, 0); \
        o[0][4] = __builtin_amdgcn_mfma_f32_16x16x32_bf16(pa0, B4.bv, o[0][4], 0, 0, 0); \
        o[1][4] = __builtin_amdgcn_mfma_f32_16x16x32_bf16(pa1, B4.bv, o[1][4], 0, 0, 0); \
        o[2][4] = __builtin_amdgcn_mfma_f32_16x16x32_bf16(pa2, B4.bv, o[2][4], 0, 0, 0); \
        o[3][4] = __builtin_amdgcn_mfma_f32_16x16x32_bf16(pa3, B4.bv, o[3][4], 0, 0, 0); \
        o[0][5] = __builtin_amdgcn_mfma_f32_16x16x32_bf16(pa0, B5.bv, o[0][5], 0, 0, 0); \
        o[1][5] = __builtin_amdgcn_mfma_f32_16x16x32_bf16(pa1, B5.bv, o[1][5], 0, 0, 0); \
        o[2][5] = __builtin_amdgcn_mfma_f32_16x16x32_bf16(pa2, B5.bv, o[2][5], 0, 0, 0); \
        o[3][5] = __builtin_amdgcn_mfma_f32_16x16x32_bf16(pa3, B5.bv, o[3][5], 0, 0, 0); \
        __builtin_amdgcn_s_setprio(0);

        {
            VISSUE(xb0, xb1, xb2, xb3, xb4, xb5, 1)
            PA_LOAD(0)
            PV_MFMA(xa0, xa1, xa2, xa3, xa4, xa5)
        }
        {
            VISSUE(xa0, xa1, xa2, xa3, xa4, xa5, 2)
            PA_LOAD(1)
            PV_MFMA(xb0, xb1, xb2, xb3, xb4, xb5)
        }
        {
            VISSUE(xb0, xb1, xb2, xb3, xb4, xb5, 3)
            PA_LOAD(2)
            PV_MFMA(xa0, xa1, xa2, xa3, xa4, xa5)
        }
        {
            PA_LOAD(3)
            PV_MFMA(xb0, xb1, xb2, xb3, xb4, xb5)
        }
#undef PA_LOAD
#undef VISSUE
#undef PV_MFMA
    }

#pragma unroll
    for (int r = 0; r < 4; ++r) {
#pragma unroll
        for (int off = 8; off >= 1; off >>= 1)
            l_part[r] += __shfl_xor(l_part[r], off);
    }
    if (li == 0) {
#pragma unroll
        for (int r = 0; r < 4; ++r)
            lred[ch][rtq * 16 + g * 4 + r] = l_part[r];
    }
    __syncthreads();

    // ---- finalize: /l, gate by bf16 u (read-only), write bf16 gated ----
#pragma unroll
    for (int rt = 0; rt < 4; ++rt) {
#pragma unroll
        for (int r = 0; r < 4; ++r) {
            const int row = rt * 16 + g * 4 + r;
            float inv = 1.0f / (lred[0][row] + lred[1][row]);
            const ushort* ub = u_buf + (rowQ0 + row) * 768;
            ushort* gb = gated + (rowQ0 + row) * 768;
#pragma unroll
            for (int ct = 0; ct < 6; ++ct) {
                int col = w * 96 + ct * 16 + li;
                gb[col] = (ushort)bfr(o[rt][ct][r] * inv * bf2f(ub[col]));
            }
        }
    }
}

extern "C" void kernel_launch(void* const* d_in, const int* in_sizes, int n_in,
                              void* d_out, int out_size, void* d_ws, size_t ws_size,
                              hipStream_t stream)
{
    const float* x    = (const float*)d_in[0];   // [8,2048,384]
    const float* pos  = (const float*)d_in[1];   // [1,2048,256]
    const float* Wuv  = (const float*)d_in[2];   // [384,1792]
    const float* Wout = (const float*)d_in[3];   // [768,384]
    float* out = (float*)d_out;                  // [8,2048,384] f32

    ushort* u_buf = (ushort*)d_ws;                       // 16384*768 bf16
    ushort* qk    = u_buf + (size_t)R_ * HID;            // 16384*256 bf16
    ushort* vT    = qk + (size_t)R_ * 256;               // 8*768*2048 bf16
    ushort* WuvThi  = vT + (size_t)B_ * HID * L_;
    ushort* WuvTlo  = WuvThi + (size_t)NUV * D2;
    ushort* WoutThi = WuvTlo + (size_t)NUV * D2;
    ushort* WoutTlo = WoutThi + (size_t)D2 * HID;
    ushort* gated   = WoutTlo + (size_t)D2 * HID;        // 16384*768 bf16
    ushort* xhi     = gated;                             // alias (dead after gemm1)

    size_t need = ((size_t)R_ * HID + (size_t)R_ * 256 + (size_t)B_ * HID * L_ +
                   2 * (size_t)NUV * D2 + 2 * (size_t)D2 * HID +
                   (size_t)R_ * HID) * 2;                // ~87.9 MB
    if (ws_size < need) return;

    {
        const int NT1 = (D2 / 32) * (NUV / 32);          // 672
        const int NT2 = (HID / 32) * (D2 / 32);          // 288
        const int NX  = ((R_ * D2) / 4 + 255) / 256;     // 6144
        conv_all2<<<dim3(NT1 + NT2 + NX), dim3(256), 0, stream>>>(
            Wuv, WuvThi, WuvTlo, Wout, WoutThi, WoutTlo, x, xhi);
    }

    // GEMM1a: u/v blocks, 1-pass hi-only staging + MFMA (n0 in [0,1536))
    gemm_2p<1, 0><<<dim3(12, R_ / 128), dim3(512), 0, stream>>>(
        xhi, D2, WuvThi, WuvTlo, D2, nullptr, 0, u_buf, qk, vT, pos, 0, D2);

    // GEMM1b: q/k blocks, 2-pass + fused RoPE (n0 in [1536,1792))
    gemm_2p<1, 1><<<dim3(2, R_ / 128), dim3(512), 0, stream>>>(
        xhi, D2, WuvThi, WuvTlo, D2, nullptr, 0, u_buf, qk, vT, pos, 1536, D2);

    fused_attn17<<<dim3(256), dim3(512), 0, stream>>>(u_buf, qk, vT, gated);

    // GEMM2: 1-pass hi-only
    gemm_2p<0, 0><<<dim3(D2 / 128, R_ / 128), dim3(512), 0, stream>>>(
        gated, HID, WoutThi, WoutTlo, HID, out, D2, nullptr, nullptr, nullptr, nullptr, 0, HID);
}